// Round 9
// baseline (1115.259 us; speedup 1.0000x reference)
//
#include <hip/hip_runtime.h>

#define DEVINL __device__ __forceinline__

typedef short bf16x8 __attribute__((ext_vector_type(8)));
typedef float f32x4 __attribute__((ext_vector_type(4)));

#define LOG2E 1.44269504088896f

DEVINL unsigned f2b(float f) {  // f32 -> bf16 bits (round to nearest even)
  unsigned u = __float_as_uint(f);
  u = (u + 0x7FFFu + ((u >> 16) & 1u)) >> 16;
  return u & 0xFFFFu;
}
DEVINL uint4 pack8(const float* v) {
  uint4 u;
  u.x = f2b(v[0]) | (f2b(v[1]) << 16);
  u.y = f2b(v[2]) | (f2b(v[3]) << 16);
  u.z = f2b(v[4]) | (f2b(v[5]) << 16);
  u.w = f2b(v[6]) | (f2b(v[7]) << 16);
  return u;
}

// ---------------- reduction helpers ----------------
DEVINL float4 block_sum4(float4 v, float4* sh) {
  const int lane = threadIdx.x & 63, wid = threadIdx.x >> 6;
#pragma unroll
  for (int o = 32; o; o >>= 1) {
    v.x += __shfl_down(v.x, o);
    v.y += __shfl_down(v.y, o);
    v.z += __shfl_down(v.z, o);
    v.w += __shfl_down(v.w, o);
  }
  __syncthreads();
  if (lane == 0) sh[wid] = v;
  __syncthreads();
  float4 a = sh[0], b = sh[1], c = sh[2], d = sh[3], r;
  r.x = a.x + b.x + c.x + d.x;
  r.y = a.y + b.y + c.y + d.y;
  r.z = a.z + b.z + c.z + d.z;
  r.w = a.w + b.w + c.w + d.w;
  return r;
}
DEVINL float block_sum1(float v, float* sh) {
  const int lane = threadIdx.x & 63, wid = threadIdx.x >> 6;
#pragma unroll
  for (int o = 32; o; o >>= 1) v += __shfl_down(v, o);
  __syncthreads();
  if (lane == 0) sh[wid] = v;
  __syncthreads();
  return sh[0] + sh[1] + sh[2] + sh[3];
}

// ---- fused table projections (9 jobs via blockIdx.y) ----
// Q-producing tables fold LOG2E (softmax uses exp2).
__global__ __launch_bounds__(256) void tabproj9_kernel(
    const float* __restrict__ in_W, const float* __restrict__ in_b,
    const float* __restrict__ cx_W, const float* __restrict__ cx_b,
    const float* __restrict__ tx_W, const float* __restrict__ tx_b,
    const float* __restrict__ sWk, const float* __restrict__ sWv,
    const float* __restrict__ sWq, const float* __restrict__ aWk,
    const float* __restrict__ aWq, float* __restrict__ Ttab) {
  const int z = blockIdx.y;
  const float* V;
  const float* bias;
  const float* W;
  float* P;
  int nvec;
  float scl = 1.f;
  if (z < 6) {
    V = in_W; bias = in_b; nvec = 3;
    const int i = z / 3, wsel = z % 3;
    W = (wsel == 0 ? sWk : wsel == 1 ? sWv : sWq) + (size_t)i * 262144;
    P = Ttab + (size_t)z * 2048;
    if (wsel == 2) scl = 0.0625f * LOG2E;
  } else if (z < 8) {
    V = cx_W; bias = cx_b; nvec = 1;
    W = aWk + (size_t)(z - 6) * 262144;
    P = Ttab + 12288 + (size_t)(z - 6) * 1024;
  } else {
    V = tx_W; bias = tx_b; nvec = 1;
    W = aWq; P = Ttab + 14336; scl = 0.08838834764831845f * LOG2E;
  }
  __shared__ float4 sh4[4];
  const int j = blockIdx.x, tid = threadIdx.x;
  float acc[4] = {0.f, 0.f, 0.f, 0.f};
  for (int kk = tid; kk < 512; kk += 256) {
    const float w = W[(size_t)kk * 512 + j];
    for (int v = 0; v < nvec; ++v) acc[v] += V[(size_t)v * 512 + kk] * w;
    acc[3] += bias[kk] * w;
  }
  float4 packed = make_float4(acc[0], acc[1], acc[2], acc[3]);
  packed = block_sum4(packed, sh4);
  if (tid == 0) {
    const float vals[4] = {packed.x * scl, packed.y * scl, packed.z * scl, packed.w * scl};
    for (int v = 0; v < nvec; ++v) P[(size_t)v * 512 + j] = vals[v];
    P[(size_t)nvec * 512 + j] = vals[3];
  }
}

// ---- fused weight transposes, K=512 (9 jobs via blockIdx.z); Q scaled w/ LOG2E ----
__global__ __launch_bounds__(256) void transpose_kvq_kernel(
    const float* __restrict__ sWk, const float* __restrict__ sWv,
    const float* __restrict__ sWq, const float* __restrict__ aWv,
    const float* __restrict__ aWq, unsigned short* __restrict__ Wkvqt0,
    unsigned short* __restrict__ aWvt0, unsigned short* __restrict__ aWqt1) {
  const int z = blockIdx.z;
  const float* src;
  unsigned short* dst;
  float scl = 1.f;
  if (z < 6) {
    const int i = z / 3, wsel = z % 3;
    src = (wsel == 0 ? sWk : wsel == 1 ? sWv : sWq) + (size_t)i * 262144;
    dst = Wkvqt0 + (size_t)i * 786432 + (size_t)wsel * 262144;
    if (wsel == 2) scl = 0.0625f * LOG2E;
  } else if (z < 8) {
    src = aWv + (size_t)(z - 6) * 262144;
    dst = aWvt0 + (size_t)(z - 6) * 262144;
  } else {
    src = aWq + 262144; dst = aWqt1; scl = 0.08838834764831845f * LOG2E;
  }
  __shared__ float tile[32][33];
  const int n0 = blockIdx.x * 32, k0 = blockIdx.y * 32;
  const int tx = threadIdx.x, ty = threadIdx.y;  // 32 x 8
#pragma unroll
  for (int r = 0; r < 4; ++r)
    tile[ty + 8 * r][tx] = src[(size_t)(k0 + ty + 8 * r) * 512 + n0 + tx];
  __syncthreads();
#pragma unroll
  for (int r = 0; r < 4; ++r)
    dst[(size_t)(n0 + ty + 8 * r) * 512 + k0 + tx] =
        (unsigned short)f2b(scl * tile[tx][ty + 8 * r]);
}

// ---- fused weight transposes, K=1024 (4 jobs via blockIdx.z) ----
__global__ __launch_bounds__(256) void transpose_f_kernel(
    const float* __restrict__ sWf, const float* __restrict__ aWf,
    unsigned short* __restrict__ Wft0, unsigned short* __restrict__ aWft0) {
  const int z = blockIdx.z;
  const float* src = (z < 2 ? sWf + (size_t)z * 524288 : aWf + (size_t)(z - 2) * 524288);
  unsigned short* dst =
      (z < 2 ? Wft0 + (size_t)z * 524288 : aWft0 + (size_t)(z - 2) * 524288);
  __shared__ float tile[32][33];
  const int n0 = blockIdx.x * 32, k0 = blockIdx.y * 32;
  const int tx = threadIdx.x, ty = threadIdx.y;  // 32 x 8
#pragma unroll
  for (int r = 0; r < 4; ++r)
    tile[ty + 8 * r][tx] = src[(size_t)(k0 + ty + 8 * r) * 512 + n0 + tx];
  __syncthreads();
#pragma unroll
  for (int r = 0; r < 4; ++r)
    dst[(size_t)(n0 + ty + 8 * r) * 1024 + k0 + tx] =
        (unsigned short)f2b(tile[tx][ty + 8 * r]);
}

// ---- cross-side encoder K/Q: rank-3 affine -> Kfr + Qbf (rows) ----
__global__ __launch_bounds__(128) void affine3kq_kernel(
    const float* __restrict__ cx, const float* __restrict__ cy, int sel,
    const float* __restrict__ TK, const float* __restrict__ TQ,
    unsigned short* __restrict__ Kfr, unsigned short* __restrict__ Qbf) {
  const int row = blockIdx.x;
  const int b = row >> 10, s = row & 1023;
  const float x = cx[row];
  const float* y = cy + (size_t)row * 8 + 2 * sel;
  const float y0 = y[0], y1 = y[1];
  const int t = threadIdx.x;
  const bool isQ = t >= 64;
  const int c = t & 63;
  const int h = c >> 5;
  const int d0 = (c & 31) * 8;
  const float* T = isQ ? TQ : TK;
  float v[8];
#pragma unroll
  for (int j = 0; j < 8; ++j) {
    const int col = h * 256 + d0 + j;
    v[j] = x * T[col] + y0 * T[512 + col] + y1 * T[1024 + col] + T[1536 + col];
  }
  const uint4 u = pack8(v);
  const int bh = b * 2 + h;
  if (isQ) {
    *(uint4*)(Qbf + ((size_t)bh * 1024 + s) * 256 + d0) = u;
  } else {
    const int kc = d0 >> 5;
    const int lane = ((d0 & 31) >> 3) * 16 + (s & 15);
    *(uint4*)(Kfr + ((size_t)(bh * 8 + kc) * 64 + (s >> 4)) * 512 + lane * 8) = u;
  }
}

// ---- cross-side encoder V: compute rank-3 affine per 32x32 tile -> Vfr direct ----
__global__ __launch_bounds__(256) void affine3v_frag_kernel(
    const float* __restrict__ cx, const float* __restrict__ cy, int sel,
    const float* __restrict__ TV, unsigned short* __restrict__ Vfr) {
  __shared__ float tile[32][33];
  const int s0 = blockIdx.x * 32, d0 = blockIdx.y * 32;
  const int bh = blockIdx.z;
  const int b = bh >> 1, h = bh & 1;
  const int tx = threadIdx.x, ty = threadIdx.y;  // 32 x 8
  const int col = h * 256 + d0 + tx;
  const float tv0 = TV[col], tv1 = TV[512 + col], tv2 = TV[1024 + col],
              tv3 = TV[1536 + col];
#pragma unroll
  for (int r = 0; r < 4; ++r) {
    const int row = b * 1024 + s0 + ty + 8 * r;
    const float x = cx[row];
    const float* y = cy + (size_t)row * 8 + 2 * sel;
    tile[ty + 8 * r][tx] = x * tv0 + y[0] * tv1 + y[1] * tv2 + tv3;
  }
  __syncthreads();
  const int idx = ty * 32 + tx;
  if (idx < 128) {
    const int dj = idx & 31, sch = idx >> 5;
    float v[8];
#pragma unroll
    for (int jj = 0; jj < 8; ++jj) v[jj] = tile[sch * 8 + jj][dj];
    const uint4 u = pack8(v);
    const int sc = s0 >> 5;
    const int dtile = (d0 + dj) >> 4;
    const int lane = sch * 16 + (dj & 15);
    *(uint4*)(Vfr + ((size_t)(bh * 32 + sc) * 16 + dtile) * 512 + lane * 8) = u;
  }
}

// ---- decoder rank-1 producers (nh=4, D=128): T rows [0]=w, [1]=bias ----
__global__ __launch_bounds__(64) void rank1_pack_kernel(
    const float* __restrict__ x, const float* __restrict__ T,
    unsigned short* __restrict__ dst, int isQ) {
  const int row = blockIdx.x;
  const int b = row >> 10, s = row & 1023;
  const float xv = x[row];
  const int c = threadIdx.x;        // 64 chunks of 8
  const int h = c >> 4;             // 16 chunks per head
  const int d0 = (c & 15) * 8;
  float v[8];
#pragma unroll
  for (int j = 0; j < 8; ++j) {
    const int col = h * 128 + d0 + j;
    v[j] = xv * T[col] + T[512 + col];
  }
  const uint4 u = pack8(v);
  const int bh = b * 4 + h;
  if (isQ) {
    *(uint4*)(dst + ((size_t)bh * 1024 + s) * 128 + d0) = u;
  } else {
    const int kc = d0 >> 5;
    const int lane = ((d0 & 31) >> 3) * 16 + (s & 15);
    *(uint4*)(dst + ((size_t)(bh * 4 + kc) * 64 + (s >> 4)) * 512 + lane * 8) = u;
  }
}

// ---- out[r,:] = cx[r]*W3[0,:] + y0*W3[1,:] + y1*W3[2,:] + bias (f32 + bf16) ----
__global__ __launch_bounds__(512) void affine3_kernel(
    const float* __restrict__ cx, const float* __restrict__ cy, int sel,
    const float* __restrict__ W3, const float* __restrict__ bias,
    float* __restrict__ out, unsigned short* __restrict__ outb) {
  const int r = blockIdx.x, j = threadIdx.x;
  const float* y = cy + (size_t)r * 8 + 2 * sel;
  const float v = cx[r] * W3[j] + y[0] * W3[512 + j] + y[1] * W3[1024 + j] + bias[j];
  if (out) out[(size_t)r * 512 + j] = v;
  if (outb) outb[(size_t)r * 512 + j] = (unsigned short)f2b(v);
}

// ---- out[r,:] = x[r]*w + b ----
__global__ __launch_bounds__(512) void rank1_kernel(
    const float* __restrict__ x, const float* __restrict__ w,
    const float* __restrict__ b, float* __restrict__ out,
    unsigned short* __restrict__ outb) {
  const int r = blockIdx.x, j = threadIdx.x;
  const float v = x[r] * w[j] + b[j];
  if (out) out[(size_t)r * 512 + j] = v;
  if (outb) outb[(size_t)r * 512 + j] = (unsigned short)f2b(v);
}

// ------------- split-K Wf GEMM (double-buffered): two K-halves via blockIdx.z ----
__global__ __launch_bounds__(256) void gemm_wf_kernel(
    const unsigned short* __restrict__ A0, const unsigned short* __restrict__ A1,
    const float* __restrict__ F0, const float* __restrict__ F1,
    const unsigned short* __restrict__ Wt, const float* __restrict__ bias,
    float* __restrict__ C0, float* __restrict__ C1) {
  constexpr int BM = 128, BN = 64, BK = 32, LDP = 40, K = 512, N = 512;
  __shared__ unsigned short As[2][BM * LDP];
  __shared__ unsigned short Bs[2][BN * LDP];
  const int kz = blockIdx.z;
  const int tid = threadIdx.x;
  const int lane = tid & 63, w = tid >> 6;
  const int bm = blockIdx.y * BM, bn = blockIdx.x * BN;
  const int wm = (w & 1) * 64, wn = (w >> 1) * 32;
  const int l15 = lane & 15, lq = lane >> 4;
  const int ar = tid >> 1, ac = (tid & 1) * 16;
  const int br = tid >> 2, bc = (tid & 3) * 8;
  const unsigned short* A = kz ? A1 : A0;
  const bool useF = (kz != 0) && (F0 != nullptr);
  const size_t arow = (size_t)(bm + ar) * 512;
  const size_t brow = (size_t)(bn + br) * 1024 + (size_t)kz * 512;
  f32x4 acc[4][2] = {};
  uint4 ra0, ra1, rb0;
#define GLOAD(k0_)                                                          \
  do {                                                                      \
    if (useF) {                                                             \
      const float* p0 = F0 + arow + (k0_) + ac;                             \
      const float* p1 = F1 + arow + (k0_) + ac;                             \
      float s[16];                                                          \
      const float4 x0 = *(const float4*)p0, x1 = *(const float4*)(p0 + 4);  \
      const float4 x2 = *(const float4*)(p0 + 8), x3 = *(const float4*)(p0 + 12); \
      const float4 y0 = *(const float4*)p1, y1 = *(const float4*)(p1 + 4);  \
      const float4 y2 = *(const float4*)(p1 + 8), y3 = *(const float4*)(p1 + 12); \
      s[0] = x0.x + y0.x; s[1] = x0.y + y0.y; s[2] = x0.z + y0.z; s[3] = x0.w + y0.w; \
      s[4] = x1.x + y1.x; s[5] = x1.y + y1.y; s[6] = x1.z + y1.z; s[7] = x1.w + y1.w; \
      s[8] = x2.x + y2.x; s[9] = x2.y + y2.y; s[10] = x2.z + y2.z; s[11] = x2.w + y2.w; \
      s[12] = x3.x + y3.x; s[13] = x3.y + y3.y; s[14] = x3.z + y3.z; s[15] = x3.w + y3.w; \
      ra0 = pack8(s); ra1 = pack8(s + 8);                                   \
    } else {                                                                \
      ra0 = *(const uint4*)(A + arow + (k0_) + ac);                         \
      ra1 = *(const uint4*)(A + arow + (k0_) + ac + 8);                     \
    }                                                                       \
    rb0 = *(const uint4*)(Wt + brow + (k0_) + bc);                          \
  } while (0)
  GLOAD(0);
  *(uint4*)(As[0] + ar * LDP + ac) = ra0;
  *(uint4*)(As[0] + ar * LDP + ac + 8) = ra1;
  *(uint4*)(Bs[0] + br * LDP + bc) = rb0;
  __syncthreads();
  int buf = 0;
  for (int k0 = 0; k0 < K; k0 += BK) {
    const bool more = (k0 + BK) < K;
    if (more) GLOAD(k0 + BK);
    bf16x8 af[4], bfr[2];
#pragma unroll
    for (int mt = 0; mt < 4; ++mt)
      af[mt] = *(const bf16x8*)(As[buf] + (wm + mt * 16 + l15) * LDP + lq * 8);
#pragma unroll
    for (int nt = 0; nt < 2; ++nt)
      bfr[nt] = *(const bf16x8*)(Bs[buf] + (wn + nt * 16 + l15) * LDP + lq * 8);
#pragma unroll
    for (int mt = 0; mt < 4; ++mt)
#pragma unroll
      for (int nt = 0; nt < 2; ++nt)
        acc[mt][nt] =
            __builtin_amdgcn_mfma_f32_16x16x32_bf16(af[mt], bfr[nt], acc[mt][nt], 0, 0, 0);
    if (more) {
      *(uint4*)(As[buf ^ 1] + ar * LDP + ac) = ra0;
      *(uint4*)(As[buf ^ 1] + ar * LDP + ac + 8) = ra1;
      *(uint4*)(Bs[buf ^ 1] + br * LDP + bc) = rb0;
    }
    __syncthreads();
    buf ^= 1;
  }
#undef GLOAD
  float* C = kz ? C1 : C0;
#pragma unroll
  for (int nt = 0; nt < 2; ++nt) {
    const int col = bn + wn + nt * 16 + l15;
    const float bv = (kz && bias) ? bias[col] : 0.f;
#pragma unroll
    for (int mt = 0; mt < 4; ++mt) {
#pragma unroll
      for (int r = 0; r < 4; ++r) {
        const int row = bm + wm + mt * 16 + lq * 4 + r;
        C[(size_t)row * N + col] = acc[mt][nt][r] + bv;
      }
    }
  }
}

// ------- MFMA GEMM with fused frag-pack epilogue (K=512, single A) ---------------
// MODE 0: N=1536 = K|V|Q sections, nh=2, D=256 -> Kfr, Vfr, Qbf
// MODE 1: N=512  = V only, nh=4, D=128 -> Vfr
// MODE 2: N=512  = Q only, nh=4, D=128 -> Qbf (weights pre-scaled)
template <int MODE>
__global__ __launch_bounds__(256) void gemm_pack_kernel(
    const unsigned short* __restrict__ A0, const unsigned short* __restrict__ Wt,
    unsigned short* __restrict__ Kfr, unsigned short* __restrict__ Vfr,
    unsigned short* __restrict__ Qbf) {
  constexpr int BM = 128, BN = 64, BK = 32, LDP = 40, K = 512;
  __shared__ unsigned short As[2][BM * LDP];
  __shared__ unsigned short Bs[2][BN * LDP];
  const int tid = threadIdx.x;
  const int lane = tid & 63, w = tid >> 6;
  const int bm = blockIdx.y * BM, bn = blockIdx.x * BN;
  const int wm = (w & 1) * 64, wn = (w >> 1) * 32;
  const int l15 = lane & 15, lq = lane >> 4;
  const int ar = tid >> 1, ac = (tid & 1) * 16;
  const int br = tid >> 2, bc = (tid & 3) * 8;
  f32x4 acc[4][2] = {};
  uint4 ra0 = *(const uint4*)(A0 + (size_t)(bm + ar) * K + ac);
  uint4 ra1 = *(const uint4*)(A0 + (size_t)(bm + ar) * K + ac + 8);
  uint4 rb0 = *(const uint4*)(Wt + (size_t)(bn + br) * K + bc);
  *(uint4*)(As[0] + ar * LDP + ac) = ra0;
  *(uint4*)(As[0] + ar * LDP + ac + 8) = ra1;
  *(uint4*)(Bs[0] + br * LDP + bc) = rb0;
  __syncthreads();
  int buf = 0;
  for (int k0 = 0; k0 < K; k0 += BK) {
    const bool more = (k0 + BK) < K;
    if (more) {
      ra0 = *(const uint4*)(A0 + (size_t)(bm + ar) * K + k0 + BK + ac);
      ra1 = *(const uint4*)(A0 + (size_t)(bm + ar) * K + k0 + BK + ac + 8);
      rb0 = *(const uint4*)(Wt + (size_t)(bn + br) * K + k0 + BK + bc);
    }
    bf16x8 af[4], bfr[2];
#pragma unroll
    for (int mt = 0; mt < 4; ++mt)
      af[mt] = *(const bf16x8*)(As[buf] + (wm + mt * 16 + l15) * LDP + lq * 8);
#pragma unroll
    for (int nt = 0; nt < 2; ++nt)
      bfr[nt] = *(const bf16x8*)(Bs[buf] + (wn + nt * 16 + l15) * LDP + lq * 8);
#pragma unroll
    for (int mt = 0; mt < 4; ++mt)
#pragma unroll
      for (int nt = 0; nt < 2; ++nt)
        acc[mt][nt] =
            __builtin_amdgcn_mfma_f32_16x16x32_bf16(af[mt], bfr[nt], acc[mt][nt], 0, 0, 0);
    if (more) {
      *(uint4*)(As[buf ^ 1] + ar * LDP + ac) = ra0;
      *(uint4*)(As[buf ^ 1] + ar * LDP + ac + 8) = ra1;
      *(uint4*)(Bs[buf ^ 1] + br * LDP + bc) = rb0;
    }
    __syncthreads();
    buf ^= 1;
  }
  // ---- fused pack epilogue ----
  const int b = bm >> 10;
  const int s0base = (bm & 1023) + wm + lq * 4;
#pragma unroll
  for (int nt = 0; nt < 2; ++nt) {
    const int col = bn + wn + nt * 16 + l15;
    int sec, h, d, nh2, Dv;
    if constexpr (MODE == 0) {
      sec = col >> 9; const int c = col & 511; h = c >> 8; d = c & 255; nh2 = 2; Dv = 256;
    } else if constexpr (MODE == 1) {
      sec = 1; h = col >> 7; d = col & 127; nh2 = 4; Dv = 128;
    } else {
      sec = 2; h = col >> 7; d = col & 127; nh2 = 4; Dv = 128;
    }
    const int bh = b * nh2 + h;
#pragma unroll
    for (int mt = 0; mt < 4; ++mt) {
      const int s0 = s0base + mt * 16;
      const float* a = (const float*)&acc[mt][nt];
      if (sec == 2) {                           // Q: [bh][s][Dv]
        unsigned short* q = Qbf + ((size_t)bh * 1024 + s0) * Dv + d;
#pragma unroll
        for (int r = 0; r < 4; ++r) q[(size_t)r * Dv] = (unsigned short)f2b(a[r]);
      } else if (sec == 0) {                    // K frag
        unsigned short* kp = Kfr +
            ((size_t)(bh * 8 + (d >> 5)) * 64 + (s0 >> 4)) * 512 +
            ((d & 31) >> 3) * 128 + (d & 7);
#pragma unroll
        for (int r = 0; r < 4; ++r)
          kp[((s0 & 15) + r) * 8] = (unsigned short)f2b(a[r]);
      } else {                                  // V frag
        unsigned short* vp = Vfr +
            ((size_t)(bh * 32 + (s0 >> 5)) * (Dv / 16) + (d >> 4)) * 512 +
            (((s0 >> 3) & 3) * 16 + (d & 15)) * 8 + (s0 & 7);
        uint2 u;
        u.x = f2b(a[0]) | (f2b(a[1]) << 16);
        u.y = f2b(a[2]) | (f2b(a[3]) << 16);
        *(uint2*)vp = u;
      }
    }
  }
}

// -------- MFMA flash attention, chunked keys + deferred normalization -----------
// Block = QT*16 q rows of one (b,head) vs ONE KV side, keys in 8 chunks of 128
// (128-key strip halves LDS vs 256 -> 3 blocks/CU for the NQS=2 config).
// No-max softmax => O = (sum_k exp2(s) V) / (sum_k exp2(s)) accumulated per chunk;
// normalization applied once at the end.  NQS Q-sets share K and V loads.
// All register arrays statically indexed (rule #20); c/kc/sc2 feed addresses only.
// NQS==2: grid = 2*256, side = bx>>8; writes f32 partials to Rp.
// NQS==1: writes bf16 with post_scale.
template <int D, int NQS, int QT>
__global__ __launch_bounds__(256, 2) void attn_mfma_kernel(
    const unsigned short* __restrict__ Qa, const unsigned short* __restrict__ Qb,
    const unsigned short* __restrict__ KfrA, const unsigned short* __restrict__ KfrB,
    const unsigned short* __restrict__ VfrA, const unsigned short* __restrict__ VfrB,
    float post_scale, int nh, unsigned short* __restrict__ R,
    float* __restrict__ Rp) {
  constexpr int QP = D + 8;      // qsh pitch
  constexpr int SP = 128 + 8;    // strip pitch (chunk = 128 keys)
  constexpr int DT = D / 64;     // d-tiles per wave
  constexpr int NR = QT * 16;    // q rows per block
  const int tid = threadIdx.x;
  const int lane = tid & 63, w = tid >> 6;
  const int l15 = lane & 15, lq = lane >> 4;
  const int nbh = 4 * nh;
  int bx = blockIdx.x;
  int side = 0;
  if constexpr (NQS == 2) { side = bx >> 8; bx &= 255; }
  const int bh = bx % nbh;       // XCD-local (b,h): same-bh blocks share an XCD's L2
  const int qb = (bx / nbh) * NR;
  const int b = bh / nh, head = bh % nh;
  const size_t rowb = (size_t)b * 1024;
  const int colo = head * D;

  __shared__ unsigned short qsh[NQS * NR * QP];
  __shared__ unsigned short ssh[NQS * NR * SP];
  __shared__ float red[NQS * QT * 4 * 16];

  // ---- stage Q ----
  for (int idx = tid; idx < NQS * NR * (D / 8); idx += 256) {
    const int set = idx / (NR * (D / 8));
    const int rem = idx - set * NR * (D / 8);
    const int r = rem / (D / 8), ch = rem - r * (D / 8);
    const unsigned short* Q = set ? Qb : Qa;
    const uint4 u = *(const uint4*)(Q + ((size_t)bh * 1024 + qb + r) * D + ch * 8);
    *(uint4*)(qsh + (set * NR + r) * QP + ch * 8) = u;
  }
  __syncthreads();

  const unsigned short* Kp = (side ? KfrB : KfrA) + (size_t)bh * ((size_t)D * 1024);
  const unsigned short* Vp = (side ? VfrB : VfrA) + (size_t)bh * ((size_t)D * 1024);

  float psum[QT][NQS][4];
#pragma unroll
  for (int qt = 0; qt < QT; ++qt)
#pragma unroll
    for (int s2 = 0; s2 < NQS; ++s2)
#pragma unroll
      for (int r = 0; r < 4; ++r) psum[qt][s2][r] = 0.f;
  f32x4 acc_o[QT][NQS][DT] = {};

#pragma unroll 1
  for (int c = 0; c < 8; ++c) {        // c only feeds addresses (safe runtime)
    // ---- QK^T for chunk: wave w owns stiles c*8 + w*2..+1 (keys w*32..+31) ----
    f32x4 sacc[QT][NQS][2] = {};
#pragma unroll 1
    for (int kc = 0; kc < D / 32; ++kc) {
      bf16x8 kf[2];
#pragma unroll
      for (int st = 0; st < 2; ++st)
        kf[st] = *(const bf16x8*)(
            Kp + ((size_t)kc * 64 + c * 8 + w * 2 + st) * 512 + lane * 8);
      bf16x8 qf[QT][NQS];
#pragma unroll
      for (int qt = 0; qt < QT; ++qt)
#pragma unroll
        for (int s2 = 0; s2 < NQS; ++s2)
          qf[qt][s2] = *(const bf16x8*)(
              qsh + (s2 * NR + qt * 16 + l15) * QP + kc * 32 + lq * 8);
      __builtin_amdgcn_s_setprio(1);
#pragma unroll
      for (int st = 0; st < 2; ++st)
#pragma unroll
        for (int qt = 0; qt < QT; ++qt)
#pragma unroll
          for (int s2 = 0; s2 < NQS; ++s2)
            sacc[qt][s2][st] = __builtin_amdgcn_mfma_f32_16x16x32_bf16(
                qf[qt][s2], kf[st], sacc[qt][s2][st], 0, 0, 0);
      __builtin_amdgcn_s_setprio(0);
    }
    // ---- exp2 + running sums + strip write (unnormalized weights) ----
#pragma unroll
    for (int qt = 0; qt < QT; ++qt)
#pragma unroll
      for (int s2 = 0; s2 < NQS; ++s2)
#pragma unroll
        for (int st = 0; st < 2; ++st)
#pragma unroll
          for (int r = 0; r < 4; ++r) {
            const float e = exp2f(sacc[qt][s2][st][r]);
            psum[qt][s2][r] += e;
            ssh[(s2 * NR + qt * 16 + lq * 4 + r) * SP + (w * 2 + st) * 16 + l15] =
                (unsigned short)f2b(e);
          }
    __syncthreads();
    // ---- PV: V loaded once, serves all Q-sets ----
#pragma unroll 1
    for (int sc2 = 0; sc2 < 4; sc2 += 2) {
      bf16x8 vb[2][DT], pa[2][QT][NQS];
#pragma unroll
      for (int u = 0; u < 2; ++u) {
#pragma unroll
        for (int dt = 0; dt < DT; ++dt)
          vb[u][dt] = *(const bf16x8*)(
              Vp + ((size_t)(c * 4 + sc2 + u) * (D / 16) + w * DT + dt) * 512 + lane * 8);
#pragma unroll
        for (int qt = 0; qt < QT; ++qt)
#pragma unroll
          for (int s2 = 0; s2 < NQS; ++s2)
            pa[u][qt][s2] = *(const bf16x8*)(
                ssh + (s2 * NR + qt * 16 + l15) * SP + (sc2 + u) * 32 + lq * 8);
      }
      __builtin_amdgcn_s_setprio(1);
#pragma unroll
      for (int u = 0; u < 2; ++u)
#pragma unroll
        for (int qt = 0; qt < QT; ++qt)
#pragma unroll
          for (int s2 = 0; s2 < NQS; ++s2)
#pragma unroll
            for (int dt = 0; dt < DT; ++dt)
              acc_o[qt][s2][dt] = __builtin_amdgcn_mfma_f32_16x16x32_bf16(
                  pa[u][qt][s2], vb[u][dt], acc_o[qt][s2][dt], 0, 0, 0);
      __builtin_amdgcn_s_setprio(0);
    }
    __syncthreads();
  }

  // ---- final row sums: reduce over 16 key-lanes, then over 4 waves ----
#pragma unroll
  for (int o = 1; o < 16; o <<= 1)
#pragma unroll
    for (int qt = 0; qt < QT; ++qt)
#pragma unroll
      for (int s2 = 0; s2 < NQS; ++s2)
#pragma unroll
        for (int r = 0; r < 4; ++r)
          psum[qt][s2][r] += __shfl_xor(psum[qt][s2][r], o);
  if (l15 == 0) {
#pragma unroll
    for (int qt = 0; qt < QT; ++qt)
#pragma unroll
      for (int s2 = 0; s2 < NQS; ++s2)
#pragma unroll
        for (int r = 0; r < 4; ++r)
          red[((s2 * QT + qt) * 4 + w) * 16 + lq * 4 + r] = psum[qt][s2][r];
  }
  __syncthreads();
  float inv[QT][NQS][4];
#pragma unroll
  for (int qt = 0; qt < QT; ++qt)
#pragma unroll
    for (int s2 = 0; s2 < NQS; ++s2)
#pragma unroll
      for (int r = 0; r < 4; ++r) {
        const float* rp = red + ((s2 * QT + qt) * 4) * 16 + lq * 4 + r;
        inv[qt][s2][r] = 1.f / (rp[0] + rp[16] + rp[32] + rp[48]);
      }

  // ---- epilogue: normalize + write ----
  if constexpr (NQS == 2) {
    float* base = Rp + (size_t)side * (4096 * 512);
#pragma unroll
    for (int qt = 0; qt < QT; ++qt)
#pragma unroll
      for (int dt = 0; dt < DT; ++dt)
#pragma unroll
        for (int r = 0; r < 4; ++r) {
          const int q = qb + qt * 16 + lq * 4 + r;
          const int d = w * (DT * 16) + dt * 16 + l15;
          base[(rowb + q) * 512 + colo + d] =
              acc_o[qt][0][dt][r] * inv[qt][0][r] + acc_o[qt][1][dt][r] * inv[qt][1][r];
        }
  } else {
#pragma unroll
    for (int qt = 0; qt < QT; ++qt)
#pragma unroll
      for (int dt = 0; dt < DT; ++dt)
#pragma unroll
        for (int r = 0; r < 4; ++r) {
          const int q = qb + qt * 16 + lq * 4 + r;
          const int d = w * (DT * 16) + dt * 16 + l15;
          R[(rowb + q) * 512 + colo + d] =
              (unsigned short)f2b(acc_o[qt][0][dt][r] * inv[qt][0][r] * post_scale);
        }
  }
}

// ---- out = LayerNorm(G0 + G1 + res) * g + b  (f32 out + optional bf16 out) ----
__global__ __launch_bounds__(256) void ln_kernel(
    const float* __restrict__ G0, const float* __restrict__ G1,
    const float* __restrict__ res, const float* __restrict__ g,
    const float* __restrict__ b, float* __restrict__ out,
    unsigned short* __restrict__ outb) {
  __shared__ float sh[4];
  const int row = blockIdx.x, tid = threadIdx.x;
  const size_t off = (size_t)row * 512;
  const float x0 = G0[off + tid] + G1[off + tid] + res[off + tid];
  const float x1 = G0[off + tid + 256] + G1[off + tid + 256] + res[off + tid + 256];
  const float mean = block_sum1(x0 + x1, sh) * (1.0f / 512.0f);
  const float d0 = x0 - mean, d1 = x1 - mean;
  const float var = block_sum1(d0 * d0 + d1 * d1, sh) * (1.0f / 512.0f);
  const float inv = rsqrtf(var + 1e-5f);
  const float y0 = d0 * inv * g[tid] + b[tid];
  const float y1 = d1 * inv * g[tid + 256] + b[tid + 256];
  out[off + tid] = y0;
  out[off + tid + 256] = y1;
  if (outb) {
    outb[off + tid] = (unsigned short)f2b(y0);
    outb[off + tid + 256] = (unsigned short)f2b(y1);
  }
}

extern "C" void kernel_launch(void* const* d_in, const int* in_sizes, int n_in,
                              void* d_out, int out_size, void* d_ws, size_t ws_size,
                              hipStream_t stream) {
  typedef unsigned short ushort_t;
  const float* cx   = (const float*)d_in[0];
  const float* cy   = (const float*)d_in[1];
  const float* txp  = (const float*)d_in[2];
  const float* in_W = (const float*)d_in[3];
  const float* in_b = (const float*)d_in[4];
  const float* cx_W = (const float*)d_in[5];
  const float* cx_b = (const float*)d_in[6];
  const float* tx_W = (const float*)d_in[7];
  const float* tx_b = (const float*)d_in[8];
  const float* sWk  = (const float*)d_in[9];
  const float* sWv  = (const float*)d_in[10];
  const float* sWq  = (const float*)d_in[11];
  const float* sWf  = (const float*)d_in[12];
  const float* sbf  = (const float*)d_in[13];
  const float* sg   = (const float*)d_in[14];
  const float* sb   = (const float*)d_in[15];
  const float* aWk  = (const float*)d_in[16];
  const float* aWv  = (const float*)d_in[17];
  const float* aWq  = (const float*)d_in[18];
  const float* aWf  = (const float*)d_in[19];
  const float* abf  = (const float*)d_in[20];
  const float* ag   = (const float*)d_in[21];
  const float* ab   = (const float*)d_in[22];

  const size_t MB = 1024 * 1024;
  char* ws = (char*)d_ws;
  float*    E     = (float*)(ws + 0 * MB);       // 8 MB
  ushort_t* Ebf   = (ushort_t*)(ws + 8 * MB);    // 4 MB
  float*    QA    = (float*)(ws + 12 * MB);      // 8 MB
  ushort_t* QAbf  = (ushort_t*)(ws + 20 * MB);   // 4 MB
  ushort_t* Rbbf  = (ushort_t*)(ws + 24 * MB);   // 4 MB
  float*    Rp    = (float*)(ws + 28 * MB);      // 16 MB attn f32 partials (2 sides)
  float*    G0    = (float*)(ws + 44 * MB);      // 8 MB Wf partial kz=0
  ushort_t* KfrA  = (ushort_t*)(ws + 52 * MB);   // 4 MB
  ushort_t* VfrA  = (ushort_t*)(ws + 56 * MB);   // 4 MB
  ushort_t* QbfA  = (ushort_t*)(ws + 60 * MB);   // 4 MB
  ushort_t* KfrB  = (ushort_t*)(ws + 64 * MB);   // 4 MB
  ushort_t* VfrB  = (ushort_t*)(ws + 68 * MB);   // 4 MB
  ushort_t* QbfB  = (ushort_t*)(ws + 72 * MB);   // 4 MB
  float*    G1    = (float*)(ws + 84 * MB);      // 8 MB Wf partial kz=1
  ushort_t* Wkvqt0 = (ushort_t*)(ws + 92 * MB);  // 2 x 1.5 MB
  ushort_t* Wkvqt[2] = {Wkvqt0, Wkvqt0 + 786432};
  ushort_t* Wft0   = (ushort_t*)(ws + 95 * MB);  // 2 x 1 MB
  ushort_t* Wft[2] = {Wft0, Wft0 + 524288};
  ushort_t* aWvt0  = (ushort_t*)(ws + 97 * MB);  // 2 x 0.5 MB
  ushort_t* aWvt[2] = {aWvt0, aWvt0 + 262144};
  ushort_t* aWqt1  = (ushort_t*)(ws + 98 * MB);  // 0.5 MB
  ushort_t* aWft0  = (ushort_t*)(ws + 99 * MB);  // 2 x 1 MB
  ushort_t* aWft[2] = {aWft0, aWft0 + 524288};
  float*    Ttab   = (float*)(ws + 101 * MB);

  float* T_sc[2][3];
  for (int i = 0; i < 2; ++i)
    for (int w = 0; w < 3; ++w) T_sc[i][w] = Ttab + (size_t)(i * 3 + w) * 2048;
  float* T_cak[2] = {Ttab + 12288, Ttab + 12288 + 1024};
  float* T_caq0 = Ttab + 14336;

  const dim3 tb(32, 8);

  // ---- prep: fused weight transposes + projection tables ----
  transpose_kvq_kernel<<<dim3(16, 16, 9), tb, 0, stream>>>(sWk, sWv, sWq, aWv, aWq,
                                                           Wkvqt0, aWvt0, aWqt1);
  transpose_f_kernel<<<dim3(16, 32, 4), tb, 0, stream>>>(sWf, aWf, Wft0, aWft0);
  tabproj9_kernel<<<dim3(512, 9), 256, 0, stream>>>(in_W, in_b, cx_W, cx_b, tx_W, tx_b,
                                                    sWk, sWv, sWq, aWk, aWq, Ttab);

  // ---- initial activations ----
  affine3_kernel<<<4096, 512, 0, stream>>>(cx, cy, 0, in_W, in_b, E, Ebf);
  rank1_kernel<<<4096, 512, 0, stream>>>(txp, tx_W, tx_b, QA, QAbf);

  // ---- 8 self/cross encoder layers ----
  for (int p = 0; p < 4; ++p) {
    for (int i = 0; i < 2; ++i) {
      gemm_pack_kernel<0><<<dim3(24, 32), 256, 0, stream>>>(Ebf, Wkvqt[i], KfrA, VfrA,
                                                            QbfA);
      const float* F0 = nullptr;
      const float* F1 = nullptr;
      if (p > 0) {
        affine3kq_kernel<<<4096, 128, 0, stream>>>(cx, cy, p, T_sc[i][0], T_sc[i][2],
                                                   KfrB, QbfB);
        affine3v_frag_kernel<<<dim3(32, 8, 8), tb, 0, stream>>>(cx, cy, p, T_sc[i][1],
                                                                VfrB);
        attn_mfma_kernel<256, 2, 2><<<512, 256, 0, stream>>>(
            QbfA, QbfB, KfrA, KfrB, VfrA, VfrB, 1.0f, 2, nullptr, Rp);
        F0 = Rp; F1 = Rp + 4096 * 512;
      } else {
        // x2 is x: 4 identical sdpa terms -> 4 * sdpa(sQ,sK,sV)
        attn_mfma_kernel<256, 1, 2><<<256, 256, 0, stream>>>(
            QbfA, QbfA, KfrA, KfrA, VfrA, VfrA, 4.0f, 2, Rbbf, nullptr);
      }
      gemm_wf_kernel<<<dim3(8, 32, 2), 256, 0, stream>>>(
          Ebf, Rbbf, F0, F1, Wft[i], sbf + (size_t)i * 512, G0, G1);
      ln_kernel<<<4096, 256, 0, stream>>>(G0, G1, E, sg + (size_t)i * 512,
                                          sb + (size_t)i * 512, E, Ebf);
    }
  }

  // ---- 2 cross-attention decoder layers (nh=4, D=128) ----
  for (int i = 0; i < 2; ++i) {
    rank1_pack_kernel<<<4096, 64, 0, stream>>>(cx, T_cak[i], KfrA, 0);
    gemm_pack_kernel<1><<<dim3(8, 32), 256, 0, stream>>>(Ebf, aWvt[i], nullptr, VfrA,
                                                         nullptr);
    if (i == 0) {
      rank1_pack_kernel<<<4096, 64, 0, stream>>>(txp, T_caq0, QbfB, 1);
    } else {
      gemm_pack_kernel<2><<<dim3(8, 32), 256, 0, stream>>>(QAbf, aWqt1, nullptr, nullptr,
                                                           QbfB);
    }
    attn_mfma_kernel<128, 1, 2><<<512, 256, 0, stream>>>(
        QbfB, QbfB, KfrA, KfrA, VfrA, VfrA, 1.0f, 4, Rbbf, nullptr);
    gemm_wf_kernel<<<dim3(8, 32, 2), 256, 0, stream>>>(
        QAbf, Rbbf, nullptr, nullptr, aWft[i], abf + (size_t)i * 512, G0, G1);
    ln_kernel<<<4096, 256, 0, stream>>>(G0, G1, QA, ag + (size_t)i * 512,
                                        ab + (size_t)i * 512,
                                        (i == 1) ? (float*)d_out : QA,
                                        (i == 1) ? nullptr : QAbf);
  }
  (void)in_sizes; (void)n_in; (void)out_size; (void)ws_size;
}

// Round 10
// 1049.927 us; speedup vs baseline: 1.0622x; 1.0622x over previous
//
#include <hip/hip_runtime.h>

#define DEVINL __device__ __forceinline__

typedef short bf16x8 __attribute__((ext_vector_type(8)));
typedef float f32x4 __attribute__((ext_vector_type(4)));

#define LOG2E 1.44269504088896f

DEVINL unsigned f2b(float f) {  // f32 -> bf16 bits (round to nearest even)
  unsigned u = __float_as_uint(f);
  u = (u + 0x7FFFu + ((u >> 16) & 1u)) >> 16;
  return u & 0xFFFFu;
}
DEVINL uint4 pack8(const float* v) {
  uint4 u;
  u.x = f2b(v[0]) | (f2b(v[1]) << 16);
  u.y = f2b(v[2]) | (f2b(v[3]) << 16);
  u.z = f2b(v[4]) | (f2b(v[5]) << 16);
  u.w = f2b(v[6]) | (f2b(v[7]) << 16);
  return u;
}

// ---------------- reduction helpers ----------------
DEVINL float4 block_sum4(float4 v, float4* sh) {
  const int lane = threadIdx.x & 63, wid = threadIdx.x >> 6;
#pragma unroll
  for (int o = 32; o; o >>= 1) {
    v.x += __shfl_down(v.x, o);
    v.y += __shfl_down(v.y, o);
    v.z += __shfl_down(v.z, o);
    v.w += __shfl_down(v.w, o);
  }
  __syncthreads();
  if (lane == 0) sh[wid] = v;
  __syncthreads();
  float4 a = sh[0], b = sh[1], c = sh[2], d = sh[3], r;
  r.x = a.x + b.x + c.x + d.x;
  r.y = a.y + b.y + c.y + d.y;
  r.z = a.z + b.z + c.z + d.z;
  r.w = a.w + b.w + c.w + d.w;
  return r;
}
DEVINL float block_sum1(float v, float* sh) {
  const int lane = threadIdx.x & 63, wid = threadIdx.x >> 6;
#pragma unroll
  for (int o = 32; o; o >>= 1) v += __shfl_down(v, o);
  __syncthreads();
  if (lane == 0) sh[wid] = v;
  __syncthreads();
  return sh[0] + sh[1] + sh[2] + sh[3];
}

// ---- fused table projections (9 jobs via blockIdx.y) ----
// Q-producing tables fold LOG2E (softmax uses exp2).
__global__ __launch_bounds__(256) void tabproj9_kernel(
    const float* __restrict__ in_W, const float* __restrict__ in_b,
    const float* __restrict__ cx_W, const float* __restrict__ cx_b,
    const float* __restrict__ tx_W, const float* __restrict__ tx_b,
    const float* __restrict__ sWk, const float* __restrict__ sWv,
    const float* __restrict__ sWq, const float* __restrict__ aWk,
    const float* __restrict__ aWq, float* __restrict__ Ttab) {
  const int z = blockIdx.y;
  const float* V;
  const float* bias;
  const float* W;
  float* P;
  int nvec;
  float scl = 1.f;
  if (z < 6) {
    V = in_W; bias = in_b; nvec = 3;
    const int i = z / 3, wsel = z % 3;
    W = (wsel == 0 ? sWk : wsel == 1 ? sWv : sWq) + (size_t)i * 262144;
    P = Ttab + (size_t)z * 2048;
    if (wsel == 2) scl = 0.0625f * LOG2E;
  } else if (z < 8) {
    V = cx_W; bias = cx_b; nvec = 1;
    W = aWk + (size_t)(z - 6) * 262144;
    P = Ttab + 12288 + (size_t)(z - 6) * 1024;
  } else {
    V = tx_W; bias = tx_b; nvec = 1;
    W = aWq; P = Ttab + 14336; scl = 0.08838834764831845f * LOG2E;
  }
  __shared__ float4 sh4[4];
  const int j = blockIdx.x, tid = threadIdx.x;
  float acc[4] = {0.f, 0.f, 0.f, 0.f};
  for (int kk = tid; kk < 512; kk += 256) {
    const float w = W[(size_t)kk * 512 + j];
    for (int v = 0; v < nvec; ++v) acc[v] += V[(size_t)v * 512 + kk] * w;
    acc[3] += bias[kk] * w;
  }
  float4 packed = make_float4(acc[0], acc[1], acc[2], acc[3]);
  packed = block_sum4(packed, sh4);
  if (tid == 0) {
    const float vals[4] = {packed.x * scl, packed.y * scl, packed.z * scl, packed.w * scl};
    for (int v = 0; v < nvec; ++v) P[(size_t)v * 512 + j] = vals[v];
    P[(size_t)nvec * 512 + j] = vals[3];
  }
}

// ---- fused weight transposes, K=512 (9 jobs via blockIdx.z); Q scaled w/ LOG2E ----
__global__ __launch_bounds__(256) void transpose_kvq_kernel(
    const float* __restrict__ sWk, const float* __restrict__ sWv,
    const float* __restrict__ sWq, const float* __restrict__ aWv,
    const float* __restrict__ aWq, unsigned short* __restrict__ Wkvqt0,
    unsigned short* __restrict__ aWvt0, unsigned short* __restrict__ aWqt1) {
  const int z = blockIdx.z;
  const float* src;
  unsigned short* dst;
  float scl = 1.f;
  if (z < 6) {
    const int i = z / 3, wsel = z % 3;
    src = (wsel == 0 ? sWk : wsel == 1 ? sWv : sWq) + (size_t)i * 262144;
    dst = Wkvqt0 + (size_t)i * 786432 + (size_t)wsel * 262144;
    if (wsel == 2) scl = 0.0625f * LOG2E;
  } else if (z < 8) {
    src = aWv + (size_t)(z - 6) * 262144;
    dst = aWvt0 + (size_t)(z - 6) * 262144;
  } else {
    src = aWq + 262144; dst = aWqt1; scl = 0.08838834764831845f * LOG2E;
  }
  __shared__ float tile[32][33];
  const int n0 = blockIdx.x * 32, k0 = blockIdx.y * 32;
  const int tx = threadIdx.x, ty = threadIdx.y;  // 32 x 8
#pragma unroll
  for (int r = 0; r < 4; ++r)
    tile[ty + 8 * r][tx] = src[(size_t)(k0 + ty + 8 * r) * 512 + n0 + tx];
  __syncthreads();
#pragma unroll
  for (int r = 0; r < 4; ++r)
    dst[(size_t)(n0 + ty + 8 * r) * 512 + k0 + tx] =
        (unsigned short)f2b(scl * tile[tx][ty + 8 * r]);
}

// ---- fused weight transposes, K=1024 (4 jobs via blockIdx.z) ----
__global__ __launch_bounds__(256) void transpose_f_kernel(
    const float* __restrict__ sWf, const float* __restrict__ aWf,
    unsigned short* __restrict__ Wft0, unsigned short* __restrict__ aWft0) {
  const int z = blockIdx.z;
  const float* src = (z < 2 ? sWf + (size_t)z * 524288 : aWf + (size_t)(z - 2) * 524288);
  unsigned short* dst =
      (z < 2 ? Wft0 + (size_t)z * 524288 : aWft0 + (size_t)(z - 2) * 524288);
  __shared__ float tile[32][33];
  const int n0 = blockIdx.x * 32, k0 = blockIdx.y * 32;
  const int tx = threadIdx.x, ty = threadIdx.y;  // 32 x 8
#pragma unroll
  for (int r = 0; r < 4; ++r)
    tile[ty + 8 * r][tx] = src[(size_t)(k0 + ty + 8 * r) * 512 + n0 + tx];
  __syncthreads();
#pragma unroll
  for (int r = 0; r < 4; ++r)
    dst[(size_t)(n0 + ty + 8 * r) * 1024 + k0 + tx] =
        (unsigned short)f2b(tile[tx][ty + 8 * r]);
}

// ---- cross-side encoder K/Q: rank-3 affine -> Kfr + Qbf (rows) ----
__global__ __launch_bounds__(128) void affine3kq_kernel(
    const float* __restrict__ cx, const float* __restrict__ cy, int sel,
    const float* __restrict__ TK, const float* __restrict__ TQ,
    unsigned short* __restrict__ Kfr, unsigned short* __restrict__ Qbf) {
  const int row = blockIdx.x;
  const int b = row >> 10, s = row & 1023;
  const float x = cx[row];
  const float* y = cy + (size_t)row * 8 + 2 * sel;
  const float y0 = y[0], y1 = y[1];
  const int t = threadIdx.x;
  const bool isQ = t >= 64;
  const int c = t & 63;
  const int h = c >> 5;
  const int d0 = (c & 31) * 8;
  const float* T = isQ ? TQ : TK;
  float v[8];
#pragma unroll
  for (int j = 0; j < 8; ++j) {
    const int col = h * 256 + d0 + j;
    v[j] = x * T[col] + y0 * T[512 + col] + y1 * T[1024 + col] + T[1536 + col];
  }
  const uint4 u = pack8(v);
  const int bh = b * 2 + h;
  if (isQ) {
    *(uint4*)(Qbf + ((size_t)bh * 1024 + s) * 256 + d0) = u;
  } else {
    const int kc = d0 >> 5;
    const int lane = ((d0 & 31) >> 3) * 16 + (s & 15);
    *(uint4*)(Kfr + ((size_t)(bh * 8 + kc) * 64 + (s >> 4)) * 512 + lane * 8) = u;
  }
}

// ---- cross-side encoder V: compute rank-3 affine per 32x32 tile -> Vfr direct ----
__global__ __launch_bounds__(256) void affine3v_frag_kernel(
    const float* __restrict__ cx, const float* __restrict__ cy, int sel,
    const float* __restrict__ TV, unsigned short* __restrict__ Vfr) {
  __shared__ float tile[32][33];
  const int s0 = blockIdx.x * 32, d0 = blockIdx.y * 32;
  const int bh = blockIdx.z;
  const int b = bh >> 1, h = bh & 1;
  const int tx = threadIdx.x, ty = threadIdx.y;  // 32 x 8
  const int col = h * 256 + d0 + tx;
  const float tv0 = TV[col], tv1 = TV[512 + col], tv2 = TV[1024 + col],
              tv3 = TV[1536 + col];
#pragma unroll
  for (int r = 0; r < 4; ++r) {
    const int row = b * 1024 + s0 + ty + 8 * r;
    const float x = cx[row];
    const float* y = cy + (size_t)row * 8 + 2 * sel;
    tile[ty + 8 * r][tx] = x * tv0 + y[0] * tv1 + y[1] * tv2 + tv3;
  }
  __syncthreads();
  const int idx = ty * 32 + tx;
  if (idx < 128) {
    const int dj = idx & 31, sch = idx >> 5;
    float v[8];
#pragma unroll
    for (int jj = 0; jj < 8; ++jj) v[jj] = tile[sch * 8 + jj][dj];
    const uint4 u = pack8(v);
    const int sc = s0 >> 5;
    const int dtile = (d0 + dj) >> 4;
    const int lane = sch * 16 + (dj & 15);
    *(uint4*)(Vfr + ((size_t)(bh * 32 + sc) * 16 + dtile) * 512 + lane * 8) = u;
  }
}

// ---- decoder rank-1 producers (nh=4, D=128): T rows [0]=w, [1]=bias ----
__global__ __launch_bounds__(64) void rank1_pack_kernel(
    const float* __restrict__ x, const float* __restrict__ T,
    unsigned short* __restrict__ dst, int isQ) {
  const int row = blockIdx.x;
  const int b = row >> 10, s = row & 1023;
  const float xv = x[row];
  const int c = threadIdx.x;        // 64 chunks of 8
  const int h = c >> 4;             // 16 chunks per head
  const int d0 = (c & 15) * 8;
  float v[8];
#pragma unroll
  for (int j = 0; j < 8; ++j) {
    const int col = h * 128 + d0 + j;
    v[j] = xv * T[col] + T[512 + col];
  }
  const uint4 u = pack8(v);
  const int bh = b * 4 + h;
  if (isQ) {
    *(uint4*)(dst + ((size_t)bh * 1024 + s) * 128 + d0) = u;
  } else {
    const int kc = d0 >> 5;
    const int lane = ((d0 & 31) >> 3) * 16 + (s & 15);
    *(uint4*)(dst + ((size_t)(bh * 4 + kc) * 64 + (s >> 4)) * 512 + lane * 8) = u;
  }
}

// ---- out[r,:] = cx[r]*W3[0,:] + y0*W3[1,:] + y1*W3[2,:] + bias (f32 + bf16) ----
__global__ __launch_bounds__(512) void affine3_kernel(
    const float* __restrict__ cx, const float* __restrict__ cy, int sel,
    const float* __restrict__ W3, const float* __restrict__ bias,
    float* __restrict__ out, unsigned short* __restrict__ outb) {
  const int r = blockIdx.x, j = threadIdx.x;
  const float* y = cy + (size_t)r * 8 + 2 * sel;
  const float v = cx[r] * W3[j] + y[0] * W3[512 + j] + y[1] * W3[1024 + j] + bias[j];
  if (out) out[(size_t)r * 512 + j] = v;
  if (outb) outb[(size_t)r * 512 + j] = (unsigned short)f2b(v);
}

// ---- out[r,:] = x[r]*w + b ----
__global__ __launch_bounds__(512) void rank1_kernel(
    const float* __restrict__ x, const float* __restrict__ w,
    const float* __restrict__ b, float* __restrict__ out,
    unsigned short* __restrict__ outb) {
  const int r = blockIdx.x, j = threadIdx.x;
  const float v = x[r] * w[j] + b[j];
  if (out) out[(size_t)r * 512 + j] = v;
  if (outb) outb[(size_t)r * 512 + j] = (unsigned short)f2b(v);
}

// ------------- split-K Wf GEMM (double-buffered): two K-halves via blockIdx.z ----
__global__ __launch_bounds__(256) void gemm_wf_kernel(
    const unsigned short* __restrict__ A0, const unsigned short* __restrict__ A1,
    const float* __restrict__ F0, const float* __restrict__ F1,
    const unsigned short* __restrict__ Wt, const float* __restrict__ bias,
    float* __restrict__ C0, float* __restrict__ C1) {
  constexpr int BM = 128, BN = 64, BK = 32, LDP = 40, K = 512, N = 512;
  __shared__ unsigned short As[2][BM * LDP];
  __shared__ unsigned short Bs[2][BN * LDP];
  const int kz = blockIdx.z;
  const int tid = threadIdx.x;
  const int lane = tid & 63, w = tid >> 6;
  const int bm = blockIdx.y * BM, bn = blockIdx.x * BN;
  const int wm = (w & 1) * 64, wn = (w >> 1) * 32;
  const int l15 = lane & 15, lq = lane >> 4;
  const int ar = tid >> 1, ac = (tid & 1) * 16;
  const int br = tid >> 2, bc = (tid & 3) * 8;
  const unsigned short* A = kz ? A1 : A0;
  const bool useF = (kz != 0) && (F0 != nullptr);
  const size_t arow = (size_t)(bm + ar) * 512;
  const size_t brow = (size_t)(bn + br) * 1024 + (size_t)kz * 512;
  f32x4 acc[4][2] = {};
  uint4 ra0, ra1, rb0;
#define GLOAD(k0_)                                                          \
  do {                                                                      \
    if (useF) {                                                             \
      const float* p0 = F0 + arow + (k0_) + ac;                             \
      const float* p1 = F1 + arow + (k0_) + ac;                             \
      float s[16];                                                          \
      const float4 x0 = *(const float4*)p0, x1 = *(const float4*)(p0 + 4);  \
      const float4 x2 = *(const float4*)(p0 + 8), x3 = *(const float4*)(p0 + 12); \
      const float4 y0 = *(const float4*)p1, y1 = *(const float4*)(p1 + 4);  \
      const float4 y2 = *(const float4*)(p1 + 8), y3 = *(const float4*)(p1 + 12); \
      s[0] = x0.x + y0.x; s[1] = x0.y + y0.y; s[2] = x0.z + y0.z; s[3] = x0.w + y0.w; \
      s[4] = x1.x + y1.x; s[5] = x1.y + y1.y; s[6] = x1.z + y1.z; s[7] = x1.w + y1.w; \
      s[8] = x2.x + y2.x; s[9] = x2.y + y2.y; s[10] = x2.z + y2.z; s[11] = x2.w + y2.w; \
      s[12] = x3.x + y3.x; s[13] = x3.y + y3.y; s[14] = x3.z + y3.z; s[15] = x3.w + y3.w; \
      ra0 = pack8(s); ra1 = pack8(s + 8);                                   \
    } else {                                                                \
      ra0 = *(const uint4*)(A + arow + (k0_) + ac);                         \
      ra1 = *(const uint4*)(A + arow + (k0_) + ac + 8);                     \
    }                                                                       \
    rb0 = *(const uint4*)(Wt + brow + (k0_) + bc);                          \
  } while (0)
  GLOAD(0);
  *(uint4*)(As[0] + ar * LDP + ac) = ra0;
  *(uint4*)(As[0] + ar * LDP + ac + 8) = ra1;
  *(uint4*)(Bs[0] + br * LDP + bc) = rb0;
  __syncthreads();
  int buf = 0;
  for (int k0 = 0; k0 < K; k0 += BK) {
    const bool more = (k0 + BK) < K;
    if (more) GLOAD(k0 + BK);
    bf16x8 af[4], bfr[2];
#pragma unroll
    for (int mt = 0; mt < 4; ++mt)
      af[mt] = *(const bf16x8*)(As[buf] + (wm + mt * 16 + l15) * LDP + lq * 8);
#pragma unroll
    for (int nt = 0; nt < 2; ++nt)
      bfr[nt] = *(const bf16x8*)(Bs[buf] + (wn + nt * 16 + l15) * LDP + lq * 8);
#pragma unroll
    for (int mt = 0; mt < 4; ++mt)
#pragma unroll
      for (int nt = 0; nt < 2; ++nt)
        acc[mt][nt] =
            __builtin_amdgcn_mfma_f32_16x16x32_bf16(af[mt], bfr[nt], acc[mt][nt], 0, 0, 0);
    if (more) {
      *(uint4*)(As[buf ^ 1] + ar * LDP + ac) = ra0;
      *(uint4*)(As[buf ^ 1] + ar * LDP + ac + 8) = ra1;
      *(uint4*)(Bs[buf ^ 1] + br * LDP + bc) = rb0;
    }
    __syncthreads();
    buf ^= 1;
  }
#undef GLOAD
  float* C = kz ? C1 : C0;
#pragma unroll
  for (int nt = 0; nt < 2; ++nt) {
    const int col = bn + wn + nt * 16 + l15;
    const float bv = (kz && bias) ? bias[col] : 0.f;
#pragma unroll
    for (int mt = 0; mt < 4; ++mt) {
#pragma unroll
      for (int r = 0; r < 4; ++r) {
        const int row = bm + wm + mt * 16 + lq * 4 + r;
        C[(size_t)row * N + col] = acc[mt][nt][r] + bv;
      }
    }
  }
}

// ------- MFMA GEMM with fused frag-pack epilogue (K=512, single A) ---------------
// MODE 0: N=1536 = K|V|Q sections, nh=2, D=256 -> Kfr, Vfr, Qbf
// MODE 1: N=512  = V only, nh=4, D=128 -> Vfr
// MODE 2: N=512  = Q only, nh=4, D=128 -> Qbf (weights pre-scaled)
template <int MODE>
__global__ __launch_bounds__(256) void gemm_pack_kernel(
    const unsigned short* __restrict__ A0, const unsigned short* __restrict__ Wt,
    unsigned short* __restrict__ Kfr, unsigned short* __restrict__ Vfr,
    unsigned short* __restrict__ Qbf) {
  constexpr int BM = 128, BN = 64, BK = 32, LDP = 40, K = 512;
  __shared__ unsigned short As[2][BM * LDP];
  __shared__ unsigned short Bs[2][BN * LDP];
  const int tid = threadIdx.x;
  const int lane = tid & 63, w = tid >> 6;
  const int bm = blockIdx.y * BM, bn = blockIdx.x * BN;
  const int wm = (w & 1) * 64, wn = (w >> 1) * 32;
  const int l15 = lane & 15, lq = lane >> 4;
  const int ar = tid >> 1, ac = (tid & 1) * 16;
  const int br = tid >> 2, bc = (tid & 3) * 8;
  f32x4 acc[4][2] = {};
  uint4 ra0 = *(const uint4*)(A0 + (size_t)(bm + ar) * K + ac);
  uint4 ra1 = *(const uint4*)(A0 + (size_t)(bm + ar) * K + ac + 8);
  uint4 rb0 = *(const uint4*)(Wt + (size_t)(bn + br) * K + bc);
  *(uint4*)(As[0] + ar * LDP + ac) = ra0;
  *(uint4*)(As[0] + ar * LDP + ac + 8) = ra1;
  *(uint4*)(Bs[0] + br * LDP + bc) = rb0;
  __syncthreads();
  int buf = 0;
  for (int k0 = 0; k0 < K; k0 += BK) {
    const bool more = (k0 + BK) < K;
    if (more) {
      ra0 = *(const uint4*)(A0 + (size_t)(bm + ar) * K + k0 + BK + ac);
      ra1 = *(const uint4*)(A0 + (size_t)(bm + ar) * K + k0 + BK + ac + 8);
      rb0 = *(const uint4*)(Wt + (size_t)(bn + br) * K + k0 + BK + bc);
    }
    bf16x8 af[4], bfr[2];
#pragma unroll
    for (int mt = 0; mt < 4; ++mt)
      af[mt] = *(const bf16x8*)(As[buf] + (wm + mt * 16 + l15) * LDP + lq * 8);
#pragma unroll
    for (int nt = 0; nt < 2; ++nt)
      bfr[nt] = *(const bf16x8*)(Bs[buf] + (wn + nt * 16 + l15) * LDP + lq * 8);
#pragma unroll
    for (int mt = 0; mt < 4; ++mt)
#pragma unroll
      for (int nt = 0; nt < 2; ++nt)
        acc[mt][nt] =
            __builtin_amdgcn_mfma_f32_16x16x32_bf16(af[mt], bfr[nt], acc[mt][nt], 0, 0, 0);
    if (more) {
      *(uint4*)(As[buf ^ 1] + ar * LDP + ac) = ra0;
      *(uint4*)(As[buf ^ 1] + ar * LDP + ac + 8) = ra1;
      *(uint4*)(Bs[buf ^ 1] + br * LDP + bc) = rb0;
    }
    __syncthreads();
    buf ^= 1;
  }
  // ---- fused pack epilogue ----
  const int b = bm >> 10;
  const int s0base = (bm & 1023) + wm + lq * 4;
#pragma unroll
  for (int nt = 0; nt < 2; ++nt) {
    const int col = bn + wn + nt * 16 + l15;
    int sec, h, d, nh2, Dv;
    if constexpr (MODE == 0) {
      sec = col >> 9; const int c = col & 511; h = c >> 8; d = c & 255; nh2 = 2; Dv = 256;
    } else if constexpr (MODE == 1) {
      sec = 1; h = col >> 7; d = col & 127; nh2 = 4; Dv = 128;
    } else {
      sec = 2; h = col >> 7; d = col & 127; nh2 = 4; Dv = 128;
    }
    const int bh = b * nh2 + h;
#pragma unroll
    for (int mt = 0; mt < 4; ++mt) {
      const int s0 = s0base + mt * 16;
      const float* a = (const float*)&acc[mt][nt];
      if (sec == 2) {                           // Q: [bh][s][Dv]
        unsigned short* q = Qbf + ((size_t)bh * 1024 + s0) * Dv + d;
#pragma unroll
        for (int r = 0; r < 4; ++r) q[(size_t)r * Dv] = (unsigned short)f2b(a[r]);
      } else if (sec == 0) {                    // K frag
        unsigned short* kp = Kfr +
            ((size_t)(bh * 8 + (d >> 5)) * 64 + (s0 >> 4)) * 512 +
            ((d & 31) >> 3) * 128 + (d & 7);
#pragma unroll
        for (int r = 0; r < 4; ++r)
          kp[((s0 & 15) + r) * 8] = (unsigned short)f2b(a[r]);
      } else {                                  // V frag
        unsigned short* vp = Vfr +
            ((size_t)(bh * 32 + (s0 >> 5)) * (Dv / 16) + (d >> 4)) * 512 +
            (((s0 >> 3) & 3) * 16 + (d & 15)) * 8 + (s0 & 7);
        uint2 u;
        u.x = f2b(a[0]) | (f2b(a[1]) << 16);
        u.y = f2b(a[2]) | (f2b(a[3]) << 16);
        *(uint2*)vp = u;
      }
    }
  }
}

// -------- MFMA flash attention, chunked keys + deferred normalization -----------
// Block = QT*16 q rows of one (b,head) vs ONE KV side, keys in 4 chunks of 256
// (R8-proven config: 256-key chunks keep MFMA bursts long; 128-key chunks
//  regressed -22% via shorter bursts + more barriers, R9 post-mortem).
// No-max softmax => O = (sum_k exp2(s) V) / (sum_k exp2(s)) accumulated per chunk;
// normalization applied once at the end.  NQS Q-sets share K and V loads.
// All register arrays statically indexed (rule #20); c/kc/sc feed addresses only.
// NQS==2: grid = 2*256, side = bx>>8; writes f32 partials to Rp.
// NQS==1: writes bf16 with post_scale.
template <int D, int NQS, int QT>
__global__ __launch_bounds__(256, 2) void attn_mfma_kernel(
    const unsigned short* __restrict__ Qa, const unsigned short* __restrict__ Qb,
    const unsigned short* __restrict__ KfrA, const unsigned short* __restrict__ KfrB,
    const unsigned short* __restrict__ VfrA, const unsigned short* __restrict__ VfrB,
    float post_scale, int nh, unsigned short* __restrict__ R,
    float* __restrict__ Rp) {
  constexpr int QP = D + 8;      // qsh pitch
  constexpr int SP = 256 + 8;    // strip pitch (chunk = 256 keys)
  constexpr int DT = D / 64;     // d-tiles per wave
  constexpr int NR = QT * 16;    // q rows per block
  const int tid = threadIdx.x;
  const int lane = tid & 63, w = tid >> 6;
  const int l15 = lane & 15, lq = lane >> 4;
  const int nbh = 4 * nh;
  int bx = blockIdx.x;
  int side = 0;
  if constexpr (NQS == 2) { side = bx >> 8; bx &= 255; }
  const int bh = bx % nbh;       // XCD-local (b,h): same-bh blocks share an XCD's L2
  const int qb = (bx / nbh) * NR;
  const int b = bh / nh, head = bh % nh;
  const size_t rowb = (size_t)b * 1024;
  const int colo = head * D;

  __shared__ unsigned short qsh[NQS * NR * QP];
  __shared__ unsigned short ssh[NQS * NR * SP];
  __shared__ float red[NQS * QT * 4 * 16];

  // ---- stage Q ----
  for (int idx = tid; idx < NQS * NR * (D / 8); idx += 256) {
    const int set = idx / (NR * (D / 8));
    const int rem = idx - set * NR * (D / 8);
    const int r = rem / (D / 8), ch = rem - r * (D / 8);
    const unsigned short* Q = set ? Qb : Qa;
    const uint4 u = *(const uint4*)(Q + ((size_t)bh * 1024 + qb + r) * D + ch * 8);
    *(uint4*)(qsh + (set * NR + r) * QP + ch * 8) = u;
  }
  __syncthreads();

  const unsigned short* Kp = (side ? KfrB : KfrA) + (size_t)bh * ((size_t)D * 1024);
  const unsigned short* Vp = (side ? VfrB : VfrA) + (size_t)bh * ((size_t)D * 1024);

  float psum[QT][NQS][4];
#pragma unroll
  for (int qt = 0; qt < QT; ++qt)
#pragma unroll
    for (int s2 = 0; s2 < NQS; ++s2)
#pragma unroll
      for (int r = 0; r < 4; ++r) psum[qt][s2][r] = 0.f;
  f32x4 acc_o[QT][NQS][DT] = {};

#pragma unroll 1
  for (int c = 0; c < 4; ++c) {        // c only feeds addresses (safe runtime)
    // ---- QK^T for chunk: wave w owns stiles c*16 + w*4 .. +3 (keys w*64..+63) ----
    f32x4 sacc[QT][NQS][4] = {};
#pragma unroll 1
    for (int kc = 0; kc < D / 32; ++kc) {
      bf16x8 kf[4];
#pragma unroll
      for (int st = 0; st < 4; ++st)
        kf[st] = *(const bf16x8*)(
            Kp + ((size_t)kc * 64 + c * 16 + w * 4 + st) * 512 + lane * 8);
      bf16x8 qf[QT][NQS];
#pragma unroll
      for (int qt = 0; qt < QT; ++qt)
#pragma unroll
        for (int s2 = 0; s2 < NQS; ++s2)
          qf[qt][s2] = *(const bf16x8*)(
              qsh + (s2 * NR + qt * 16 + l15) * QP + kc * 32 + lq * 8);
      __builtin_amdgcn_s_setprio(1);
#pragma unroll
      for (int st = 0; st < 4; ++st)
#pragma unroll
        for (int qt = 0; qt < QT; ++qt)
#pragma unroll
          for (int s2 = 0; s2 < NQS; ++s2)
            sacc[qt][s2][st] = __builtin_amdgcn_mfma_f32_16x16x32_bf16(
                qf[qt][s2], kf[st], sacc[qt][s2][st], 0, 0, 0);
      __builtin_amdgcn_s_setprio(0);
    }
    // ---- exp2 + running sums + strip write (unnormalized weights) ----
#pragma unroll
    for (int qt = 0; qt < QT; ++qt)
#pragma unroll
      for (int s2 = 0; s2 < NQS; ++s2)
#pragma unroll
        for (int st = 0; st < 4; ++st)
#pragma unroll
          for (int r = 0; r < 4; ++r) {
            const float e = exp2f(sacc[qt][s2][st][r]);
            psum[qt][s2][r] += e;
            ssh[(s2 * NR + qt * 16 + lq * 4 + r) * SP + (w * 4 + st) * 16 + l15] =
                (unsigned short)f2b(e);
          }
    __syncthreads();
    // ---- PV: V loaded once, serves all Q-sets ----
#pragma unroll 1
    for (int sc = 0; sc < 8; sc += 2) {
      bf16x8 vb[2][DT], pa[2][QT][NQS];
#pragma unroll
      for (int u = 0; u < 2; ++u) {
#pragma unroll
        for (int dt = 0; dt < DT; ++dt)
          vb[u][dt] = *(const bf16x8*)(
              Vp + ((size_t)(c * 8 + sc + u) * (D / 16) + w * DT + dt) * 512 + lane * 8);
#pragma unroll
        for (int qt = 0; qt < QT; ++qt)
#pragma unroll
          for (int s2 = 0; s2 < NQS; ++s2)
            pa[u][qt][s2] = *(const bf16x8*)(
                ssh + (s2 * NR + qt * 16 + l15) * SP + (sc + u) * 32 + lq * 8);
      }
      __builtin_amdgcn_s_setprio(1);
#pragma unroll
      for (int u = 0; u < 2; ++u)
#pragma unroll
        for (int qt = 0; qt < QT; ++qt)
#pragma unroll
          for (int s2 = 0; s2 < NQS; ++s2)
#pragma unroll
            for (int dt = 0; dt < DT; ++dt)
              acc_o[qt][s2][dt] = __builtin_amdgcn_mfma_f32_16x16x32_bf16(
                  pa[u][qt][s2], vb[u][dt], acc_o[qt][s2][dt], 0, 0, 0);
      __builtin_amdgcn_s_setprio(0);
    }
    __syncthreads();
  }

  // ---- final row sums: reduce over 16 key-lanes, then over 4 waves ----
#pragma unroll
  for (int o = 1; o < 16; o <<= 1)
#pragma unroll
    for (int qt = 0; qt < QT; ++qt)
#pragma unroll
      for (int s2 = 0; s2 < NQS; ++s2)
#pragma unroll
        for (int r = 0; r < 4; ++r)
          psum[qt][s2][r] += __shfl_xor(psum[qt][s2][r], o);
  if (l15 == 0) {
#pragma unroll
    for (int qt = 0; qt < QT; ++qt)
#pragma unroll
      for (int s2 = 0; s2 < NQS; ++s2)
#pragma unroll
        for (int r = 0; r < 4; ++r)
          red[((s2 * QT + qt) * 4 + w) * 16 + lq * 4 + r] = psum[qt][s2][r];
  }
  __syncthreads();
  float inv[QT][NQS][4];
#pragma unroll
  for (int qt = 0; qt < QT; ++qt)
#pragma unroll
    for (int s2 = 0; s2 < NQS; ++s2)
#pragma unroll
      for (int r = 0; r < 4; ++r) {
        const float* rp = red + ((s2 * QT + qt) * 4) * 16 + lq * 4 + r;
        inv[qt][s2][r] = 1.f / (rp[0] + rp[16] + rp[32] + rp[48]);
      }

  // ---- epilogue: normalize + write ----
  if constexpr (NQS == 2) {
    float* base = Rp + (size_t)side * (4096 * 512);
#pragma unroll
    for (int qt = 0; qt < QT; ++qt)
#pragma unroll
      for (int dt = 0; dt < DT; ++dt)
#pragma unroll
        for (int r = 0; r < 4; ++r) {
          const int q = qb + qt * 16 + lq * 4 + r;
          const int d = w * (DT * 16) + dt * 16 + l15;
          base[(rowb + q) * 512 + colo + d] =
              acc_o[qt][0][dt][r] * inv[qt][0][r] + acc_o[qt][1][dt][r] * inv[qt][1][r];
        }
  } else {
#pragma unroll
    for (int qt = 0; qt < QT; ++qt)
#pragma unroll
      for (int dt = 0; dt < DT; ++dt)
#pragma unroll
        for (int r = 0; r < 4; ++r) {
          const int q = qb + qt * 16 + lq * 4 + r;
          const int d = w * (DT * 16) + dt * 16 + l15;
          R[(rowb + q) * 512 + colo + d] =
              (unsigned short)f2b(acc_o[qt][0][dt][r] * inv[qt][0][r] * post_scale);
        }
  }
}

// ---- out = LayerNorm(G0 + G1 + res) * g + b  (f32 out + optional bf16 out) ----
__global__ __launch_bounds__(256) void ln_kernel(
    const float* __restrict__ G0, const float* __restrict__ G1,
    const float* __restrict__ res, const float* __restrict__ g,
    const float* __restrict__ b, float* __restrict__ out,
    unsigned short* __restrict__ outb) {
  __shared__ float sh[4];
  const int row = blockIdx.x, tid = threadIdx.x;
  const size_t off = (size_t)row * 512;
  const float x0 = G0[off + tid] + G1[off + tid] + res[off + tid];
  const float x1 = G0[off + tid + 256] + G1[off + tid + 256] + res[off + tid + 256];
  const float mean = block_sum1(x0 + x1, sh) * (1.0f / 512.0f);
  const float d0 = x0 - mean, d1 = x1 - mean;
  const float var = block_sum1(d0 * d0 + d1 * d1, sh) * (1.0f / 512.0f);
  const float inv = rsqrtf(var + 1e-5f);
  const float y0 = d0 * inv * g[tid] + b[tid];
  const float y1 = d1 * inv * g[tid + 256] + b[tid + 256];
  out[off + tid] = y0;
  out[off + tid + 256] = y1;
  if (outb) {
    outb[off + tid] = (unsigned short)f2b(y0);
    outb[off + tid + 256] = (unsigned short)f2b(y1);
  }
}

extern "C" void kernel_launch(void* const* d_in, const int* in_sizes, int n_in,
                              void* d_out, int out_size, void* d_ws, size_t ws_size,
                              hipStream_t stream) {
  typedef unsigned short ushort_t;
  const float* cx   = (const float*)d_in[0];
  const float* cy   = (const float*)d_in[1];
  const float* txp  = (const float*)d_in[2];
  const float* in_W = (const float*)d_in[3];
  const float* in_b = (const float*)d_in[4];
  const float* cx_W = (const float*)d_in[5];
  const float* cx_b = (const float*)d_in[6];
  const float* tx_W = (const float*)d_in[7];
  const float* tx_b = (const float*)d_in[8];
  const float* sWk  = (const float*)d_in[9];
  const float* sWv  = (const float*)d_in[10];
  const float* sWq  = (const float*)d_in[11];
  const float* sWf  = (const float*)d_in[12];
  const float* sbf  = (const float*)d_in[13];
  const float* sg   = (const float*)d_in[14];
  const float* sb   = (const float*)d_in[15];
  const float* aWk  = (const float*)d_in[16];
  const float* aWv  = (const float*)d_in[17];
  const float* aWq  = (const float*)d_in[18];
  const float* aWf  = (const float*)d_in[19];
  const float* abf  = (const float*)d_in[20];
  const float* ag   = (const float*)d_in[21];
  const float* ab   = (const float*)d_in[22];

  const size_t MB = 1024 * 1024;
  char* ws = (char*)d_ws;
  float*    E     = (float*)(ws + 0 * MB);       // 8 MB
  ushort_t* Ebf   = (ushort_t*)(ws + 8 * MB);    // 4 MB
  float*    QA    = (float*)(ws + 12 * MB);      // 8 MB
  ushort_t* QAbf  = (ushort_t*)(ws + 20 * MB);   // 4 MB
  ushort_t* Rbbf  = (ushort_t*)(ws + 24 * MB);   // 4 MB
  float*    Rp    = (float*)(ws + 28 * MB);      // 16 MB attn f32 partials (2 sides)
  float*    G0    = (float*)(ws + 44 * MB);      // 8 MB Wf partial kz=0
  ushort_t* KfrA  = (ushort_t*)(ws + 52 * MB);   // 4 MB
  ushort_t* VfrA  = (ushort_t*)(ws + 56 * MB);   // 4 MB
  ushort_t* QbfA  = (ushort_t*)(ws + 60 * MB);   // 4 MB
  ushort_t* KfrB  = (ushort_t*)(ws + 64 * MB);   // 4 MB
  ushort_t* VfrB  = (ushort_t*)(ws + 68 * MB);   // 4 MB
  ushort_t* QbfB  = (ushort_t*)(ws + 72 * MB);   // 4 MB
  float*    G1    = (float*)(ws + 84 * MB);      // 8 MB Wf partial kz=1
  ushort_t* Wkvqt0 = (ushort_t*)(ws + 92 * MB);  // 2 x 1.5 MB
  ushort_t* Wkvqt[2] = {Wkvqt0, Wkvqt0 + 786432};
  ushort_t* Wft0   = (ushort_t*)(ws + 95 * MB);  // 2 x 1 MB
  ushort_t* Wft[2] = {Wft0, Wft0 + 524288};
  ushort_t* aWvt0  = (ushort_t*)(ws + 97 * MB);  // 2 x 0.5 MB
  ushort_t* aWvt[2] = {aWvt0, aWvt0 + 262144};
  ushort_t* aWqt1  = (ushort_t*)(ws + 98 * MB);  // 0.5 MB
  ushort_t* aWft0  = (ushort_t*)(ws + 99 * MB);  // 2 x 1 MB
  ushort_t* aWft[2] = {aWft0, aWft0 + 524288};
  float*    Ttab   = (float*)(ws + 101 * MB);

  float* T_sc[2][3];
  for (int i = 0; i < 2; ++i)
    for (int w = 0; w < 3; ++w) T_sc[i][w] = Ttab + (size_t)(i * 3 + w) * 2048;
  float* T_cak[2] = {Ttab + 12288, Ttab + 12288 + 1024};
  float* T_caq0 = Ttab + 14336;

  const dim3 tb(32, 8);

  // ---- prep: fused weight transposes + projection tables ----
  transpose_kvq_kernel<<<dim3(16, 16, 9), tb, 0, stream>>>(sWk, sWv, sWq, aWv, aWq,
                                                           Wkvqt0, aWvt0, aWqt1);
  transpose_f_kernel<<<dim3(16, 32, 4), tb, 0, stream>>>(sWf, aWf, Wft0, aWft0);
  tabproj9_kernel<<<dim3(512, 9), 256, 0, stream>>>(in_W, in_b, cx_W, cx_b, tx_W, tx_b,
                                                    sWk, sWv, sWq, aWk, aWq, Ttab);

  // ---- initial activations ----
  affine3_kernel<<<4096, 512, 0, stream>>>(cx, cy, 0, in_W, in_b, E, Ebf);
  rank1_kernel<<<4096, 512, 0, stream>>>(txp, tx_W, tx_b, QA, QAbf);

  // ---- 8 self/cross encoder layers ----
  for (int p = 0; p < 4; ++p) {
    for (int i = 0; i < 2; ++i) {
      gemm_pack_kernel<0><<<dim3(24, 32), 256, 0, stream>>>(Ebf, Wkvqt[i], KfrA, VfrA,
                                                            QbfA);
      const float* F0 = nullptr;
      const float* F1 = nullptr;
      if (p > 0) {
        affine3kq_kernel<<<4096, 128, 0, stream>>>(cx, cy, p, T_sc[i][0], T_sc[i][2],
                                                   KfrB, QbfB);
        affine3v_frag_kernel<<<dim3(32, 8, 8), tb, 0, stream>>>(cx, cy, p, T_sc[i][1],
                                                                VfrB);
        attn_mfma_kernel<256, 2, 2><<<512, 256, 0, stream>>>(
            QbfA, QbfB, KfrA, KfrB, VfrA, VfrB, 1.0f, 2, nullptr, Rp);
        F0 = Rp; F1 = Rp + 4096 * 512;
      } else {
        // x2 is x: 4 identical sdpa terms -> 4 * sdpa(sQ,sK,sV)
        attn_mfma_kernel<256, 1, 2><<<256, 256, 0, stream>>>(
            QbfA, QbfA, KfrA, KfrA, VfrA, VfrA, 4.0f, 2, Rbbf, nullptr);
      }
      gemm_wf_kernel<<<dim3(8, 32, 2), 256, 0, stream>>>(
          Ebf, Rbbf, F0, F1, Wft[i], sbf + (size_t)i * 512, G0, G1);
      ln_kernel<<<4096, 256, 0, stream>>>(G0, G1, E, sg + (size_t)i * 512,
                                          sb + (size_t)i * 512, E, Ebf);
    }
  }

  // ---- 2 cross-attention decoder layers (nh=4, D=128) ----
  for (int i = 0; i < 2; ++i) {
    rank1_pack_kernel<<<4096, 64, 0, stream>>>(cx, T_cak[i], KfrA, 0);
    gemm_pack_kernel<1><<<dim3(8, 32), 256, 0, stream>>>(Ebf, aWvt[i], nullptr, VfrA,
                                                         nullptr);
    if (i == 0) {
      rank1_pack_kernel<<<4096, 64, 0, stream>>>(txp, T_caq0, QbfB, 1);
    } else {
      gemm_pack_kernel<2><<<dim3(8, 32), 256, 0, stream>>>(QAbf, aWqt1, nullptr, nullptr,
                                                           QbfB);
    }
    attn_mfma_kernel<128, 1, 2><<<512, 256, 0, stream>>>(
        QbfB, QbfB, KfrA, KfrA, VfrA, VfrA, 1.0f, 4, Rbbf, nullptr);
    gemm_wf_kernel<<<dim3(8, 32, 2), 256, 0, stream>>>(
        QAbf, Rbbf, nullptr, nullptr, aWft[i], abf + (size_t)i * 512, G0, G1);
    ln_kernel<<<4096, 256, 0, stream>>>(G0, G1, QA, ag + (size_t)i * 512,
                                        ab + (size_t)i * 512,
                                        (i == 1) ? (float*)d_out : QA,
                                        (i == 1) ? nullptr : QAbf);
  }
  (void)in_sizes; (void)n_in; (void)out_size; (void)ws_size;
}

// Round 11
// 980.788 us; speedup vs baseline: 1.1371x; 1.0705x over previous
//
#include <hip/hip_runtime.h>

#define DEVINL __device__ __forceinline__

typedef short bf16x8 __attribute__((ext_vector_type(8)));
typedef float f32x4 __attribute__((ext_vector_type(4)));

#define LOG2E 1.44269504088896f

DEVINL unsigned f2b(float f) {  // f32 -> bf16 bits (round to nearest even)
  unsigned u = __float_as_uint(f);
  u = (u + 0x7FFFu + ((u >> 16) & 1u)) >> 16;
  return u & 0xFFFFu;
}
DEVINL uint4 pack8(const float* v) {
  uint4 u;
  u.x = f2b(v[0]) | (f2b(v[1]) << 16);
  u.y = f2b(v[2]) | (f2b(v[3]) << 16);
  u.z = f2b(v[4]) | (f2b(v[5]) << 16);
  u.w = f2b(v[6]) | (f2b(v[7]) << 16);
  return u;
}

// ---------------- reduction helpers ----------------
DEVINL float4 block_sum4(float4 v, float4* sh) {
  const int lane = threadIdx.x & 63, wid = threadIdx.x >> 6;
#pragma unroll
  for (int o = 32; o; o >>= 1) {
    v.x += __shfl_down(v.x, o);
    v.y += __shfl_down(v.y, o);
    v.z += __shfl_down(v.z, o);
    v.w += __shfl_down(v.w, o);
  }
  __syncthreads();
  if (lane == 0) sh[wid] = v;
  __syncthreads();
  float4 a = sh[0], b = sh[1], c = sh[2], d = sh[3], r;
  r.x = a.x + b.x + c.x + d.x;
  r.y = a.y + b.y + c.y + d.y;
  r.z = a.z + b.z + c.z + d.z;
  r.w = a.w + b.w + c.w + d.w;
  return r;
}
DEVINL float block_sum1(float v, float* sh) {
  const int lane = threadIdx.x & 63, wid = threadIdx.x >> 6;
#pragma unroll
  for (int o = 32; o; o >>= 1) v += __shfl_down(v, o);
  __syncthreads();
  if (lane == 0) sh[wid] = v;
  __syncthreads();
  return sh[0] + sh[1] + sh[2] + sh[3];
}

// ---- fused table projections (9 jobs via blockIdx.y) ----
// Q-producing tables fold LOG2E (softmax uses exp2).
__global__ __launch_bounds__(256) void tabproj9_kernel(
    const float* __restrict__ in_W, const float* __restrict__ in_b,
    const float* __restrict__ cx_W, const float* __restrict__ cx_b,
    const float* __restrict__ tx_W, const float* __restrict__ tx_b,
    const float* __restrict__ sWk, const float* __restrict__ sWv,
    const float* __restrict__ sWq, const float* __restrict__ aWk,
    const float* __restrict__ aWq, float* __restrict__ Ttab) {
  const int z = blockIdx.y;
  const float* V;
  const float* bias;
  const float* W;
  float* P;
  int nvec;
  float scl = 1.f;
  if (z < 6) {
    V = in_W; bias = in_b; nvec = 3;
    const int i = z / 3, wsel = z % 3;
    W = (wsel == 0 ? sWk : wsel == 1 ? sWv : sWq) + (size_t)i * 262144;
    P = Ttab + (size_t)z * 2048;
    if (wsel == 2) scl = 0.0625f * LOG2E;
  } else if (z < 8) {
    V = cx_W; bias = cx_b; nvec = 1;
    W = aWk + (size_t)(z - 6) * 262144;
    P = Ttab + 12288 + (size_t)(z - 6) * 1024;
  } else {
    V = tx_W; bias = tx_b; nvec = 1;
    W = aWq; P = Ttab + 14336; scl = 0.08838834764831845f * LOG2E;
  }
  __shared__ float4 sh4[4];
  const int j = blockIdx.x, tid = threadIdx.x;
  float acc[4] = {0.f, 0.f, 0.f, 0.f};
  for (int kk = tid; kk < 512; kk += 256) {
    const float w = W[(size_t)kk * 512 + j];
    for (int v = 0; v < nvec; ++v) acc[v] += V[(size_t)v * 512 + kk] * w;
    acc[3] += bias[kk] * w;
  }
  float4 packed = make_float4(acc[0], acc[1], acc[2], acc[3]);
  packed = block_sum4(packed, sh4);
  if (tid == 0) {
    const float vals[4] = {packed.x * scl, packed.y * scl, packed.z * scl, packed.w * scl};
    for (int v = 0; v < nvec; ++v) P[(size_t)v * 512 + j] = vals[v];
    P[(size_t)nvec * 512 + j] = vals[3];
  }
}

// ---- fused weight transposes, K=512 (9 jobs via blockIdx.z); Q scaled w/ LOG2E ----
__global__ __launch_bounds__(256) void transpose_kvq_kernel(
    const float* __restrict__ sWk, const float* __restrict__ sWv,
    const float* __restrict__ sWq, const float* __restrict__ aWv,
    const float* __restrict__ aWq, unsigned short* __restrict__ Wkvqt0,
    unsigned short* __restrict__ aWvt0, unsigned short* __restrict__ aWqt1) {
  const int z = blockIdx.z;
  const float* src;
  unsigned short* dst;
  float scl = 1.f;
  if (z < 6) {
    const int i = z / 3, wsel = z % 3;
    src = (wsel == 0 ? sWk : wsel == 1 ? sWv : sWq) + (size_t)i * 262144;
    dst = Wkvqt0 + (size_t)i * 786432 + (size_t)wsel * 262144;
    if (wsel == 2) scl = 0.0625f * LOG2E;
  } else if (z < 8) {
    src = aWv + (size_t)(z - 6) * 262144;
    dst = aWvt0 + (size_t)(z - 6) * 262144;
  } else {
    src = aWq + 262144; dst = aWqt1; scl = 0.08838834764831845f * LOG2E;
  }
  __shared__ float tile[32][33];
  const int n0 = blockIdx.x * 32, k0 = blockIdx.y * 32;
  const int tx = threadIdx.x, ty = threadIdx.y;  // 32 x 8
#pragma unroll
  for (int r = 0; r < 4; ++r)
    tile[ty + 8 * r][tx] = src[(size_t)(k0 + ty + 8 * r) * 512 + n0 + tx];
  __syncthreads();
#pragma unroll
  for (int r = 0; r < 4; ++r)
    dst[(size_t)(n0 + ty + 8 * r) * 512 + k0 + tx] =
        (unsigned short)f2b(scl * tile[tx][ty + 8 * r]);
}

// ---- fused weight transposes, K=1024 (4 jobs via blockIdx.z) ----
__global__ __launch_bounds__(256) void transpose_f_kernel(
    const float* __restrict__ sWf, const float* __restrict__ aWf,
    unsigned short* __restrict__ Wft0, unsigned short* __restrict__ aWft0) {
  const int z = blockIdx.z;
  const float* src = (z < 2 ? sWf + (size_t)z * 524288 : aWf + (size_t)(z - 2) * 524288);
  unsigned short* dst =
      (z < 2 ? Wft0 + (size_t)z * 524288 : aWft0 + (size_t)(z - 2) * 524288);
  __shared__ float tile[32][33];
  const int n0 = blockIdx.x * 32, k0 = blockIdx.y * 32;
  const int tx = threadIdx.x, ty = threadIdx.y;  // 32 x 8
#pragma unroll
  for (int r = 0; r < 4; ++r)
    tile[ty + 8 * r][tx] = src[(size_t)(k0 + ty + 8 * r) * 512 + n0 + tx];
  __syncthreads();
#pragma unroll
  for (int r = 0; r < 4; ++r)
    dst[(size_t)(n0 + ty + 8 * r) * 1024 + k0 + tx] =
        (unsigned short)f2b(tile[tx][ty + 8 * r]);
}

// ---- cross-side encoder K/Q: rank-3 affine -> Kfr + Qbf (rows) ----
__global__ __launch_bounds__(128) void affine3kq_kernel(
    const float* __restrict__ cx, const float* __restrict__ cy, int sel,
    const float* __restrict__ TK, const float* __restrict__ TQ,
    unsigned short* __restrict__ Kfr, unsigned short* __restrict__ Qbf) {
  const int row = blockIdx.x;
  const int b = row >> 10, s = row & 1023;
  const float x = cx[row];
  const float* y = cy + (size_t)row * 8 + 2 * sel;
  const float y0 = y[0], y1 = y[1];
  const int t = threadIdx.x;
  const bool isQ = t >= 64;
  const int c = t & 63;
  const int h = c >> 5;
  const int d0 = (c & 31) * 8;
  const float* T = isQ ? TQ : TK;
  float v[8];
#pragma unroll
  for (int j = 0; j < 8; ++j) {
    const int col = h * 256 + d0 + j;
    v[j] = x * T[col] + y0 * T[512 + col] + y1 * T[1024 + col] + T[1536 + col];
  }
  const uint4 u = pack8(v);
  const int bh = b * 2 + h;
  if (isQ) {
    *(uint4*)(Qbf + ((size_t)bh * 1024 + s) * 256 + d0) = u;
  } else {
    const int kc = d0 >> 5;
    const int lane = ((d0 & 31) >> 3) * 16 + (s & 15);
    *(uint4*)(Kfr + ((size_t)(bh * 8 + kc) * 64 + (s >> 4)) * 512 + lane * 8) = u;
  }
}

// ---- cross-side encoder V: compute rank-3 affine per 32x32 tile -> Vfr direct ----
__global__ __launch_bounds__(256) void affine3v_frag_kernel(
    const float* __restrict__ cx, const float* __restrict__ cy, int sel,
    const float* __restrict__ TV, unsigned short* __restrict__ Vfr) {
  __shared__ float tile[32][33];
  const int s0 = blockIdx.x * 32, d0 = blockIdx.y * 32;
  const int bh = blockIdx.z;
  const int b = bh >> 1, h = bh & 1;
  const int tx = threadIdx.x, ty = threadIdx.y;  // 32 x 8
  const int col = h * 256 + d0 + tx;
  const float tv0 = TV[col], tv1 = TV[512 + col], tv2 = TV[1024 + col],
              tv3 = TV[1536 + col];
#pragma unroll
  for (int r = 0; r < 4; ++r) {
    const int row = b * 1024 + s0 + ty + 8 * r;
    const float x = cx[row];
    const float* y = cy + (size_t)row * 8 + 2 * sel;
    tile[ty + 8 * r][tx] = x * tv0 + y[0] * tv1 + y[1] * tv2 + tv3;
  }
  __syncthreads();
  const int idx = ty * 32 + tx;
  if (idx < 128) {
    const int dj = idx & 31, sch = idx >> 5;
    float v[8];
#pragma unroll
    for (int jj = 0; jj < 8; ++jj) v[jj] = tile[sch * 8 + jj][dj];
    const uint4 u = pack8(v);
    const int sc = s0 >> 5;
    const int dtile = (d0 + dj) >> 4;
    const int lane = sch * 16 + (dj & 15);
    *(uint4*)(Vfr + ((size_t)(bh * 32 + sc) * 16 + dtile) * 512 + lane * 8) = u;
  }
}

// ---- decoder rank-1 producers (nh=4, D=128): T rows [0]=w, [1]=bias ----
__global__ __launch_bounds__(64) void rank1_pack_kernel(
    const float* __restrict__ x, const float* __restrict__ T,
    unsigned short* __restrict__ dst, int isQ) {
  const int row = blockIdx.x;
  const int b = row >> 10, s = row & 1023;
  const float xv = x[row];
  const int c = threadIdx.x;        // 64 chunks of 8
  const int h = c >> 4;             // 16 chunks per head
  const int d0 = (c & 15) * 8;
  float v[8];
#pragma unroll
  for (int j = 0; j < 8; ++j) {
    const int col = h * 128 + d0 + j;
    v[j] = xv * T[col] + T[512 + col];
  }
  const uint4 u = pack8(v);
  const int bh = b * 4 + h;
  if (isQ) {
    *(uint4*)(dst + ((size_t)bh * 1024 + s) * 128 + d0) = u;
  } else {
    const int kc = d0 >> 5;
    const int lane = ((d0 & 31) >> 3) * 16 + (s & 15);
    *(uint4*)(dst + ((size_t)(bh * 4 + kc) * 64 + (s >> 4)) * 512 + lane * 8) = u;
  }
}

// ---- out[r,:] = cx[r]*W3[0,:] + y0*W3[1,:] + y1*W3[2,:] + bias (f32 + bf16) ----
__global__ __launch_bounds__(512) void affine3_kernel(
    const float* __restrict__ cx, const float* __restrict__ cy, int sel,
    const float* __restrict__ W3, const float* __restrict__ bias,
    float* __restrict__ out, unsigned short* __restrict__ outb) {
  const int r = blockIdx.x, j = threadIdx.x;
  const float* y = cy + (size_t)r * 8 + 2 * sel;
  const float v = cx[r] * W3[j] + y[0] * W3[512 + j] + y[1] * W3[1024 + j] + bias[j];
  if (out) out[(size_t)r * 512 + j] = v;
  if (outb) outb[(size_t)r * 512 + j] = (unsigned short)f2b(v);
}

// ---- out[r,:] = x[r]*w + b ----
__global__ __launch_bounds__(512) void rank1_kernel(
    const float* __restrict__ x, const float* __restrict__ w,
    const float* __restrict__ b, float* __restrict__ out,
    unsigned short* __restrict__ outb) {
  const int r = blockIdx.x, j = threadIdx.x;
  const float v = x[r] * w[j] + b[j];
  if (out) out[(size_t)r * 512 + j] = v;
  if (outb) outb[(size_t)r * 512 + j] = (unsigned short)f2b(v);
}

// ------------- split-K Wf GEMM (double-buffered): two K-halves via blockIdx.z ----
// XCD-aware block swizzle: same-bm blocks (sharing A panel) stay on one XCD.
__global__ __launch_bounds__(256) void gemm_wf_kernel(
    const unsigned short* __restrict__ A0, const unsigned short* __restrict__ A1,
    const float* __restrict__ F0, const float* __restrict__ F1,
    const unsigned short* __restrict__ Wt, const float* __restrict__ bias,
    float* __restrict__ C0, float* __restrict__ C1) {
  constexpr int BM = 128, BN = 64, BK = 32, LDP = 40, K = 512, N = 512;
  __shared__ unsigned short As[2][BM * LDP];
  __shared__ unsigned short Bs[2][BN * LDP];
  const int kz = blockIdx.z;
  const int tid = threadIdx.x;
  const int lane = tid & 63, w = tid >> 6;
  const int lin = blockIdx.y * 8 + blockIdx.x;      // 256 blocks per kz
  const int swz = (lin & 7) * 32 + (lin >> 3);      // bijective, 256%8==0
  const int bm = (swz >> 3) * BM, bn = (swz & 7) * BN;
  const int wm = (w & 1) * 64, wn = (w >> 1) * 32;
  const int l15 = lane & 15, lq = lane >> 4;
  const int ar = tid >> 1, ac = (tid & 1) * 16;
  const int br = tid >> 2, bc = (tid & 3) * 8;
  const unsigned short* A = kz ? A1 : A0;
  const bool useF = (kz != 0) && (F0 != nullptr);
  const size_t arow = (size_t)(bm + ar) * 512;
  const size_t brow = (size_t)(bn + br) * 1024 + (size_t)kz * 512;
  f32x4 acc[4][2] = {};
  uint4 ra0, ra1, rb0;
#define GLOAD(k0_)                                                          \
  do {                                                                      \
    if (useF) {                                                             \
      const float* p0 = F0 + arow + (k0_) + ac;                             \
      const float* p1 = F1 + arow + (k0_) + ac;                             \
      float s[16];                                                          \
      const float4 x0 = *(const float4*)p0, x1 = *(const float4*)(p0 + 4);  \
      const float4 x2 = *(const float4*)(p0 + 8), x3 = *(const float4*)(p0 + 12); \
      const float4 y0 = *(const float4*)p1, y1 = *(const float4*)(p1 + 4);  \
      const float4 y2 = *(const float4*)(p1 + 8), y3 = *(const float4*)(p1 + 12); \
      s[0] = x0.x + y0.x; s[1] = x0.y + y0.y; s[2] = x0.z + y0.z; s[3] = x0.w + y0.w; \
      s[4] = x1.x + y1.x; s[5] = x1.y + y1.y; s[6] = x1.z + y1.z; s[7] = x1.w + y1.w; \
      s[8] = x2.x + y2.x; s[9] = x2.y + y2.y; s[10] = x2.z + y2.z; s[11] = x2.w + y2.w; \
      s[12] = x3.x + y3.x; s[13] = x3.y + y3.y; s[14] = x3.z + y3.z; s[15] = x3.w + y3.w; \
      ra0 = pack8(s); ra1 = pack8(s + 8);                                   \
    } else {                                                                \
      ra0 = *(const uint4*)(A + arow + (k0_) + ac);                         \
      ra1 = *(const uint4*)(A + arow + (k0_) + ac + 8);                     \
    }                                                                       \
    rb0 = *(const uint4*)(Wt + brow + (k0_) + bc);                          \
  } while (0)
  GLOAD(0);
  *(uint4*)(As[0] + ar * LDP + ac) = ra0;
  *(uint4*)(As[0] + ar * LDP + ac + 8) = ra1;
  *(uint4*)(Bs[0] + br * LDP + bc) = rb0;
  __syncthreads();
  int buf = 0;
  for (int k0 = 0; k0 < K; k0 += BK) {
    const bool more = (k0 + BK) < K;
    if (more) GLOAD(k0 + BK);
    bf16x8 af[4], bfr[2];
#pragma unroll
    for (int mt = 0; mt < 4; ++mt)
      af[mt] = *(const bf16x8*)(As[buf] + (wm + mt * 16 + l15) * LDP + lq * 8);
#pragma unroll
    for (int nt = 0; nt < 2; ++nt)
      bfr[nt] = *(const bf16x8*)(Bs[buf] + (wn + nt * 16 + l15) * LDP + lq * 8);
#pragma unroll
    for (int mt = 0; mt < 4; ++mt)
#pragma unroll
      for (int nt = 0; nt < 2; ++nt)
        acc[mt][nt] =
            __builtin_amdgcn_mfma_f32_16x16x32_bf16(af[mt], bfr[nt], acc[mt][nt], 0, 0, 0);
    if (more) {
      *(uint4*)(As[buf ^ 1] + ar * LDP + ac) = ra0;
      *(uint4*)(As[buf ^ 1] + ar * LDP + ac + 8) = ra1;
      *(uint4*)(Bs[buf ^ 1] + br * LDP + bc) = rb0;
    }
    __syncthreads();
    buf ^= 1;
  }
#undef GLOAD
  float* C = kz ? C1 : C0;
#pragma unroll
  for (int nt = 0; nt < 2; ++nt) {
    const int col = bn + wn + nt * 16 + l15;
    const float bv = (kz && bias) ? bias[col] : 0.f;
#pragma unroll
    for (int mt = 0; mt < 4; ++mt) {
#pragma unroll
      for (int r = 0; r < 4; ++r) {
        const int row = bm + wm + mt * 16 + lq * 4 + r;
        C[(size_t)row * N + col] = acc[mt][nt][r] + bv;
      }
    }
  }
}

// ------- MFMA GEMM with fused frag-pack epilogue (K=512, single A) ---------------
// MODE 0: N=1536 = K|V|Q sections, nh=2, D=256 -> Kfr, Vfr, Qbf
// MODE 1: N=512  = V only, nh=4, D=128 -> Vfr
// MODE 2: N=512  = Q only, nh=4, D=128 -> Qbf (weights pre-scaled)
// XCD-aware swizzle: same-bm blocks (sharing A panel) stay on one XCD.
template <int MODE>
__global__ __launch_bounds__(256) void gemm_pack_kernel(
    const unsigned short* __restrict__ A0, const unsigned short* __restrict__ Wt,
    unsigned short* __restrict__ Kfr, unsigned short* __restrict__ Vfr,
    unsigned short* __restrict__ Qbf) {
  constexpr int BM = 128, BN = 64, BK = 32, LDP = 40, K = 512;
  __shared__ unsigned short As[2][BM * LDP];
  __shared__ unsigned short Bs[2][BN * LDP];
  const int tid = threadIdx.x;
  const int lane = tid & 63, w = tid >> 6;
  const int nbx = gridDim.x;
  const int lin = blockIdx.y * nbx + blockIdx.x;
  const int nwg = nbx * gridDim.y;                  // 768 or 256, both %8==0
  const int swz = (lin & 7) * (nwg >> 3) + (lin >> 3);
  const int bm = (swz / nbx) * BM, bn = (swz % nbx) * BN;
  const int wm = (w & 1) * 64, wn = (w >> 1) * 32;
  const int l15 = lane & 15, lq = lane >> 4;
  const int ar = tid >> 1, ac = (tid & 1) * 16;
  const int br = tid >> 2, bc = (tid & 3) * 8;
  f32x4 acc[4][2] = {};
  uint4 ra0 = *(const uint4*)(A0 + (size_t)(bm + ar) * K + ac);
  uint4 ra1 = *(const uint4*)(A0 + (size_t)(bm + ar) * K + ac + 8);
  uint4 rb0 = *(const uint4*)(Wt + (size_t)(bn + br) * K + bc);
  *(uint4*)(As[0] + ar * LDP + ac) = ra0;
  *(uint4*)(As[0] + ar * LDP + ac + 8) = ra1;
  *(uint4*)(Bs[0] + br * LDP + bc) = rb0;
  __syncthreads();
  int buf = 0;
  for (int k0 = 0; k0 < K; k0 += BK) {
    const bool more = (k0 + BK) < K;
    if (more) {
      ra0 = *(const uint4*)(A0 + (size_t)(bm + ar) * K + k0 + BK + ac);
      ra1 = *(const uint4*)(A0 + (size_t)(bm + ar) * K + k0 + BK + ac + 8);
      rb0 = *(const uint4*)(Wt + (size_t)(bn + br) * K + k0 + BK + bc);
    }
    bf16x8 af[4], bfr[2];
#pragma unroll
    for (int mt = 0; mt < 4; ++mt)
      af[mt] = *(const bf16x8*)(As[buf] + (wm + mt * 16 + l15) * LDP + lq * 8);
#pragma unroll
    for (int nt = 0; nt < 2; ++nt)
      bfr[nt] = *(const bf16x8*)(Bs[buf] + (wn + nt * 16 + l15) * LDP + lq * 8);
#pragma unroll
    for (int mt = 0; mt < 4; ++mt)
#pragma unroll
      for (int nt = 0; nt < 2; ++nt)
        acc[mt][nt] =
            __builtin_amdgcn_mfma_f32_16x16x32_bf16(af[mt], bfr[nt], acc[mt][nt], 0, 0, 0);
    if (more) {
      *(uint4*)(As[buf ^ 1] + ar * LDP + ac) = ra0;
      *(uint4*)(As[buf ^ 1] + ar * LDP + ac + 8) = ra1;
      *(uint4*)(Bs[buf ^ 1] + br * LDP + bc) = rb0;
    }
    __syncthreads();
    buf ^= 1;
  }
  // ---- fused pack epilogue ----
  const int b = bm >> 10;
  const int s0base = (bm & 1023) + wm + lq * 4;
#pragma unroll
  for (int nt = 0; nt < 2; ++nt) {
    const int col = bn + wn + nt * 16 + l15;
    int sec, h, d, nh2, Dv;
    if constexpr (MODE == 0) {
      sec = col >> 9; const int c = col & 511; h = c >> 8; d = c & 255; nh2 = 2; Dv = 256;
    } else if constexpr (MODE == 1) {
      sec = 1; h = col >> 7; d = col & 127; nh2 = 4; Dv = 128;
    } else {
      sec = 2; h = col >> 7; d = col & 127; nh2 = 4; Dv = 128;
    }
    const int bh = b * nh2 + h;
#pragma unroll
    for (int mt = 0; mt < 4; ++mt) {
      const int s0 = s0base + mt * 16;
      const float* a = (const float*)&acc[mt][nt];
      if (sec == 2) {                           // Q: [bh][s][Dv]
        unsigned short* q = Qbf + ((size_t)bh * 1024 + s0) * Dv + d;
#pragma unroll
        for (int r = 0; r < 4; ++r) q[(size_t)r * Dv] = (unsigned short)f2b(a[r]);
      } else if (sec == 0) {                    // K frag
        unsigned short* kp = Kfr +
            ((size_t)(bh * 8 + (d >> 5)) * 64 + (s0 >> 4)) * 512 +
            ((d & 31) >> 3) * 128 + (d & 7);
#pragma unroll
        for (int r = 0; r < 4; ++r)
          kp[((s0 & 15) + r) * 8] = (unsigned short)f2b(a[r]);
      } else {                                  // V frag
        unsigned short* vp = Vfr +
            ((size_t)(bh * 32 + (s0 >> 5)) * (Dv / 16) + (d >> 4)) * 512 +
            (((s0 >> 3) & 3) * 16 + (d & 15)) * 8 + (s0 & 7);
        uint2 u;
        u.x = f2b(a[0]) | (f2b(a[1]) << 16);
        u.y = f2b(a[2]) | (f2b(a[3]) << 16);
        *(uint2*)vp = u;
      }
    }
  }
}

// -------- MFMA flash attention, chunked keys + deferred normalization -----------
// Block = QT*16 q rows of one (b,head) vs ONE KV side, keys in 4 chunks of 256
// (R8-proven config; 128-key chunks regressed -22%, R9 post-mortem).
// No-max softmax => O = (sum_k exp2(s) V) / (sum_k exp2(s)) accumulated per chunk;
// normalization applied once at the end.  NQS Q-sets share K and V loads.
// All register arrays statically indexed (rule #20); c/kc/sc feed addresses only.
// NQS==2: grid = 2*256, side = bx>>8; writes f32 partials to Rp.
// NQS==1: writes bf16 with post_scale.
template <int D, int NQS, int QT>
__global__ __launch_bounds__(256, 2) void attn_mfma_kernel(
    const unsigned short* __restrict__ Qa, const unsigned short* __restrict__ Qb,
    const unsigned short* __restrict__ KfrA, const unsigned short* __restrict__ KfrB,
    const unsigned short* __restrict__ VfrA, const unsigned short* __restrict__ VfrB,
    float post_scale, int nh, unsigned short* __restrict__ R,
    float* __restrict__ Rp) {
  constexpr int QP = D + 8;      // qsh pitch
  constexpr int SP = 256 + 8;    // strip pitch (chunk = 256 keys)
  constexpr int DT = D / 64;     // d-tiles per wave
  constexpr int NR = QT * 16;    // q rows per block
  const int tid = threadIdx.x;
  const int lane = tid & 63, w = tid >> 6;
  const int l15 = lane & 15, lq = lane >> 4;
  const int nbh = 4 * nh;
  int bx = blockIdx.x;
  int side = 0;
  if constexpr (NQS == 2) { side = bx >> 8; bx &= 255; }
  const int bh = bx % nbh;       // XCD-local (b,h): same-bh blocks share an XCD's L2
  const int qb = (bx / nbh) * NR;
  const int b = bh / nh, head = bh % nh;
  const size_t rowb = (size_t)b * 1024;
  const int colo = head * D;

  __shared__ unsigned short qsh[NQS * NR * QP];
  __shared__ unsigned short ssh[NQS * NR * SP];
  __shared__ float red[NQS * QT * 4 * 16];

  // ---- stage Q ----
  for (int idx = tid; idx < NQS * NR * (D / 8); idx += 256) {
    const int set = idx / (NR * (D / 8));
    const int rem = idx - set * NR * (D / 8);
    const int r = rem / (D / 8), ch = rem - r * (D / 8);
    const unsigned short* Q = set ? Qb : Qa;
    const uint4 u = *(const uint4*)(Q + ((size_t)bh * 1024 + qb + r) * D + ch * 8);
    *(uint4*)(qsh + (set * NR + r) * QP + ch * 8) = u;
  }
  __syncthreads();

  const unsigned short* Kp = (side ? KfrB : KfrA) + (size_t)bh * ((size_t)D * 1024);
  const unsigned short* Vp = (side ? VfrB : VfrA) + (size_t)bh * ((size_t)D * 1024);

  float psum[QT][NQS][4];
#pragma unroll
  for (int qt = 0; qt < QT; ++qt)
#pragma unroll
    for (int s2 = 0; s2 < NQS; ++s2)
#pragma unroll
      for (int r = 0; r < 4; ++r) psum[qt][s2][r] = 0.f;
  f32x4 acc_o[QT][NQS][DT] = {};

#pragma unroll 1
  for (int c = 0; c < 4; ++c) {        // c only feeds addresses (safe runtime)
    // ---- QK^T for chunk: wave w owns stiles c*16 + w*4 .. +3 (keys w*64..+63) ----
    f32x4 sacc[QT][NQS][4] = {};
#pragma unroll 1
    for (int kc = 0; kc < D / 32; ++kc) {
      bf16x8 kf[4];
#pragma unroll
      for (int st = 0; st < 4; ++st)
        kf[st] = *(const bf16x8*)(
            Kp + ((size_t)kc * 64 + c * 16 + w * 4 + st) * 512 + lane * 8);
      bf16x8 qf[QT][NQS];
#pragma unroll
      for (int qt = 0; qt < QT; ++qt)
#pragma unroll
        for (int s2 = 0; s2 < NQS; ++s2)
          qf[qt][s2] = *(const bf16x8*)(
              qsh + (s2 * NR + qt * 16 + l15) * QP + kc * 32 + lq * 8);
      __builtin_amdgcn_s_setprio(1);
#pragma unroll
      for (int st = 0; st < 4; ++st)
#pragma unroll
        for (int qt = 0; qt < QT; ++qt)
#pragma unroll
          for (int s2 = 0; s2 < NQS; ++s2)
            sacc[qt][s2][st] = __builtin_amdgcn_mfma_f32_16x16x32_bf16(
                qf[qt][s2], kf[st], sacc[qt][s2][st], 0, 0, 0);
      __builtin_amdgcn_s_setprio(0);
    }
    // ---- exp2 + running sums + strip write (unnormalized weights) ----
#pragma unroll
    for (int qt = 0; qt < QT; ++qt)
#pragma unroll
      for (int s2 = 0; s2 < NQS; ++s2)
#pragma unroll
        for (int st = 0; st < 4; ++st)
#pragma unroll
          for (int r = 0; r < 4; ++r) {
            const float e = exp2f(sacc[qt][s2][st][r]);
            psum[qt][s2][r] += e;
            ssh[(s2 * NR + qt * 16 + lq * 4 + r) * SP + (w * 4 + st) * 16 + l15] =
                (unsigned short)f2b(e);
          }
    __syncthreads();
    // ---- PV: V loaded once, serves all Q-sets ----
#pragma unroll 1
    for (int sc = 0; sc < 8; sc += 2) {
      bf16x8 vb[2][DT], pa[2][QT][NQS];
#pragma unroll
      for (int u = 0; u < 2; ++u) {
#pragma unroll
        for (int dt = 0; dt < DT; ++dt)
          vb[u][dt] = *(const bf16x8*)(
              Vp + ((size_t)(c * 8 + sc + u) * (D / 16) + w * DT + dt) * 512 + lane * 8);
#pragma unroll
        for (int qt = 0; qt < QT; ++qt)
#pragma unroll
          for (int s2 = 0; s2 < NQS; ++s2)
            pa[u][qt][s2] = *(const bf16x8*)(
                ssh + (s2 * NR + qt * 16 + l15) * SP + (sc + u) * 32 + lq * 8);
      }
      __builtin_amdgcn_s_setprio(1);
#pragma unroll
      for (int u = 0; u < 2; ++u)
#pragma unroll
        for (int qt = 0; qt < QT; ++qt)
#pragma unroll
          for (int s2 = 0; s2 < NQS; ++s2)
#pragma unroll
            for (int dt = 0; dt < DT; ++dt)
              acc_o[qt][s2][dt] = __builtin_amdgcn_mfma_f32_16x16x32_bf16(
                  pa[u][qt][s2], vb[u][dt], acc_o[qt][s2][dt], 0, 0, 0);
      __builtin_amdgcn_s_setprio(0);
    }
    __syncthreads();
  }

  // ---- final row sums: reduce over 16 key-lanes, then over 4 waves ----
#pragma unroll
  for (int o = 1; o < 16; o <<= 1)
#pragma unroll
    for (int qt = 0; qt < QT; ++qt)
#pragma unroll
      for (int s2 = 0; s2 < NQS; ++s2)
#pragma unroll
        for (int r = 0; r < 4; ++r)
          psum[qt][s2][r] += __shfl_xor(psum[qt][s2][r], o);
  if (l15 == 0) {
#pragma unroll
    for (int qt = 0; qt < QT; ++qt)
#pragma unroll
      for (int s2 = 0; s2 < NQS; ++s2)
#pragma unroll
        for (int r = 0; r < 4; ++r)
          red[((s2 * QT + qt) * 4 + w) * 16 + lq * 4 + r] = psum[qt][s2][r];
  }
  __syncthreads();
  float inv[QT][NQS][4];
#pragma unroll
  for (int qt = 0; qt < QT; ++qt)
#pragma unroll
    for (int s2 = 0; s2 < NQS; ++s2)
#pragma unroll
      for (int r = 0; r < 4; ++r) {
        const float* rp = red + ((s2 * QT + qt) * 4) * 16 + lq * 4 + r;
        inv[qt][s2][r] = 1.f / (rp[0] + rp[16] + rp[32] + rp[48]);
      }

  // ---- epilogue: normalize + write ----
  if constexpr (NQS == 2) {
    float* base = Rp + (size_t)side * (4096 * 512);
#pragma unroll
    for (int qt = 0; qt < QT; ++qt)
#pragma unroll
      for (int dt = 0; dt < DT; ++dt)
#pragma unroll
        for (int r = 0; r < 4; ++r) {
          const int q = qb + qt * 16 + lq * 4 + r;
          const int d = w * (DT * 16) + dt * 16 + l15;
          base[(rowb + q) * 512 + colo + d] =
              acc_o[qt][0][dt][r] * inv[qt][0][r] + acc_o[qt][1][dt][r] * inv[qt][1][r];
        }
  } else {
#pragma unroll
    for (int qt = 0; qt < QT; ++qt)
#pragma unroll
      for (int dt = 0; dt < DT; ++dt)
#pragma unroll
        for (int r = 0; r < 4; ++r) {
          const int q = qb + qt * 16 + lq * 4 + r;
          const int d = w * (DT * 16) + dt * 16 + l15;
          R[(rowb + q) * 512 + colo + d] =
              (unsigned short)f2b(acc_o[qt][0][dt][r] * inv[qt][0][r] * post_scale);
        }
  }
}

// ---- out = LayerNorm(G0 + G1 + res) * g + b  (f32 out + optional bf16 out) ----
__global__ __launch_bounds__(256) void ln_kernel(
    const float* __restrict__ G0, const float* __restrict__ G1,
    const float* __restrict__ res, const float* __restrict__ g,
    const float* __restrict__ b, float* __restrict__ out,
    unsigned short* __restrict__ outb) {
  __shared__ float sh[4];
  const int row = blockIdx.x, tid = threadIdx.x;
  const size_t off = (size_t)row * 512;
  const float x0 = G0[off + tid] + G1[off + tid] + res[off + tid];
  const float x1 = G0[off + tid + 256] + G1[off + tid + 256] + res[off + tid + 256];
  const float mean = block_sum1(x0 + x1, sh) * (1.0f / 512.0f);
  const float d0 = x0 - mean, d1 = x1 - mean;
  const float var = block_sum1(d0 * d0 + d1 * d1, sh) * (1.0f / 512.0f);
  const float inv = rsqrtf(var + 1e-5f);
  const float y0 = d0 * inv * g[tid] + b[tid];
  const float y1 = d1 * inv * g[tid + 256] + b[tid + 256];
  out[off + tid] = y0;
  out[off + tid + 256] = y1;
  if (outb) {
    outb[off + tid] = (unsigned short)f2b(y0);
    outb[off + tid + 256] = (unsigned short)f2b(y1);
  }
}

extern "C" void kernel_launch(void* const* d_in, const int* in_sizes, int n_in,
                              void* d_out, int out_size, void* d_ws, size_t ws_size,
                              hipStream_t stream) {
  typedef unsigned short ushort_t;
  const float* cx   = (const float*)d_in[0];
  const float* cy   = (const float*)d_in[1];
  const float* txp  = (const float*)d_in[2];
  const float* in_W = (const float*)d_in[3];
  const float* in_b = (const float*)d_in[4];
  const float* cx_W = (const float*)d_in[5];
  const float* cx_b = (const float*)d_in[6];
  const float* tx_W = (const float*)d_in[7];
  const float* tx_b = (const float*)d_in[8];
  const float* sWk  = (const float*)d_in[9];
  const float* sWv  = (const float*)d_in[10];
  const float* sWq  = (const float*)d_in[11];
  const float* sWf  = (const float*)d_in[12];
  const float* sbf  = (const float*)d_in[13];
  const float* sg   = (const float*)d_in[14];
  const float* sb   = (const float*)d_in[15];
  const float* aWk  = (const float*)d_in[16];
  const float* aWv  = (const float*)d_in[17];
  const float* aWq  = (const float*)d_in[18];
  const float* aWf  = (const float*)d_in[19];
  const float* abf  = (const float*)d_in[20];
  const float* ag   = (const float*)d_in[21];
  const float* ab   = (const float*)d_in[22];

  const size_t MB = 1024 * 1024;
  char* ws = (char*)d_ws;
  float*    E     = (float*)(ws + 0 * MB);       // 8 MB
  ushort_t* Ebf   = (ushort_t*)(ws + 8 * MB);    // 4 MB
  float*    QA    = (float*)(ws + 12 * MB);      // 8 MB
  ushort_t* QAbf  = (ushort_t*)(ws + 20 * MB);   // 4 MB
  ushort_t* Rbbf  = (ushort_t*)(ws + 24 * MB);   // 4 MB
  float*    Rp    = (float*)(ws + 28 * MB);      // 16 MB attn f32 partials (2 sides)
  float*    G0    = (float*)(ws + 44 * MB);      // 8 MB Wf partial kz=0
  ushort_t* KfrA  = (ushort_t*)(ws + 52 * MB);   // 4 MB
  ushort_t* VfrA  = (ushort_t*)(ws + 56 * MB);   // 4 MB
  ushort_t* QbfA  = (ushort_t*)(ws + 60 * MB);   // 4 MB
  ushort_t* KfrB  = (ushort_t*)(ws + 64 * MB);   // 4 MB
  ushort_t* VfrB  = (ushort_t*)(ws + 68 * MB);   // 4 MB
  ushort_t* QbfB  = (ushort_t*)(ws + 72 * MB);   // 4 MB
  float*    G1    = (float*)(ws + 84 * MB);      // 8 MB Wf partial kz=1
  ushort_t* Wkvqt0 = (ushort_t*)(ws + 92 * MB);  // 2 x 1.5 MB
  ushort_t* Wkvqt[2] = {Wkvqt0, Wkvqt0 + 786432};
  ushort_t* Wft0   = (ushort_t*)(ws + 95 * MB);  // 2 x 1 MB
  ushort_t* Wft[2] = {Wft0, Wft0 + 524288};
  ushort_t* aWvt0  = (ushort_t*)(ws + 97 * MB);  // 2 x 0.5 MB
  ushort_t* aWvt[2] = {aWvt0, aWvt0 + 262144};
  ushort_t* aWqt1  = (ushort_t*)(ws + 98 * MB);  // 0.5 MB
  ushort_t* aWft0  = (ushort_t*)(ws + 99 * MB);  // 2 x 1 MB
  ushort_t* aWft[2] = {aWft0, aWft0 + 524288};
  float*    Ttab   = (float*)(ws + 101 * MB);

  float* T_sc[2][3];
  for (int i = 0; i < 2; ++i)
    for (int w = 0; w < 3; ++w) T_sc[i][w] = Ttab + (size_t)(i * 3 + w) * 2048;
  float* T_cak[2] = {Ttab + 12288, Ttab + 12288 + 1024};
  float* T_caq0 = Ttab + 14336;

  const dim3 tb(32, 8);

  // ---- prep: fused weight transposes + projection tables ----
  transpose_kvq_kernel<<<dim3(16, 16, 9), tb, 0, stream>>>(sWk, sWv, sWq, aWv, aWq,
                                                           Wkvqt0, aWvt0, aWqt1);
  transpose_f_kernel<<<dim3(16, 32, 4), tb, 0, stream>>>(sWf, aWf, Wft0, aWft0);
  tabproj9_kernel<<<dim3(512, 9), 256, 0, stream>>>(in_W, in_b, cx_W, cx_b, tx_W, tx_b,
                                                    sWk, sWv, sWq, aWk, aWq, Ttab);

  // ---- initial activations ----
  affine3_kernel<<<4096, 512, 0, stream>>>(cx, cy, 0, in_W, in_b, E, Ebf);
  rank1_kernel<<<4096, 512, 0, stream>>>(txp, tx_W, tx_b, QA, QAbf);

  // ---- 8 self/cross encoder layers ----
  for (int p = 0; p < 4; ++p) {
    for (int i = 0; i < 2; ++i) {
      gemm_pack_kernel<0><<<dim3(24, 32), 256, 0, stream>>>(Ebf, Wkvqt[i], KfrA, VfrA,
                                                            QbfA);
      const float* F0 = nullptr;
      const float* F1 = nullptr;
      if (p > 0) {
        affine3kq_kernel<<<4096, 128, 0, stream>>>(cx, cy, p, T_sc[i][0], T_sc[i][2],
                                                   KfrB, QbfB);
        affine3v_frag_kernel<<<dim3(32, 8, 8), tb, 0, stream>>>(cx, cy, p, T_sc[i][1],
                                                                VfrB);
        attn_mfma_kernel<256, 2, 2><<<512, 256, 0, stream>>>(
            QbfA, QbfB, KfrA, KfrB, VfrA, VfrB, 1.0f, 2, nullptr, Rp);
        F0 = Rp; F1 = Rp + 4096 * 512;
      } else {
        // x2 is x: 4 identical sdpa terms -> 4 * sdpa(sQ,sK,sV)
        attn_mfma_kernel<256, 1, 1><<<512, 256, 0, stream>>>(
            QbfA, QbfA, KfrA, KfrA, VfrA, VfrA, 4.0f, 2, Rbbf, nullptr);
      }
      gemm_wf_kernel<<<dim3(8, 32, 2), 256, 0, stream>>>(
          Ebf, Rbbf, F0, F1, Wft[i], sbf + (size_t)i * 512, G0, G1);
      ln_kernel<<<4096, 256, 0, stream>>>(G0, G1, E, sg + (size_t)i * 512,
                                          sb + (size_t)i * 512, E, Ebf);
    }
  }

  // ---- 2 cross-attention decoder layers (nh=4, D=128) ----
  for (int i = 0; i < 2; ++i) {
    rank1_pack_kernel<<<4096, 64, 0, stream>>>(cx, T_cak[i], KfrA, 0);
    gemm_pack_kernel<1><<<dim3(8, 32), 256, 0, stream>>>(Ebf, aWvt[i], nullptr, VfrA,
                                                         nullptr);
    if (i == 0) {
      rank1_pack_kernel<<<4096, 64, 0, stream>>>(txp, T_caq0, QbfB, 1);
    } else {
      gemm_pack_kernel<2><<<dim3(8, 32), 256, 0, stream>>>(QAbf, aWqt1, nullptr, nullptr,
                                                           QbfB);
    }
    attn_mfma_kernel<128, 1, 2><<<512, 256, 0, stream>>>(
        QbfB, QbfB, KfrA, KfrA, VfrA, VfrA, 1.0f, 4, Rbbf, nullptr);
    gemm_wf_kernel<<<dim3(8, 32, 2), 256, 0, stream>>>(
        QAbf, Rbbf, nullptr, nullptr, aWft[i], abf + (size_t)i * 512, G0, G1);
    ln_kernel<<<4096, 256, 0, stream>>>(G0, G1, QA, ag + (size_t)i * 512,
                                        ab + (size_t)i * 512,
                                        (i == 1) ? (float*)d_out : QA,
                                        (i == 1) ? nullptr : QAbf);
  }
  (void)in_sizes; (void)n_in; (void)out_size; (void)ws_size;
}

// Round 13
// 962.874 us; speedup vs baseline: 1.1583x; 1.0186x over previous
//
#include <hip/hip_runtime.h>

#define DEVINL __device__ __forceinline__

typedef short bf16x8 __attribute__((ext_vector_type(8)));
typedef float f32x4 __attribute__((ext_vector_type(4)));

#define LOG2E 1.44269504088896f

DEVINL unsigned f2b(float f) {  // f32 -> bf16 bits (round to nearest even)
  unsigned u = __float_as_uint(f);
  u = (u + 0x7FFFu + ((u >> 16) & 1u)) >> 16;
  return u & 0xFFFFu;
}
DEVINL uint4 pack8(const float* v) {
  uint4 u;
  u.x = f2b(v[0]) | (f2b(v[1]) << 16);
  u.y = f2b(v[2]) | (f2b(v[3]) << 16);
  u.z = f2b(v[4]) | (f2b(v[5]) << 16);
  u.w = f2b(v[6]) | (f2b(v[7]) << 16);
  return u;
}

// ---------------- reduction helpers ----------------
DEVINL float4 block_sum4(float4 v, float4* sh) {
  const int lane = threadIdx.x & 63, wid = threadIdx.x >> 6;
#pragma unroll
  for (int o = 32; o; o >>= 1) {
    v.x += __shfl_down(v.x, o);
    v.y += __shfl_down(v.y, o);
    v.z += __shfl_down(v.z, o);
    v.w += __shfl_down(v.w, o);
  }
  __syncthreads();
  if (lane == 0) sh[wid] = v;
  __syncthreads();
  float4 a = sh[0], b = sh[1], c = sh[2], d = sh[3], r;
  r.x = a.x + b.x + c.x + d.x;
  r.y = a.y + b.y + c.y + d.y;
  r.z = a.z + b.z + c.z + d.z;
  r.w = a.w + b.w + c.w + d.w;
  return r;
}
DEVINL float block_sum1(float v, float* sh) {
  const int lane = threadIdx.x & 63, wid = threadIdx.x >> 6;
#pragma unroll
  for (int o = 32; o; o >>= 1) v += __shfl_down(v, o);
  __syncthreads();
  if (lane == 0) sh[wid] = v;
  __syncthreads();
  return sh[0] + sh[1] + sh[2] + sh[3];
}

// ---- fused table projections (9 jobs via blockIdx.y) ----
// Q-producing tables fold LOG2E (softmax uses exp2).
__global__ __launch_bounds__(256) void tabproj9_kernel(
    const float* __restrict__ in_W, const float* __restrict__ in_b,
    const float* __restrict__ cx_W, const float* __restrict__ cx_b,
    const float* __restrict__ tx_W, const float* __restrict__ tx_b,
    const float* __restrict__ sWk, const float* __restrict__ sWv,
    const float* __restrict__ sWq, const float* __restrict__ aWk,
    const float* __restrict__ aWq, float* __restrict__ Ttab) {
  const int z = blockIdx.y;
  const float* V;
  const float* bias;
  const float* W;
  float* P;
  int nvec;
  float scl = 1.f;
  if (z < 6) {
    V = in_W; bias = in_b; nvec = 3;
    const int i = z / 3, wsel = z % 3;
    W = (wsel == 0 ? sWk : wsel == 1 ? sWv : sWq) + (size_t)i * 262144;
    P = Ttab + (size_t)z * 2048;
    if (wsel == 2) scl = 0.0625f * LOG2E;
  } else if (z < 8) {
    V = cx_W; bias = cx_b; nvec = 1;
    W = aWk + (size_t)(z - 6) * 262144;
    P = Ttab + 12288 + (size_t)(z - 6) * 1024;
  } else {
    V = tx_W; bias = tx_b; nvec = 1;
    W = aWq; P = Ttab + 14336; scl = 0.08838834764831845f * LOG2E;
  }
  __shared__ float4 sh4[4];
  const int j = blockIdx.x, tid = threadIdx.x;
  float acc[4] = {0.f, 0.f, 0.f, 0.f};
  for (int kk = tid; kk < 512; kk += 256) {
    const float w = W[(size_t)kk * 512 + j];
    for (int v = 0; v < nvec; ++v) acc[v] += V[(size_t)v * 512 + kk] * w;
    acc[3] += bias[kk] * w;
  }
  float4 packed = make_float4(acc[0], acc[1], acc[2], acc[3]);
  packed = block_sum4(packed, sh4);
  if (tid == 0) {
    const float vals[4] = {packed.x * scl, packed.y * scl, packed.z * scl, packed.w * scl};
    for (int v = 0; v < nvec; ++v) P[(size_t)v * 512 + j] = vals[v];
    P[(size_t)nvec * 512 + j] = vals[3];
  }
}

// ---- fused weight transposes, K=512 (9 jobs via blockIdx.z); Q scaled w/ LOG2E ----
__global__ __launch_bounds__(256) void transpose_kvq_kernel(
    const float* __restrict__ sWk, const float* __restrict__ sWv,
    const float* __restrict__ sWq, const float* __restrict__ aWv,
    const float* __restrict__ aWq, unsigned short* __restrict__ Wkvqt0,
    unsigned short* __restrict__ aWvt0, unsigned short* __restrict__ aWqt1) {
  const int z = blockIdx.z;
  const float* src;
  unsigned short* dst;
  float scl = 1.f;
  if (z < 6) {
    const int i = z / 3, wsel = z % 3;
    src = (wsel == 0 ? sWk : wsel == 1 ? sWv : sWq) + (size_t)i * 262144;
    dst = Wkvqt0 + (size_t)i * 786432 + (size_t)wsel * 262144;
    if (wsel == 2) scl = 0.0625f * LOG2E;
  } else if (z < 8) {
    src = aWv + (size_t)(z - 6) * 262144;
    dst = aWvt0 + (size_t)(z - 6) * 262144;
  } else {
    src = aWq + 262144; dst = aWqt1; scl = 0.08838834764831845f * LOG2E;
  }
  __shared__ float tile[32][33];
  const int n0 = blockIdx.x * 32, k0 = blockIdx.y * 32;
  const int tx = threadIdx.x, ty = threadIdx.y;  // 32 x 8
#pragma unroll
  for (int r = 0; r < 4; ++r)
    tile[ty + 8 * r][tx] = src[(size_t)(k0 + ty + 8 * r) * 512 + n0 + tx];
  __syncthreads();
#pragma unroll
  for (int r = 0; r < 4; ++r)
    dst[(size_t)(n0 + ty + 8 * r) * 512 + k0 + tx] =
        (unsigned short)f2b(scl * tile[tx][ty + 8 * r]);
}

// ---- fused weight transposes, K=1024 (4 jobs via blockIdx.z) ----
__global__ __launch_bounds__(256) void transpose_f_kernel(
    const float* __restrict__ sWf, const float* __restrict__ aWf,
    unsigned short* __restrict__ Wft0, unsigned short* __restrict__ aWft0) {
  const int z = blockIdx.z;
  const float* src = (z < 2 ? sWf + (size_t)z * 524288 : aWf + (size_t)(z - 2) * 524288);
  unsigned short* dst =
      (z < 2 ? Wft0 + (size_t)z * 524288 : aWft0 + (size_t)(z - 2) * 524288);
  __shared__ float tile[32][33];
  const int n0 = blockIdx.x * 32, k0 = blockIdx.y * 32;
  const int tx = threadIdx.x, ty = threadIdx.y;  // 32 x 8
#pragma unroll
  for (int r = 0; r < 4; ++r)
    tile[ty + 8 * r][tx] = src[(size_t)(k0 + ty + 8 * r) * 512 + n0 + tx];
  __syncthreads();
#pragma unroll
  for (int r = 0; r < 4; ++r)
    dst[(size_t)(n0 + ty + 8 * r) * 1024 + k0 + tx] =
        (unsigned short)f2b(tile[tx][ty + 8 * r]);
}

// ---- merged cross-side encoder producers: K/Q rows + V frag tiles -------------
// grid = 4096 blocks x 256 threads.
//   bz < 2048 : K/Q for rows 2*bz, 2*bz+1 (128 threads each; same math as old
//               affine3kq at 128 threads/row).
//   bz >= 2048: V 32x32 tile -> Vfr (same math as old affine3v_frag;
//               vb bits: [0:4]=s-tile, [5:7]=d-tile, [8:10]=bh).
__global__ __launch_bounds__(256) void affine3kqv_kernel(
    const float* __restrict__ cx, const float* __restrict__ cy, int sel,
    const float* __restrict__ TK, const float* __restrict__ TV,
    const float* __restrict__ TQ, unsigned short* __restrict__ Kfr,
    unsigned short* __restrict__ Qbf, unsigned short* __restrict__ Vfr) {
  __shared__ float tile[32][33];
  const int bz = blockIdx.x;
  if (bz < 2048) {
    const int row = bz * 2 + (threadIdx.x >> 7);
    const int t = threadIdx.x & 127;
    const int b = row >> 10, s = row & 1023;
    const float x = cx[row];
    const float* y = cy + (size_t)row * 8 + 2 * sel;
    const float y0 = y[0], y1 = y[1];
    const bool isQ = t >= 64;
    const int c = t & 63;
    const int h = c >> 5;
    const int d0 = (c & 31) * 8;
    const float* T = isQ ? TQ : TK;
    float v[8];
#pragma unroll
    for (int j = 0; j < 8; ++j) {
      const int col = h * 256 + d0 + j;
      v[j] = x * T[col] + y0 * T[512 + col] + y1 * T[1024 + col] + T[1536 + col];
    }
    const uint4 u = pack8(v);
    const int bh = b * 2 + h;
    if (isQ) {
      *(uint4*)(Qbf + ((size_t)bh * 1024 + s) * 256 + d0) = u;
    } else {
      const int kc = d0 >> 5;
      const int lane = ((d0 & 31) >> 3) * 16 + (s & 15);
      *(uint4*)(Kfr + ((size_t)(bh * 8 + kc) * 64 + (s >> 4)) * 512 + lane * 8) = u;
    }
  } else {
    const int vb = bz - 2048;
    const int s0 = (vb & 31) * 32, d0 = ((vb >> 5) & 7) * 32;
    const int bh = vb >> 8;
    const int b = bh >> 1, h = bh & 1;
    const int tx = threadIdx.x & 31, ty = threadIdx.x >> 5;  // 32 x 8
    const int col = h * 256 + d0 + tx;
    const float tv0 = TV[col], tv1 = TV[512 + col], tv2 = TV[1024 + col],
                tv3 = TV[1536 + col];
#pragma unroll
    for (int r = 0; r < 4; ++r) {
      const int row = b * 1024 + s0 + ty + 8 * r;
      const float x = cx[row];
      const float* y = cy + (size_t)row * 8 + 2 * sel;
      tile[ty + 8 * r][tx] = x * tv0 + y[0] * tv1 + y[1] * tv2 + tv3;
    }
    __syncthreads();
    const int idx = threadIdx.x;
    if (idx < 128) {
      const int dj = idx & 31, sch = idx >> 5;
      float v[8];
#pragma unroll
      for (int jj = 0; jj < 8; ++jj) v[jj] = tile[sch * 8 + jj][dj];
      const uint4 u = pack8(v);
      const int sc = s0 >> 5;
      const int dtile = (d0 + dj) >> 4;
      const int lane = sch * 16 + (dj & 15);
      *(uint4*)(Vfr + ((size_t)(bh * 32 + sc) * 16 + dtile) * 512 + lane * 8) = u;
    }
  }
}

// ---- decoder rank-1 producers (nh=4, D=128): T rows [0]=w, [1]=bias ----
__global__ __launch_bounds__(64) void rank1_pack_kernel(
    const float* __restrict__ x, const float* __restrict__ T,
    unsigned short* __restrict__ dst, int isQ) {
  const int row = blockIdx.x;
  const int b = row >> 10, s = row & 1023;
  const float xv = x[row];
  const int c = threadIdx.x;        // 64 chunks of 8
  const int h = c >> 4;             // 16 chunks per head
  const int d0 = (c & 15) * 8;
  float v[8];
#pragma unroll
  for (int j = 0; j < 8; ++j) {
    const int col = h * 128 + d0 + j;
    v[j] = xv * T[col] + T[512 + col];
  }
  const uint4 u = pack8(v);
  const int bh = b * 4 + h;
  if (isQ) {
    *(uint4*)(dst + ((size_t)bh * 1024 + s) * 128 + d0) = u;
  } else {
    const int kc = d0 >> 5;
    const int lane = ((d0 & 31) >> 3) * 16 + (s & 15);
    *(uint4*)(dst + ((size_t)(bh * 4 + kc) * 64 + (s >> 4)) * 512 + lane * 8) = u;
  }
}

// ---- merged decoder i=0 producers: t<64 K from (xk,Tk), t>=64 Q from (xq,Tq) ----
__global__ __launch_bounds__(128) void rank1kq_kernel(
    const float* __restrict__ xk, const float* __restrict__ Tk,
    unsigned short* __restrict__ dstK, const float* __restrict__ xq,
    const float* __restrict__ Tq, unsigned short* __restrict__ dstQ) {
  const int row = blockIdx.x;
  const int b = row >> 10, s = row & 1023;
  const bool isQ = threadIdx.x >= 64;
  const float xv = isQ ? xq[row] : xk[row];
  const float* T = isQ ? Tq : Tk;
  const int c = threadIdx.x & 63;
  const int h = c >> 4;
  const int d0 = (c & 15) * 8;
  float v[8];
#pragma unroll
  for (int j = 0; j < 8; ++j) {
    const int col = h * 128 + d0 + j;
    v[j] = xv * T[col] + T[512 + col];
  }
  const uint4 u = pack8(v);
  const int bh = b * 4 + h;
  if (isQ) {
    *(uint4*)(dstQ + ((size_t)bh * 1024 + s) * 128 + d0) = u;
  } else {
    const int kc = d0 >> 5;
    const int lane = ((d0 & 31) >> 3) * 16 + (s & 15);
    *(uint4*)(dstK + ((size_t)(bh * 4 + kc) * 64 + (s >> 4)) * 512 + lane * 8) = u;
  }
}

// ---- merged initial activations: y=0 affine3(sel=0)->E/Ebf, y=1 rank1->QA/QAbf ----
__global__ __launch_bounds__(512) void init2_kernel(
    const float* __restrict__ cx, const float* __restrict__ cy,
    const float* __restrict__ in_W, const float* __restrict__ in_b,
    const float* __restrict__ txp, const float* __restrict__ tx_W,
    const float* __restrict__ tx_b, float* __restrict__ E,
    unsigned short* __restrict__ Ebf, float* __restrict__ QA,
    unsigned short* __restrict__ QAbf) {
  const int r = blockIdx.x, j = threadIdx.x;
  if (blockIdx.y == 0) {
    const float* y = cy + (size_t)r * 8;
    const float v = cx[r] * in_W[j] + y[0] * in_W[512 + j] + y[1] * in_W[1024 + j] +
                    in_b[j];
    E[(size_t)r * 512 + j] = v;
    Ebf[(size_t)r * 512 + j] = (unsigned short)f2b(v);
  } else {
    const float v = txp[r] * tx_W[j] + tx_b[j];
    QA[(size_t)r * 512 + j] = v;
    QAbf[(size_t)r * 512 + j] = (unsigned short)f2b(v);
  }
}

// ------------- split-K Wf GEMM (double-buffered): two K-halves via blockIdx.z ----
// XCD-aware block swizzle: same-bm blocks (sharing A panel) stay on one XCD.
__global__ __launch_bounds__(256) void gemm_wf_kernel(
    const unsigned short* __restrict__ A0, const unsigned short* __restrict__ A1,
    const float* __restrict__ F0, const float* __restrict__ F1,
    const unsigned short* __restrict__ Wt, const float* __restrict__ bias,
    float* __restrict__ C0, float* __restrict__ C1) {
  constexpr int BM = 128, BN = 64, BK = 32, LDP = 40, K = 512, N = 512;
  __shared__ unsigned short As[2][BM * LDP];
  __shared__ unsigned short Bs[2][BN * LDP];
  const int kz = blockIdx.z;
  const int tid = threadIdx.x;
  const int lane = tid & 63, w = tid >> 6;
  const int lin = blockIdx.y * 8 + blockIdx.x;      // 256 blocks per kz
  const int swz = (lin & 7) * 32 + (lin >> 3);      // bijective, 256%8==0
  const int bm = (swz >> 3) * BM, bn = (swz & 7) * BN;
  const int wm = (w & 1) * 64, wn = (w >> 1) * 32;
  const int l15 = lane & 15, lq = lane >> 4;
  const int ar = tid >> 1, ac = (tid & 1) * 16;
  const int br = tid >> 2, bc = (tid & 3) * 8;
  const unsigned short* A = kz ? A1 : A0;
  const bool useF = (kz != 0) && (F0 != nullptr);
  const size_t arow = (size_t)(bm + ar) * 512;
  const size_t brow = (size_t)(bn + br) * 1024 + (size_t)kz * 512;
  f32x4 acc[4][2] = {};
  uint4 ra0, ra1, rb0;
#define GLOAD(k0_)                                                          \
  do {                                                                      \
    if (useF) {                                                             \
      const float* p0 = F0 + arow + (k0_) + ac;                             \
      const float* p1 = F1 + arow + (k0_) + ac;                             \
      float s[16];                                                          \
      const float4 x0 = *(const float4*)p0, x1 = *(const float4*)(p0 + 4);  \
      const float4 x2 = *(const float4*)(p0 + 8), x3 = *(const float4*)(p0 + 12); \
      const float4 y0 = *(const float4*)p1, y1 = *(const float4*)(p1 + 4);  \
      const float4 y2 = *(const float4*)(p1 + 8), y3 = *(const float4*)(p1 + 12); \
      s[0] = x0.x + y0.x; s[1] = x0.y + y0.y; s[2] = x0.z + y0.z; s[3] = x0.w + y0.w; \
      s[4] = x1.x + y1.x; s[5] = x1.y + y1.y; s[6] = x1.z + y1.z; s[7] = x1.w + y1.w; \
      s[8] = x2.x + y2.x; s[9] = x2.y + y2.y; s[10] = x2.z + y2.z; s[11] = x2.w + y2.w; \
      s[12] = x3.x + y3.x; s[13] = x3.y + y3.y; s[14] = x3.z + y3.z; s[15] = x3.w + y3.w; \
      ra0 = pack8(s); ra1 = pack8(s + 8);                                   \
    } else {                                                                \
      ra0 = *(const uint4*)(A + arow + (k0_) + ac);                         \
      ra1 = *(const uint4*)(A + arow + (k0_) + ac + 8);                     \
    }                                                                       \
    rb0 = *(const uint4*)(Wt + brow + (k0_) + bc);                          \
  } while (0)
  GLOAD(0);
  *(uint4*)(As[0] + ar * LDP + ac) = ra0;
  *(uint4*)(As[0] + ar * LDP + ac + 8) = ra1;
  *(uint4*)(Bs[0] + br * LDP + bc) = rb0;
  __syncthreads();
  int buf = 0;
  for (int k0 = 0; k0 < K; k0 += BK) {
    const bool more = (k0 + BK) < K;
    if (more) GLOAD(k0 + BK);
    bf16x8 af[4], bfr[2];
#pragma unroll
    for (int mt = 0; mt < 4; ++mt)
      af[mt] = *(const bf16x8*)(As[buf] + (wm + mt * 16 + l15) * LDP + lq * 8);
#pragma unroll
    for (int nt = 0; nt < 2; ++nt)
      bfr[nt] = *(const bf16x8*)(Bs[buf] + (wn + nt * 16 + l15) * LDP + lq * 8);
#pragma unroll
    for (int mt = 0; mt < 4; ++mt)
#pragma unroll
      for (int nt = 0; nt < 2; ++nt)
        acc[mt][nt] =
            __builtin_amdgcn_mfma_f32_16x16x32_bf16(af[mt], bfr[nt], acc[mt][nt], 0, 0, 0);
    if (more) {
      *(uint4*)(As[buf ^ 1] + ar * LDP + ac) = ra0;
      *(uint4*)(As[buf ^ 1] + ar * LDP + ac + 8) = ra1;
      *(uint4*)(Bs[buf ^ 1] + br * LDP + bc) = rb0;
    }
    __syncthreads();
    buf ^= 1;
  }
#undef GLOAD
  float* C = kz ? C1 : C0;
#pragma unroll
  for (int nt = 0; nt < 2; ++nt) {
    const int col = bn + wn + nt * 16 + l15;
    const float bv = (kz && bias) ? bias[col] : 0.f;
#pragma unroll
    for (int mt = 0; mt < 4; ++mt) {
#pragma unroll
      for (int r = 0; r < 4; ++r) {
        const int row = bm + wm + mt * 16 + lq * 4 + r;
        C[(size_t)row * N + col] = acc[mt][nt][r] + bv;
      }
    }
  }
}

// ------- MFMA GEMM with fused frag-pack epilogue (K=512, single A) ---------------
// MODE 0: N=1536 = K|V|Q sections, nh=2, D=256 -> Kfr, Vfr, Qbf
// MODE 1: N=512  = V only, nh=4, D=128 -> Vfr
// MODE 2: N=512  = Q only, nh=4, D=128 -> Qbf (weights pre-scaled)
// XCD-aware swizzle: same-bm blocks (sharing A panel) stay on one XCD.
template <int MODE>
__global__ __launch_bounds__(256) void gemm_pack_kernel(
    const unsigned short* __restrict__ A0, const unsigned short* __restrict__ Wt,
    unsigned short* __restrict__ Kfr, unsigned short* __restrict__ Vfr,
    unsigned short* __restrict__ Qbf) {
  constexpr int BM = 128, BN = 64, BK = 32, LDP = 40, K = 512;
  __shared__ unsigned short As[2][BM * LDP];
  __shared__ unsigned short Bs[2][BN * LDP];
  const int tid = threadIdx.x;
  const int lane = tid & 63, w = tid >> 6;
  const int nbx = gridDim.x;
  const int lin = blockIdx.y * nbx + blockIdx.x;
  const int nwg = nbx * gridDim.y;                  // 768 or 256, both %8==0
  const int swz = (lin & 7) * (nwg >> 3) + (lin >> 3);
  const int bm = (swz / nbx) * BM, bn = (swz % nbx) * BN;
  const int wm = (w & 1) * 64, wn = (w >> 1) * 32;
  const int l15 = lane & 15, lq = lane >> 4;
  const int ar = tid >> 1, ac = (tid & 1) * 16;
  const int br = tid >> 2, bc = (tid & 3) * 8;
  f32x4 acc[4][2] = {};
  uint4 ra0 = *(const uint4*)(A0 + (size_t)(bm + ar) * K + ac);
  uint4 ra1 = *(const uint4*)(A0 + (size_t)(bm + ar) * K + ac + 8);
  uint4 rb0 = *(const uint4*)(Wt + (size_t)(bn + br) * K + bc);
  *(uint4*)(As[0] + ar * LDP + ac) = ra0;
  *(uint4*)(As[0] + ar * LDP + ac + 8) = ra1;
  *(uint4*)(Bs[0] + br * LDP + bc) = rb0;
  __syncthreads();
  int buf = 0;
  for (int k0 = 0; k0 < K; k0 += BK) {
    const bool more = (k0 + BK) < K;
    if (more) {
      ra0 = *(const uint4*)(A0 + (size_t)(bm + ar) * K + k0 + BK + ac);
      ra1 = *(const uint4*)(A0 + (size_t)(bm + ar) * K + k0 + BK + ac + 8);
      rb0 = *(const uint4*)(Wt + (size_t)(bn + br) * K + k0 + BK + bc);
    }
    bf16x8 af[4], bfr[2];
#pragma unroll
    for (int mt = 0; mt < 4; ++mt)
      af[mt] = *(const bf16x8*)(As[buf] + (wm + mt * 16 + l15) * LDP + lq * 8);
#pragma unroll
    for (int nt = 0; nt < 2; ++nt)
      bfr[nt] = *(const bf16x8*)(Bs[buf] + (wn + nt * 16 + l15) * LDP + lq * 8);
#pragma unroll
    for (int mt = 0; mt < 4; ++mt)
#pragma unroll
      for (int nt = 0; nt < 2; ++nt)
        acc[mt][nt] =
            __builtin_amdgcn_mfma_f32_16x16x32_bf16(af[mt], bfr[nt], acc[mt][nt], 0, 0, 0);
    if (more) {
      *(uint4*)(As[buf ^ 1] + ar * LDP + ac) = ra0;
      *(uint4*)(As[buf ^ 1] + ar * LDP + ac + 8) = ra1;
      *(uint4*)(Bs[buf ^ 1] + br * LDP + bc) = rb0;
    }
    __syncthreads();
    buf ^= 1;
  }
  // ---- fused pack epilogue ----
  const int b = bm >> 10;
  const int s0base = (bm & 1023) + wm + lq * 4;
#pragma unroll
  for (int nt = 0; nt < 2; ++nt) {
    const int col = bn + wn + nt * 16 + l15;
    int sec, h, d, nh2, Dv;
    if constexpr (MODE == 0) {
      sec = col >> 9; const int c = col & 511; h = c >> 8; d = c & 255; nh2 = 2; Dv = 256;
    } else if constexpr (MODE == 1) {
      sec = 1; h = col >> 7; d = col & 127; nh2 = 4; Dv = 128;
    } else {
      sec = 2; h = col >> 7; d = col & 127; nh2 = 4; Dv = 128;
    }
    const int bh = b * nh2 + h;
#pragma unroll
    for (int mt = 0; mt < 4; ++mt) {
      const int s0 = s0base + mt * 16;
      const float* a = (const float*)&acc[mt][nt];
      if (sec == 2) {                           // Q: [bh][s][Dv]
        unsigned short* q = Qbf + ((size_t)bh * 1024 + s0) * Dv + d;
#pragma unroll
        for (int r = 0; r < 4; ++r) q[(size_t)r * Dv] = (unsigned short)f2b(a[r]);
      } else if (sec == 0) {                    // K frag
        unsigned short* kp = Kfr +
            ((size_t)(bh * 8 + (d >> 5)) * 64 + (s0 >> 4)) * 512 +
            ((d & 31) >> 3) * 128 + (d & 7);
#pragma unroll
        for (int r = 0; r < 4; ++r)
          kp[((s0 & 15) + r) * 8] = (unsigned short)f2b(a[r]);
      } else {                                  // V frag
        unsigned short* vp = Vfr +
            ((size_t)(bh * 32 + (s0 >> 5)) * (Dv / 16) + (d >> 4)) * 512 +
            (((s0 >> 3) & 3) * 16 + (d & 15)) * 8 + (s0 & 7);
        uint2 u;
        u.x = f2b(a[0]) | (f2b(a[1]) << 16);
        u.y = f2b(a[2]) | (f2b(a[3]) << 16);
        *(uint2*)vp = u;
      }
    }
  }
}

// -------- MFMA flash attention, chunked keys + deferred normalization -----------
// Block = QT*16 q rows of one (b,head) vs ONE KV side, keys in 4 chunks of 256
// (R8-proven config; 128-key chunks regressed -22%, R9 post-mortem).
// No-max softmax => O = (sum_k exp2(s) V) / (sum_k exp2(s)) accumulated per chunk;
// normalization applied once at the end.  NQS Q-sets share K and V loads.
// All register arrays statically indexed (rule #20); c/kc/sc feed addresses only.
// NQS==2: grid = 2*256, side = bx>>8; writes f32 partials to Rp.
// NQS==1: writes bf16 with post_scale.
template <int D, int NQS, int QT>
__global__ __launch_bounds__(256, 2) void attn_mfma_kernel(
    const unsigned short* __restrict__ Qa, const unsigned short* __restrict__ Qb,
    const unsigned short* __restrict__ KfrA, const unsigned short* __restrict__ KfrB,
    const unsigned short* __restrict__ VfrA, const unsigned short* __restrict__ VfrB,
    float post_scale, int nh, unsigned short* __restrict__ R,
    float* __restrict__ Rp) {
  constexpr int QP = D + 8;      // qsh pitch
  constexpr int SP = 256 + 8;    // strip pitch (chunk = 256 keys)
  constexpr int DT = D / 64;     // d-tiles per wave
  constexpr int NR = QT * 16;    // q rows per block
  const int tid = threadIdx.x;
  const int lane = tid & 63, w = tid >> 6;
  const int l15 = lane & 15, lq = lane >> 4;
  const int nbh = 4 * nh;
  int bx = blockIdx.x;
  int side = 0;
  if constexpr (NQS == 2) { side = bx >> 8; bx &= 255; }
  const int bh = bx % nbh;       // XCD-local (b,h): same-bh blocks share an XCD's L2
  const int qb = (bx / nbh) * NR;
  const int b = bh / nh, head = bh % nh;
  const size_t rowb = (size_t)b * 1024;
  const int colo = head * D;

  __shared__ unsigned short qsh[NQS * NR * QP];
  __shared__ unsigned short ssh[NQS * NR * SP];
  __shared__ float red[NQS * QT * 4 * 16];

  // ---- stage Q ----
  for (int idx = tid; idx < NQS * NR * (D / 8); idx += 256) {
    const int set = idx / (NR * (D / 8));
    const int rem = idx - set * NR * (D / 8);
    const int r = rem / (D / 8), ch = rem - r * (D / 8);
    const unsigned short* Q = set ? Qb : Qa;
    const uint4 u = *(const uint4*)(Q + ((size_t)bh * 1024 + qb + r) * D + ch * 8);
    *(uint4*)(qsh + (set * NR + r) * QP + ch * 8) = u;
  }
  __syncthreads();

  const unsigned short* Kp = (side ? KfrB : KfrA) + (size_t)bh * ((size_t)D * 1024);
  const unsigned short* Vp = (side ? VfrB : VfrA) + (size_t)bh * ((size_t)D * 1024);

  float psum[QT][NQS][4];
#pragma unroll
  for (int qt = 0; qt < QT; ++qt)
#pragma unroll
    for (int s2 = 0; s2 < NQS; ++s2)
#pragma unroll
      for (int r = 0; r < 4; ++r) psum[qt][s2][r] = 0.f;
  f32x4 acc_o[QT][NQS][DT] = {};

#pragma unroll 1
  for (int c = 0; c < 4; ++c) {        // c only feeds addresses (safe runtime)
    // ---- QK^T for chunk: wave w owns stiles c*16 + w*4 .. +3 (keys w*64..+63) ----
    f32x4 sacc[QT][NQS][4] = {};
#pragma unroll 1
    for (int kc = 0; kc < D / 32; ++kc) {
      bf16x8 kf[4];
#pragma unroll
      for (int st = 0; st < 4; ++st)
        kf[st] = *(const bf16x8*)(
            Kp + ((size_t)kc * 64 + c * 16 + w * 4 + st) * 512 + lane * 8);
      bf16x8 qf[QT][NQS];
#pragma unroll
      for (int qt = 0; qt < QT; ++qt)
#pragma unroll
        for (int s2 = 0; s2 < NQS; ++s2)
          qf[qt][s2] = *(const bf16x8*)(
              qsh + (s2 * NR + qt * 16 + l15) * QP + kc * 32 + lq * 8);
      __builtin_amdgcn_s_setprio(1);
#pragma unroll
      for (int st = 0; st < 4; ++st)
#pragma unroll
        for (int qt = 0; qt < QT; ++qt)
#pragma unroll
          for (int s2 = 0; s2 < NQS; ++s2)
            sacc[qt][s2][st] = __builtin_amdgcn_mfma_f32_16x16x32_bf16(
                qf[qt][s2], kf[st], sacc[qt][s2][st], 0, 0, 0);
      __builtin_amdgcn_s_setprio(0);
    }
    // ---- exp2 + running sums + strip write (unnormalized weights) ----
#pragma unroll
    for (int qt = 0; qt < QT; ++qt)
#pragma unroll
      for (int s2 = 0; s2 < NQS; ++s2)
#pragma unroll
        for (int st = 0; st < 4; ++st)
#pragma unroll
          for (int r = 0; r < 4; ++r) {
            const float e = exp2f(sacc[qt][s2][st][r]);
            psum[qt][s2][r] += e;
            ssh[(s2 * NR + qt * 16 + lq * 4 + r) * SP + (w * 4 + st) * 16 + l15] =
                (unsigned short)f2b(e);
          }
    __syncthreads();
    // ---- PV: V loaded once, serves all Q-sets ----
#pragma unroll 1
    for (int sc = 0; sc < 8; sc += 2) {
      bf16x8 vb[2][DT], pa[2][QT][NQS];
#pragma unroll
      for (int u = 0; u < 2; ++u) {
#pragma unroll
        for (int dt = 0; dt < DT; ++dt)
          vb[u][dt] = *(const bf16x8*)(
              Vp + ((size_t)(c * 8 + sc + u) * (D / 16) + w * DT + dt) * 512 + lane * 8);
#pragma unroll
        for (int qt = 0; qt < QT; ++qt)
#pragma unroll
          for (int s2 = 0; s2 < NQS; ++s2)
            pa[u][qt][s2] = *(const bf16x8*)(
                ssh + (s2 * NR + qt * 16 + l15) * SP + (sc + u) * 32 + lq * 8);
      }
      __builtin_amdgcn_s_setprio(1);
#pragma unroll
      for (int u = 0; u < 2; ++u)
#pragma unroll
        for (int qt = 0; qt < QT; ++qt)
#pragma unroll
          for (int s2 = 0; s2 < NQS; ++s2)
#pragma unroll
            for (int dt = 0; dt < DT; ++dt)
              acc_o[qt][s2][dt] = __builtin_amdgcn_mfma_f32_16x16x32_bf16(
                  pa[u][qt][s2], vb[u][dt], acc_o[qt][s2][dt], 0, 0, 0);
      __builtin_amdgcn_s_setprio(0);
    }
    __syncthreads();
  }

  // ---- final row sums: reduce over 16 key-lanes, then over 4 waves ----
#pragma unroll
  for (int o = 1; o < 16; o <<= 1)
#pragma unroll
    for (int qt = 0; qt < QT; ++qt)
#pragma unroll
      for (int s2 = 0; s2 < NQS; ++s2)
#pragma unroll
        for (int r = 0; r < 4; ++r)
          psum[qt][s2][r] += __shfl_xor(psum[qt][s2][r], o);
  if (l15 == 0) {
#pragma unroll
    for (int qt = 0; qt < QT; ++qt)
#pragma unroll
      for (int s2 = 0; s2 < NQS; ++s2)
#pragma unroll
        for (int r = 0; r < 4; ++r)
          red[((s2 * QT + qt) * 4 + w) * 16 + lq * 4 + r] = psum[qt][s2][r];
  }
  __syncthreads();
  float inv[QT][NQS][4];
#pragma unroll
  for (int qt = 0; qt < QT; ++qt)
#pragma unroll
    for (int s2 = 0; s2 < NQS; ++s2)
#pragma unroll
      for (int r = 0; r < 4; ++r) {
        const float* rp = red + ((s2 * QT + qt) * 4) * 16 + lq * 4 + r;
        inv[qt][s2][r] = 1.f / (rp[0] + rp[16] + rp[32] + rp[48]);
      }

  // ---- epilogue: normalize + write ----
  if constexpr (NQS == 2) {
    float* base = Rp + (size_t)side * (4096 * 512);
#pragma unroll
    for (int qt = 0; qt < QT; ++qt)
#pragma unroll
      for (int dt = 0; dt < DT; ++dt)
#pragma unroll
        for (int r = 0; r < 4; ++r) {
          const int q = qb + qt * 16 + lq * 4 + r;
          const int d = w * (DT * 16) + dt * 16 + l15;
          base[(rowb + q) * 512 + colo + d] =
              acc_o[qt][0][dt][r] * inv[qt][0][r] + acc_o[qt][1][dt][r] * inv[qt][1][r];
        }
  } else {
#pragma unroll
    for (int qt = 0; qt < QT; ++qt)
#pragma unroll
      for (int dt = 0; dt < DT; ++dt)
#pragma unroll
        for (int r = 0; r < 4; ++r) {
          const int q = qb + qt * 16 + lq * 4 + r;
          const int d = w * (DT * 16) + dt * 16 + l15;
          R[(rowb + q) * 512 + colo + d] =
              (unsigned short)f2b(acc_o[qt][0][dt][r] * inv[qt][0][r] * post_scale);
        }
  }
}

// ---- out = LayerNorm(G0 + G1 + res) * g + b  (f32 out + optional bf16 out) ----
__global__ __launch_bounds__(256) void ln_kernel(
    const float* __restrict__ G0, const float* __restrict__ G1,
    const float* __restrict__ res, const float* __restrict__ g,
    const float* __restrict__ b, float* __restrict__ out,
    unsigned short* __restrict__ outb) {
  __shared__ float sh[4];
  const int row = blockIdx.x, tid = threadIdx.x;
  const size_t off = (size_t)row * 512;
  const float x0 = G0[off + tid] + G1[off + tid] + res[off + tid];
  const float x1 = G0[off + tid + 256] + G1[off + tid + 256] + res[off + tid + 256];
  const float mean = block_sum1(x0 + x1, sh) * (1.0f / 512.0f);
  const float d0 = x0 - mean, d1 = x1 - mean;
  const float var = block_sum1(d0 * d0 + d1 * d1, sh) * (1.0f / 512.0f);
  const float inv = rsqrtf(var + 1e-5f);
  const float y0 = d0 * inv * g[tid] + b[tid];
  const float y1 = d1 * inv * g[tid + 256] + b[tid + 256];
  out[off + tid] = y0;
  out[off + tid + 256] = y1;
  if (outb) {
    outb[off + tid] = (unsigned short)f2b(y0);
    outb[off + tid + 256] = (unsigned short)f2b(y1);
  }
}

extern "C" void kernel_launch(void* const* d_in, const int* in_sizes, int n_in,
                              void* d_out, int out_size, void* d_ws, size_t ws_size,
                              hipStream_t stream) {
  typedef unsigned short ushort_t;
  const float* cx   = (const float*)d_in[0];
  const float* cy   = (const float*)d_in[1];
  const float* txp  = (const float*)d_in[2];
  const float* in_W = (const float*)d_in[3];
  const float* in_b = (const float*)d_in[4];
  const float* cx_W = (const float*)d_in[5];
  const float* cx_b = (const float*)d_in[6];
  const float* tx_W = (const float*)d_in[7];
  const float* tx_b = (const float*)d_in[8];
  const float* sWk  = (const float*)d_in[9];
  const float* sWv  = (const float*)d_in[10];
  const float* sWq  = (const float*)d_in[11];
  const float* sWf  = (const float*)d_in[12];
  const float* sbf  = (const float*)d_in[13];
  const float* sg   = (const float*)d_in[14];
  const float* sb   = (const float*)d_in[15];
  const float* aWk  = (const float*)d_in[16];
  const float* aWv  = (const float*)d_in[17];
  const float* aWq  = (const float*)d_in[18];
  const float* aWf  = (const float*)d_in[19];
  const float* abf  = (const float*)d_in[20];
  const float* ag   = (const float*)d_in[21];
  const float* ab   = (const float*)d_in[22];

  const size_t MB = 1024 * 1024;
  char* ws = (char*)d_ws;
  float*    E     = (float*)(ws + 0 * MB);       // 8 MB
  ushort_t* Ebf   = (ushort_t*)(ws + 8 * MB);    // 4 MB
  float*    QA    = (float*)(ws + 12 * MB);      // 8 MB
  ushort_t* QAbf  = (ushort_t*)(ws + 20 * MB);   // 4 MB
  ushort_t* Rbbf  = (ushort_t*)(ws + 24 * MB);   // 4 MB
  float*    Rp    = (float*)(ws + 28 * MB);      // 16 MB attn f32 partials (2 sides)
  float*    G0    = (float*)(ws + 44 * MB);      // 8 MB Wf partial kz=0
  ushort_t* KfrA  = (ushort_t*)(ws + 52 * MB);   // 4 MB
  ushort_t* VfrA  = (ushort_t*)(ws + 56 * MB);   // 4 MB
  ushort_t* QbfA  = (ushort_t*)(ws + 60 * MB);   // 4 MB
  ushort_t* KfrB  = (ushort_t*)(ws + 64 * MB);   // 4 MB
  ushort_t* VfrB  = (ushort_t*)(ws + 68 * MB);   // 4 MB
  ushort_t* QbfB  = (ushort_t*)(ws + 72 * MB);   // 4 MB
  float*    G1    = (float*)(ws + 84 * MB);      // 8 MB Wf partial kz=1
  ushort_t* Wkvqt0 = (ushort_t*)(ws + 92 * MB);  // 2 x 1.5 MB
  ushort_t* Wkvqt[2] = {Wkvqt0, Wkvqt0 + 786432};
  ushort_t* Wft0   = (ushort_t*)(ws + 95 * MB);  // 2 x 1 MB
  ushort_t* Wft[2] = {Wft0, Wft0 + 524288};
  ushort_t* aWvt0  = (ushort_t*)(ws + 97 * MB);  // 2 x 0.5 MB
  ushort_t* aWvt[2] = {aWvt0, aWvt0 + 262144};
  ushort_t* aWqt1  = (ushort_t*)(ws + 98 * MB);  // 0.5 MB
  ushort_t* aWft0  = (ushort_t*)(ws + 99 * MB);  // 2 x 1 MB
  ushort_t* aWft[2] = {aWft0, aWft0 + 524288};
  float*    Ttab   = (float*)(ws + 101 * MB);

  float* T_sc[2][3];
  for (int i = 0; i < 2; ++i)
    for (int w = 0; w < 3; ++w) T_sc[i][w] = Ttab + (size_t)(i * 3 + w) * 2048;
  float* T_cak[2] = {Ttab + 12288, Ttab + 12288 + 1024};
  float* T_caq0 = Ttab + 14336;

  const dim3 tb(32, 8);

  // ---- prep: fused weight transposes + projection tables ----
  transpose_kvq_kernel<<<dim3(16, 16, 9), tb, 0, stream>>>(sWk, sWv, sWq, aWv, aWq,
                                                           Wkvqt0, aWvt0, aWqt1);
  transpose_f_kernel<<<dim3(16, 32, 4), tb, 0, stream>>>(sWf, aWf, Wft0, aWft0);
  tabproj9_kernel<<<dim3(512, 9), 256, 0, stream>>>(in_W, in_b, cx_W, cx_b, tx_W, tx_b,
                                                    sWk, sWv, sWq, aWk, aWq, Ttab);

  // ---- initial activations (merged) ----
  init2_kernel<<<dim3(4096, 2), 512, 0, stream>>>(cx, cy, in_W, in_b, txp, tx_W, tx_b,
                                                  E, Ebf, QA, QAbf);

  // ---- 8 self/cross encoder layers ----
  for (int p = 0; p < 4; ++p) {
    for (int i = 0; i < 2; ++i) {
      gemm_pack_kernel<0><<<dim3(24, 32), 256, 0, stream>>>(Ebf, Wkvqt[i], KfrA, VfrA,
                                                            QbfA);
      const float* F0 = nullptr;
      const float* F1 = nullptr;
      if (p > 0) {
        affine3kqv_kernel<<<4096, 256, 0, stream>>>(cx, cy, p, T_sc[i][0], T_sc[i][1],
                                                    T_sc[i][2], KfrB, QbfB, VfrB);
        attn_mfma_kernel<256, 2, 2><<<512, 256, 0, stream>>>(
            QbfA, QbfB, KfrA, KfrB, VfrA, VfrB, 1.0f, 2, nullptr, Rp);
        F0 = Rp; F1 = Rp + 4096 * 512;
      } else {
        // x2 is x: 4 identical sdpa terms -> 4 * sdpa(sQ,sK,sV)
        attn_mfma_kernel<256, 1, 1><<<512, 256, 0, stream>>>(
            QbfA, QbfA, KfrA, KfrA, VfrA, VfrA, 4.0f, 2, Rbbf, nullptr);
      }
      gemm_wf_kernel<<<dim3(8, 32, 2), 256, 0, stream>>>(
          Ebf, Rbbf, F0, F1, Wft[i], sbf + (size_t)i * 512, G0, G1);
      ln_kernel<<<4096, 256, 0, stream>>>(G0, G1, E, sg + (size_t)i * 512,
                                          sb + (size_t)i * 512, E, Ebf);
    }
  }

  // ---- 2 cross-attention decoder layers (nh=4, D=128) ----
  for (int i = 0; i < 2; ++i) {
    if (i == 0) {
      rank1kq_kernel<<<4096, 128, 0, stream>>>(cx, T_cak[0], KfrA, txp, T_caq0, QbfB);
    } else {
      rank1_pack_kernel<<<4096, 64, 0, stream>>>(cx, T_cak[1], KfrA, 0);
    }
    gemm_pack_kernel<1><<<dim3(8, 32), 256, 0, stream>>>(Ebf, aWvt[i], nullptr, VfrA,
                                                         nullptr);
    if (i == 1) {
      gemm_pack_kernel<2><<<dim3(8, 32), 256, 0, stream>>>(QAbf, aWqt1, nullptr, nullptr,
                                                           QbfB);
    }
    attn_mfma_kernel<128, 1, 2><<<512, 256, 0, stream>>>(
        QbfB, QbfB, KfrA, KfrA, VfrA, VfrA, 1.0f, 4, Rbbf, nullptr);
    gemm_wf_kernel<<<dim3(8, 32, 2), 256, 0, stream>>>(
        QAbf, Rbbf, nullptr, nullptr, aWft[i], abf + (size_t)i * 512, G0, G1);
    ln_kernel<<<4096, 256, 0, stream>>>(G0, G1, QA, ag + (size_t)i * 512,
                                        ab + (size_t)i * 512,
                                        (i == 1) ? (float*)d_out : QA,
                                        (i == 1) ? nullptr : QAbf);
  }
  (void)in_sizes; (void)n_in; (void)out_size; (void)ws_size;
}

// Round 14
// 947.572 us; speedup vs baseline: 1.1770x; 1.0161x over previous
//
#include <hip/hip_runtime.h>

#define DEVINL __device__ __forceinline__

typedef short bf16x8 __attribute__((ext_vector_type(8)));
typedef float f32x4 __attribute__((ext_vector_type(4)));

#define LOG2E 1.44269504088896f

DEVINL unsigned f2b(float f) {  // f32 -> bf16 bits (round to nearest even)
  unsigned u = __float_as_uint(f);
  u = (u + 0x7FFFu + ((u >> 16) & 1u)) >> 16;
  return u & 0xFFFFu;
}
DEVINL uint4 pack8(const float* v) {
  uint4 u;
  u.x = f2b(v[0]) | (f2b(v[1]) << 16);
  u.y = f2b(v[2]) | (f2b(v[3]) << 16);
  u.z = f2b(v[4]) | (f2b(v[5]) << 16);
  u.w = f2b(v[6]) | (f2b(v[7]) << 16);
  return u;
}

// ---------------- reduction helpers ----------------
DEVINL float4 block_sum4(float4 v, float4* sh) {
  const int lane = threadIdx.x & 63, wid = threadIdx.x >> 6;
#pragma unroll
  for (int o = 32; o; o >>= 1) {
    v.x += __shfl_down(v.x, o);
    v.y += __shfl_down(v.y, o);
    v.z += __shfl_down(v.z, o);
    v.w += __shfl_down(v.w, o);
  }
  __syncthreads();
  if (lane == 0) sh[wid] = v;
  __syncthreads();
  float4 a = sh[0], b = sh[1], c = sh[2], d = sh[3], r;
  r.x = a.x + b.x + c.x + d.x;
  r.y = a.y + b.y + c.y + d.y;
  r.z = a.z + b.z + c.z + d.z;
  r.w = a.w + b.w + c.w + d.w;
  return r;
}
DEVINL float block_sum1(float v, float* sh) {
  const int lane = threadIdx.x & 63, wid = threadIdx.x >> 6;
#pragma unroll
  for (int o = 32; o; o >>= 1) v += __shfl_down(v, o);
  __syncthreads();
  if (lane == 0) sh[wid] = v;
  __syncthreads();
  return sh[0] + sh[1] + sh[2] + sh[3];
}

// ---- fused table projections (9 jobs via blockIdx.y) ----
// Q-producing tables fold LOG2E (softmax uses exp2).
__global__ __launch_bounds__(256) void tabproj9_kernel(
    const float* __restrict__ in_W, const float* __restrict__ in_b,
    const float* __restrict__ cx_W, const float* __restrict__ cx_b,
    const float* __restrict__ tx_W, const float* __restrict__ tx_b,
    const float* __restrict__ sWk, const float* __restrict__ sWv,
    const float* __restrict__ sWq, const float* __restrict__ aWk,
    const float* __restrict__ aWq, float* __restrict__ Ttab) {
  const int z = blockIdx.y;
  const float* V;
  const float* bias;
  const float* W;
  float* P;
  int nvec;
  float scl = 1.f;
  if (z < 6) {
    V = in_W; bias = in_b; nvec = 3;
    const int i = z / 3, wsel = z % 3;
    W = (wsel == 0 ? sWk : wsel == 1 ? sWv : sWq) + (size_t)i * 262144;
    P = Ttab + (size_t)z * 2048;
    if (wsel == 2) scl = 0.0625f * LOG2E;
  } else if (z < 8) {
    V = cx_W; bias = cx_b; nvec = 1;
    W = aWk + (size_t)(z - 6) * 262144;
    P = Ttab + 12288 + (size_t)(z - 6) * 1024;
  } else {
    V = tx_W; bias = tx_b; nvec = 1;
    W = aWq; P = Ttab + 14336; scl = 0.08838834764831845f * LOG2E;
  }
  __shared__ float4 sh4[4];
  const int j = blockIdx.x, tid = threadIdx.x;
  float acc[4] = {0.f, 0.f, 0.f, 0.f};
  for (int kk = tid; kk < 512; kk += 256) {
    const float w = W[(size_t)kk * 512 + j];
    for (int v = 0; v < nvec; ++v) acc[v] += V[(size_t)v * 512 + kk] * w;
    acc[3] += bias[kk] * w;
  }
  float4 packed = make_float4(acc[0], acc[1], acc[2], acc[3]);
  packed = block_sum4(packed, sh4);
  if (tid == 0) {
    const float vals[4] = {packed.x * scl, packed.y * scl, packed.z * scl, packed.w * scl};
    for (int v = 0; v < nvec; ++v) P[(size_t)v * 512 + j] = vals[v];
    P[(size_t)nvec * 512 + j] = vals[3];
  }
}

// ---- fused weight transposes, K=512 (9 jobs via blockIdx.z); Q scaled w/ LOG2E ----
__global__ __launch_bounds__(256) void transpose_kvq_kernel(
    const float* __restrict__ sWk, const float* __restrict__ sWv,
    const float* __restrict__ sWq, const float* __restrict__ aWv,
    const float* __restrict__ aWq, unsigned short* __restrict__ Wkvqt0,
    unsigned short* __restrict__ aWvt0, unsigned short* __restrict__ aWqt1) {
  const int z = blockIdx.z;
  const float* src;
  unsigned short* dst;
  float scl = 1.f;
  if (z < 6) {
    const int i = z / 3, wsel = z % 3;
    src = (wsel == 0 ? sWk : wsel == 1 ? sWv : sWq) + (size_t)i * 262144;
    dst = Wkvqt0 + (size_t)i * 786432 + (size_t)wsel * 262144;
    if (wsel == 2) scl = 0.0625f * LOG2E;
  } else if (z < 8) {
    src = aWv + (size_t)(z - 6) * 262144;
    dst = aWvt0 + (size_t)(z - 6) * 262144;
  } else {
    src = aWq + 262144; dst = aWqt1; scl = 0.08838834764831845f * LOG2E;
  }
  __shared__ float tile[32][33];
  const int n0 = blockIdx.x * 32, k0 = blockIdx.y * 32;
  const int tx = threadIdx.x, ty = threadIdx.y;  // 32 x 8
#pragma unroll
  for (int r = 0; r < 4; ++r)
    tile[ty + 8 * r][tx] = src[(size_t)(k0 + ty + 8 * r) * 512 + n0 + tx];
  __syncthreads();
#pragma unroll
  for (int r = 0; r < 4; ++r)
    dst[(size_t)(n0 + ty + 8 * r) * 512 + k0 + tx] =
        (unsigned short)f2b(scl * tile[tx][ty + 8 * r]);
}

// ---- fused weight transposes, K=1024 (4 jobs via blockIdx.z) ----
__global__ __launch_bounds__(256) void transpose_f_kernel(
    const float* __restrict__ sWf, const float* __restrict__ aWf,
    unsigned short* __restrict__ Wft0, unsigned short* __restrict__ aWft0) {
  const int z = blockIdx.z;
  const float* src = (z < 2 ? sWf + (size_t)z * 524288 : aWf + (size_t)(z - 2) * 524288);
  unsigned short* dst =
      (z < 2 ? Wft0 + (size_t)z * 524288 : aWft0 + (size_t)(z - 2) * 524288);
  __shared__ float tile[32][33];
  const int n0 = blockIdx.x * 32, k0 = blockIdx.y * 32;
  const int tx = threadIdx.x, ty = threadIdx.y;  // 32 x 8
#pragma unroll
  for (int r = 0; r < 4; ++r)
    tile[ty + 8 * r][tx] = src[(size_t)(k0 + ty + 8 * r) * 512 + n0 + tx];
  __syncthreads();
#pragma unroll
  for (int r = 0; r < 4; ++r)
    dst[(size_t)(n0 + ty + 8 * r) * 1024 + k0 + tx] =
        (unsigned short)f2b(tile[tx][ty + 8 * r]);
}

// ---- merged cross-side encoder producers: K/Q rows + V frag tiles -------------
__global__ __launch_bounds__(256) void affine3kqv_kernel(
    const float* __restrict__ cx, const float* __restrict__ cy, int sel,
    const float* __restrict__ TK, const float* __restrict__ TV,
    const float* __restrict__ TQ, unsigned short* __restrict__ Kfr,
    unsigned short* __restrict__ Qbf, unsigned short* __restrict__ Vfr) {
  __shared__ float tile[32][33];
  const int bz = blockIdx.x;
  if (bz < 2048) {
    const int row = bz * 2 + (threadIdx.x >> 7);
    const int t = threadIdx.x & 127;
    const int b = row >> 10, s = row & 1023;
    const float x = cx[row];
    const float* y = cy + (size_t)row * 8 + 2 * sel;
    const float y0 = y[0], y1 = y[1];
    const bool isQ = t >= 64;
    const int c = t & 63;
    const int h = c >> 5;
    const int d0 = (c & 31) * 8;
    const float* T = isQ ? TQ : TK;
    float v[8];
#pragma unroll
    for (int j = 0; j < 8; ++j) {
      const int col = h * 256 + d0 + j;
      v[j] = x * T[col] + y0 * T[512 + col] + y1 * T[1024 + col] + T[1536 + col];
    }
    const uint4 u = pack8(v);
    const int bh = b * 2 + h;
    if (isQ) {
      *(uint4*)(Qbf + ((size_t)bh * 1024 + s) * 256 + d0) = u;
    } else {
      const int kc = d0 >> 5;
      const int lane = ((d0 & 31) >> 3) * 16 + (s & 15);
      *(uint4*)(Kfr + ((size_t)(bh * 8 + kc) * 64 + (s >> 4)) * 512 + lane * 8) = u;
    }
  } else {
    const int vb = bz - 2048;
    const int s0 = (vb & 31) * 32, d0 = ((vb >> 5) & 7) * 32;
    const int bh = vb >> 8;
    const int b = bh >> 1, h = bh & 1;
    const int tx = threadIdx.x & 31, ty = threadIdx.x >> 5;  // 32 x 8
    const int col = h * 256 + d0 + tx;
    const float tv0 = TV[col], tv1 = TV[512 + col], tv2 = TV[1024 + col],
                tv3 = TV[1536 + col];
#pragma unroll
    for (int r = 0; r < 4; ++r) {
      const int row = b * 1024 + s0 + ty + 8 * r;
      const float x = cx[row];
      const float* y = cy + (size_t)row * 8 + 2 * sel;
      tile[ty + 8 * r][tx] = x * tv0 + y[0] * tv1 + y[1] * tv2 + tv3;
    }
    __syncthreads();
    const int idx = threadIdx.x;
    if (idx < 128) {
      const int dj = idx & 31, sch = idx >> 5;
      float v[8];
#pragma unroll
      for (int jj = 0; jj < 8; ++jj) v[jj] = tile[sch * 8 + jj][dj];
      const uint4 u = pack8(v);
      const int sc = s0 >> 5;
      const int dtile = (d0 + dj) >> 4;
      const int lane = sch * 16 + (dj & 15);
      *(uint4*)(Vfr + ((size_t)(bh * 32 + sc) * 16 + dtile) * 512 + lane * 8) = u;
    }
  }
}

// ---- decoder rank-1 producers (nh=4, D=128): T rows [0]=w, [1]=bias ----
__global__ __launch_bounds__(64) void rank1_pack_kernel(
    const float* __restrict__ x, const float* __restrict__ T,
    unsigned short* __restrict__ dst, int isQ) {
  const int row = blockIdx.x;
  const int b = row >> 10, s = row & 1023;
  const float xv = x[row];
  const int c = threadIdx.x;        // 64 chunks of 8
  const int h = c >> 4;             // 16 chunks per head
  const int d0 = (c & 15) * 8;
  float v[8];
#pragma unroll
  for (int j = 0; j < 8; ++j) {
    const int col = h * 128 + d0 + j;
    v[j] = xv * T[col] + T[512 + col];
  }
  const uint4 u = pack8(v);
  const int bh = b * 4 + h;
  if (isQ) {
    *(uint4*)(dst + ((size_t)bh * 1024 + s) * 128 + d0) = u;
  } else {
    const int kc = d0 >> 5;
    const int lane = ((d0 & 31) >> 3) * 16 + (s & 15);
    *(uint4*)(dst + ((size_t)(bh * 4 + kc) * 64 + (s >> 4)) * 512 + lane * 8) = u;
  }
}

// ---- merged decoder i=0 producers: t<64 K from (xk,Tk), t>=64 Q from (xq,Tq) ----
__global__ __launch_bounds__(128) void rank1kq_kernel(
    const float* __restrict__ xk, const float* __restrict__ Tk,
    unsigned short* __restrict__ dstK, const float* __restrict__ xq,
    const float* __restrict__ Tq, unsigned short* __restrict__ dstQ) {
  const int row = blockIdx.x;
  const int b = row >> 10, s = row & 1023;
  const bool isQ = threadIdx.x >= 64;
  const float xv = isQ ? xq[row] : xk[row];
  const float* T = isQ ? Tq : Tk;
  const int c = threadIdx.x & 63;
  const int h = c >> 4;
  const int d0 = (c & 15) * 8;
  float v[8];
#pragma unroll
  for (int j = 0; j < 8; ++j) {
    const int col = h * 128 + d0 + j;
    v[j] = xv * T[col] + T[512 + col];
  }
  const uint4 u = pack8(v);
  const int bh = b * 4 + h;
  if (isQ) {
    *(uint4*)(dstQ + ((size_t)bh * 1024 + s) * 128 + d0) = u;
  } else {
    const int kc = d0 >> 5;
    const int lane = ((d0 & 31) >> 3) * 16 + (s & 15);
    *(uint4*)(dstK + ((size_t)(bh * 4 + kc) * 64 + (s >> 4)) * 512 + lane * 8) = u;
  }
}

// ---- merged initial activations: y=0 affine3(sel=0)->E/Ebf, y=1 rank1->QA/QAbf ----
__global__ __launch_bounds__(512) void init2_kernel(
    const float* __restrict__ cx, const float* __restrict__ cy,
    const float* __restrict__ in_W, const float* __restrict__ in_b,
    const float* __restrict__ txp, const float* __restrict__ tx_W,
    const float* __restrict__ tx_b, float* __restrict__ E,
    unsigned short* __restrict__ Ebf, float* __restrict__ QA,
    unsigned short* __restrict__ QAbf) {
  const int r = blockIdx.x, j = threadIdx.x;
  if (blockIdx.y == 0) {
    const float* y = cy + (size_t)r * 8;
    const float v = cx[r] * in_W[j] + y[0] * in_W[512 + j] + y[1] * in_W[1024 + j] +
                    in_b[j];
    E[(size_t)r * 512 + j] = v;
    Ebf[(size_t)r * 512 + j] = (unsigned short)f2b(v);
  } else {
    const float v = txp[r] * tx_W[j] + tx_b[j];
    QA[(size_t)r * 512 + j] = v;
    QAbf[(size_t)r * 512 + j] = (unsigned short)f2b(v);
  }
}

// ------------- split-K Wf GEMM (double-buffered): two K-halves via blockIdx.z ----
// XCD-aware block swizzle: same-bm blocks (sharing A panel) stay on one XCD.
__global__ __launch_bounds__(256) void gemm_wf_kernel(
    const unsigned short* __restrict__ A0, const unsigned short* __restrict__ A1,
    const float* __restrict__ F0, const float* __restrict__ F1,
    const unsigned short* __restrict__ Wt, const float* __restrict__ bias,
    float* __restrict__ C0, float* __restrict__ C1) {
  constexpr int BM = 128, BN = 64, BK = 32, LDP = 40, K = 512, N = 512;
  __shared__ unsigned short As[2][BM * LDP];
  __shared__ unsigned short Bs[2][BN * LDP];
  const int kz = blockIdx.z;
  const int tid = threadIdx.x;
  const int lane = tid & 63, w = tid >> 6;
  const int lin = blockIdx.y * 8 + blockIdx.x;      // 256 blocks per kz
  const int swz = (lin & 7) * 32 + (lin >> 3);      // bijective, 256%8==0
  const int bm = (swz >> 3) * BM, bn = (swz & 7) * BN;
  const int wm = (w & 1) * 64, wn = (w >> 1) * 32;
  const int l15 = lane & 15, lq = lane >> 4;
  const int ar = tid >> 1, ac = (tid & 1) * 16;
  const int br = tid >> 2, bc = (tid & 3) * 8;
  const unsigned short* A = kz ? A1 : A0;
  const bool useF = (kz != 0) && (F0 != nullptr);
  const size_t arow = (size_t)(bm + ar) * 512;
  const size_t brow = (size_t)(bn + br) * 1024 + (size_t)kz * 512;
  f32x4 acc[4][2] = {};
  uint4 ra0, ra1, rb0;
#define GLOAD(k0_)                                                          \
  do {                                                                      \
    if (useF) {                                                             \
      const float* p0 = F0 + arow + (k0_) + ac;                             \
      const float* p1 = F1 + arow + (k0_) + ac;                             \
      float s[16];                                                          \
      const float4 x0 = *(const float4*)p0, x1 = *(const float4*)(p0 + 4);  \
      const float4 x2 = *(const float4*)(p0 + 8), x3 = *(const float4*)(p0 + 12); \
      const float4 y0 = *(const float4*)p1, y1 = *(const float4*)(p1 + 4);  \
      const float4 y2 = *(const float4*)(p1 + 8), y3 = *(const float4*)(p1 + 12); \
      s[0] = x0.x + y0.x; s[1] = x0.y + y0.y; s[2] = x0.z + y0.z; s[3] = x0.w + y0.w; \
      s[4] = x1.x + y1.x; s[5] = x1.y + y1.y; s[6] = x1.z + y1.z; s[7] = x1.w + y1.w; \
      s[8] = x2.x + y2.x; s[9] = x2.y + y2.y; s[10] = x2.z + y2.z; s[11] = x2.w + y2.w; \
      s[12] = x3.x + y3.x; s[13] = x3.y + y3.y; s[14] = x3.z + y3.z; s[15] = x3.w + y3.w; \
      ra0 = pack8(s); ra1 = pack8(s + 8);                                   \
    } else {                                                                \
      ra0 = *(const uint4*)(A + arow + (k0_) + ac);                         \
      ra1 = *(const uint4*)(A + arow + (k0_) + ac + 8);                     \
    }                                                                       \
    rb0 = *(const uint4*)(Wt + brow + (k0_) + bc);                          \
  } while (0)
  GLOAD(0);
  *(uint4*)(As[0] + ar * LDP + ac) = ra0;
  *(uint4*)(As[0] + ar * LDP + ac + 8) = ra1;
  *(uint4*)(Bs[0] + br * LDP + bc) = rb0;
  __syncthreads();
  int buf = 0;
  for (int k0 = 0; k0 < K; k0 += BK) {
    const bool more = (k0 + BK) < K;
    if (more) GLOAD(k0 + BK);
    bf16x8 af[4], bfr[2];
#pragma unroll
    for (int mt = 0; mt < 4; ++mt)
      af[mt] = *(const bf16x8*)(As[buf] + (wm + mt * 16 + l15) * LDP + lq * 8);
#pragma unroll
    for (int nt = 0; nt < 2; ++nt)
      bfr[nt] = *(const bf16x8*)(Bs[buf] + (wn + nt * 16 + l15) * LDP + lq * 8);
#pragma unroll
    for (int mt = 0; mt < 4; ++mt)
#pragma unroll
      for (int nt = 0; nt < 2; ++nt)
        acc[mt][nt] =
            __builtin_amdgcn_mfma_f32_16x16x32_bf16(af[mt], bfr[nt], acc[mt][nt], 0, 0, 0);
    if (more) {
      *(uint4*)(As[buf ^ 1] + ar * LDP + ac) = ra0;
      *(uint4*)(As[buf ^ 1] + ar * LDP + ac + 8) = ra1;
      *(uint4*)(Bs[buf ^ 1] + br * LDP + bc) = rb0;
    }
    __syncthreads();
    buf ^= 1;
  }
#undef GLOAD
  float* C = kz ? C1 : C0;
#pragma unroll
  for (int nt = 0; nt < 2; ++nt) {
    const int col = bn + wn + nt * 16 + l15;
    const float bv = (kz && bias) ? bias[col] : 0.f;
#pragma unroll
    for (int mt = 0; mt < 4; ++mt) {
#pragma unroll
      for (int r = 0; r < 4; ++r) {
        const int row = bm + wm + mt * 16 + lq * 4 + r;
        C[(size_t)row * N + col] = acc[mt][nt][r] + bv;
      }
    }
  }
}

// ---- 128x128-tile KVQ GEMM with fused frag-pack epilogue (K=512, N=1536) --------
// m93-style tile upgrade: 16 MFMA per K-step per wave (2x the 128x64 tile),
// amortizing staging + barriers.  4 waves of 64x64; acc[4][4] = 64 VGPR, static.
// XCD-aware swizzle (nwg=384, %8==0): same-bm blocks share an XCD's L2.
__global__ __launch_bounds__(256) void gemm_pack_big_kernel(
    const unsigned short* __restrict__ A0, const unsigned short* __restrict__ Wt,
    unsigned short* __restrict__ Kfr, unsigned short* __restrict__ Vfr,
    unsigned short* __restrict__ Qbf) {
  constexpr int BM = 128, BN = 128, BK = 32, LDP = 40, K = 512;
  __shared__ unsigned short As[2][BM * LDP];
  __shared__ unsigned short Bs[2][BN * LDP];
  const int tid = threadIdx.x;
  const int lane = tid & 63, w = tid >> 6;
  const int lin = blockIdx.y * 12 + blockIdx.x;     // 384 blocks
  const int swz = (lin & 7) * 48 + (lin >> 3);      // bijective, 384%8==0
  const int bm = (swz / 12) * BM, bn = (swz % 12) * BN;
  const int wm = (w & 1) * 64, wn = (w >> 1) * 64;
  const int l15 = lane & 15, lq = lane >> 4;
  const int r2 = tid >> 1, c2 = (tid & 1) * 16;     // stage: 128 rows x 32 cols
  f32x4 acc[4][4] = {};
  uint4 ra0 = *(const uint4*)(A0 + (size_t)(bm + r2) * K + c2);
  uint4 ra1 = *(const uint4*)(A0 + (size_t)(bm + r2) * K + c2 + 8);
  uint4 rb0 = *(const uint4*)(Wt + (size_t)(bn + r2) * K + c2);
  uint4 rb1 = *(const uint4*)(Wt + (size_t)(bn + r2) * K + c2 + 8);
  *(uint4*)(As[0] + r2 * LDP + c2) = ra0;
  *(uint4*)(As[0] + r2 * LDP + c2 + 8) = ra1;
  *(uint4*)(Bs[0] + r2 * LDP + c2) = rb0;
  *(uint4*)(Bs[0] + r2 * LDP + c2 + 8) = rb1;
  __syncthreads();
  int buf = 0;
  for (int k0 = 0; k0 < K; k0 += BK) {
    const bool more = (k0 + BK) < K;
    if (more) {
      ra0 = *(const uint4*)(A0 + (size_t)(bm + r2) * K + k0 + BK + c2);
      ra1 = *(const uint4*)(A0 + (size_t)(bm + r2) * K + k0 + BK + c2 + 8);
      rb0 = *(const uint4*)(Wt + (size_t)(bn + r2) * K + k0 + BK + c2);
      rb1 = *(const uint4*)(Wt + (size_t)(bn + r2) * K + k0 + BK + c2 + 8);
    }
    bf16x8 af[4], bfr[4];
#pragma unroll
    for (int mt = 0; mt < 4; ++mt)
      af[mt] = *(const bf16x8*)(As[buf] + (wm + mt * 16 + l15) * LDP + lq * 8);
#pragma unroll
    for (int nt = 0; nt < 4; ++nt)
      bfr[nt] = *(const bf16x8*)(Bs[buf] + (wn + nt * 16 + l15) * LDP + lq * 8);
    __builtin_amdgcn_s_setprio(1);
#pragma unroll
    for (int mt = 0; mt < 4; ++mt)
#pragma unroll
      for (int nt = 0; nt < 4; ++nt)
        acc[mt][nt] =
            __builtin_amdgcn_mfma_f32_16x16x32_bf16(af[mt], bfr[nt], acc[mt][nt], 0, 0, 0);
    __builtin_amdgcn_s_setprio(0);
    if (more) {
      *(uint4*)(As[buf ^ 1] + r2 * LDP + c2) = ra0;
      *(uint4*)(As[buf ^ 1] + r2 * LDP + c2 + 8) = ra1;
      *(uint4*)(Bs[buf ^ 1] + r2 * LDP + c2) = rb0;
      *(uint4*)(Bs[buf ^ 1] + r2 * LDP + c2 + 8) = rb1;
    }
    __syncthreads();
    buf ^= 1;
  }
  // ---- fused pack epilogue (col math absolute; identical mapping to MODE 0) ----
  const int b = bm >> 10;
  const int s0base = (bm & 1023) + wm + lq * 4;
#pragma unroll
  for (int nt = 0; nt < 4; ++nt) {
    const int col = bn + wn + nt * 16 + l15;
    const int sec = col >> 9;
    const int cc = col & 511;
    const int h = cc >> 8, d = cc & 255;
    const int bh = b * 2 + h;
#pragma unroll
    for (int mt = 0; mt < 4; ++mt) {
      const int s0 = s0base + mt * 16;
      const float* a = (const float*)&acc[mt][nt];
      if (sec == 2) {                           // Q: [bh][s][256]
        unsigned short* q = Qbf + ((size_t)bh * 1024 + s0) * 256 + d;
#pragma unroll
        for (int r = 0; r < 4; ++r) q[(size_t)r * 256] = (unsigned short)f2b(a[r]);
      } else if (sec == 0) {                    // K frag
        unsigned short* kp = Kfr +
            ((size_t)(bh * 8 + (d >> 5)) * 64 + (s0 >> 4)) * 512 +
            ((d & 31) >> 3) * 128 + (d & 7);
#pragma unroll
        for (int r = 0; r < 4; ++r)
          kp[((s0 & 15) + r) * 8] = (unsigned short)f2b(a[r]);
      } else {                                  // V frag
        unsigned short* vp = Vfr +
            ((size_t)(bh * 32 + (s0 >> 5)) * 16 + (d >> 4)) * 512 +
            (((s0 >> 3) & 3) * 16 + (d & 15)) * 8 + (s0 & 7);
        uint2 u;
        u.x = f2b(a[0]) | (f2b(a[1]) << 16);
        u.y = f2b(a[2]) | (f2b(a[3]) << 16);
        *(uint2*)vp = u;
      }
    }
  }
}

// ------- MFMA GEMM with fused frag-pack epilogue (K=512, single A) ---------------
// MODE 1: N=512  = V only, nh=4, D=128 -> Vfr
// MODE 2: N=512  = Q only, nh=4, D=128 -> Qbf (weights pre-scaled)
// XCD-aware swizzle: same-bm blocks (sharing A panel) stay on one XCD.
template <int MODE>
__global__ __launch_bounds__(256) void gemm_pack_kernel(
    const unsigned short* __restrict__ A0, const unsigned short* __restrict__ Wt,
    unsigned short* __restrict__ Kfr, unsigned short* __restrict__ Vfr,
    unsigned short* __restrict__ Qbf) {
  constexpr int BM = 128, BN = 64, BK = 32, LDP = 40, K = 512;
  __shared__ unsigned short As[2][BM * LDP];
  __shared__ unsigned short Bs[2][BN * LDP];
  const int tid = threadIdx.x;
  const int lane = tid & 63, w = tid >> 6;
  const int nbx = gridDim.x;
  const int lin = blockIdx.y * nbx + blockIdx.x;
  const int nwg = nbx * gridDim.y;                  // 256, %8==0
  const int swz = (lin & 7) * (nwg >> 3) + (lin >> 3);
  const int bm = (swz / nbx) * BM, bn = (swz % nbx) * BN;
  const int wm = (w & 1) * 64, wn = (w >> 1) * 32;
  const int l15 = lane & 15, lq = lane >> 4;
  const int ar = tid >> 1, ac = (tid & 1) * 16;
  const int br = tid >> 2, bc = (tid & 3) * 8;
  f32x4 acc[4][2] = {};
  uint4 ra0 = *(const uint4*)(A0 + (size_t)(bm + ar) * K + ac);
  uint4 ra1 = *(const uint4*)(A0 + (size_t)(bm + ar) * K + ac + 8);
  uint4 rb0 = *(const uint4*)(Wt + (size_t)(bn + br) * K + bc);
  *(uint4*)(As[0] + ar * LDP + ac) = ra0;
  *(uint4*)(As[0] + ar * LDP + ac + 8) = ra1;
  *(uint4*)(Bs[0] + br * LDP + bc) = rb0;
  __syncthreads();
  int buf = 0;
  for (int k0 = 0; k0 < K; k0 += BK) {
    const bool more = (k0 + BK) < K;
    if (more) {
      ra0 = *(const uint4*)(A0 + (size_t)(bm + ar) * K + k0 + BK + ac);
      ra1 = *(const uint4*)(A0 + (size_t)(bm + ar) * K + k0 + BK + ac + 8);
      rb0 = *(const uint4*)(Wt + (size_t)(bn + br) * K + k0 + BK + bc);
    }
    bf16x8 af[4], bfr[2];
#pragma unroll
    for (int mt = 0; mt < 4; ++mt)
      af[mt] = *(const bf16x8*)(As[buf] + (wm + mt * 16 + l15) * LDP + lq * 8);
#pragma unroll
    for (int nt = 0; nt < 2; ++nt)
      bfr[nt] = *(const bf16x8*)(Bs[buf] + (wn + nt * 16 + l15) * LDP + lq * 8);
#pragma unroll
    for (int mt = 0; mt < 4; ++mt)
#pragma unroll
      for (int nt = 0; nt < 2; ++nt)
        acc[mt][nt] =
            __builtin_amdgcn_mfma_f32_16x16x32_bf16(af[mt], bfr[nt], acc[mt][nt], 0, 0, 0);
    if (more) {
      *(uint4*)(As[buf ^ 1] + ar * LDP + ac) = ra0;
      *(uint4*)(As[buf ^ 1] + ar * LDP + ac + 8) = ra1;
      *(uint4*)(Bs[buf ^ 1] + br * LDP + bc) = rb0;
    }
    __syncthreads();
    buf ^= 1;
  }
  // ---- fused pack epilogue ----
  const int b = bm >> 10;
  const int s0base = (bm & 1023) + wm + lq * 4;
#pragma unroll
  for (int nt = 0; nt < 2; ++nt) {
    const int col = bn + wn + nt * 16 + l15;
    const int h = col >> 7, d = col & 127;
    const int bh = b * 4 + h;
#pragma unroll
    for (int mt = 0; mt < 4; ++mt) {
      const int s0 = s0base + mt * 16;
      const float* a = (const float*)&acc[mt][nt];
      if constexpr (MODE == 2) {                // Q: [bh][s][128]
        unsigned short* q = Qbf + ((size_t)bh * 1024 + s0) * 128 + d;
#pragma unroll
        for (int r = 0; r < 4; ++r) q[(size_t)r * 128] = (unsigned short)f2b(a[r]);
      } else {                                  // V frag
        unsigned short* vp = Vfr +
            ((size_t)(bh * 32 + (s0 >> 5)) * 8 + (d >> 4)) * 512 +
            (((s0 >> 3) & 3) * 16 + (d & 15)) * 8 + (s0 & 7);
        uint2 u;
        u.x = f2b(a[0]) | (f2b(a[1]) << 16);
        u.y = f2b(a[2]) | (f2b(a[3]) << 16);
        *(uint2*)vp = u;
      }
    }
  }
  (void)Kfr;
}

// -------- MFMA flash attention, chunked keys + deferred normalization -----------
// Block = QT*16 q rows of one (b,head) vs ONE KV side, keys in 4 chunks of 256
// (R8-proven config; 128-key chunks regressed -22%, R9 post-mortem).
// No-max softmax => O = (sum_k exp2(s) V) / (sum_k exp2(s)) accumulated per chunk;
// normalization applied once at the end.  NQS Q-sets share K and V loads.
// All register arrays statically indexed (rule #20); c/kc/sc feed addresses only.
// NQS==2: grid = 2*256, side = bx>>8; writes f32 partials to Rp.
// NQS==1: writes bf16 with post_scale.
template <int D, int NQS, int QT>
__global__ __launch_bounds__(256, 2) void attn_mfma_kernel(
    const unsigned short* __restrict__ Qa, const unsigned short* __restrict__ Qb,
    const unsigned short* __restrict__ KfrA, const unsigned short* __restrict__ KfrB,
    const unsigned short* __restrict__ VfrA, const unsigned short* __restrict__ VfrB,
    float post_scale, int nh, unsigned short* __restrict__ R,
    float* __restrict__ Rp) {
  constexpr int QP = D + 8;      // qsh pitch
  constexpr int SP = 256 + 8;    // strip pitch (chunk = 256 keys)
  constexpr int DT = D / 64;     // d-tiles per wave
  constexpr int NR = QT * 16;    // q rows per block
  const int tid = threadIdx.x;
  const int lane = tid & 63, w = tid >> 6;
  const int l15 = lane & 15, lq = lane >> 4;
  const int nbh = 4 * nh;
  int bx = blockIdx.x;
  int side = 0;
  if constexpr (NQS == 2) { side = bx >> 8; bx &= 255; }
  const int bh = bx % nbh;       // XCD-local (b,h): same-bh blocks share an XCD's L2
  const int qb = (bx / nbh) * NR;
  const int b = bh / nh, head = bh % nh;
  const size_t rowb = (size_t)b * 1024;
  const int colo = head * D;

  __shared__ unsigned short qsh[NQS * NR * QP];
  __shared__ unsigned short ssh[NQS * NR * SP];
  __shared__ float red[NQS * QT * 4 * 16];

  // ---- stage Q ----
  for (int idx = tid; idx < NQS * NR * (D / 8); idx += 256) {
    const int set = idx / (NR * (D / 8));
    const int rem = idx - set * NR * (D / 8);
    const int r = rem / (D / 8), ch = rem - r * (D / 8);
    const unsigned short* Q = set ? Qb : Qa;
    const uint4 u = *(const uint4*)(Q + ((size_t)bh * 1024 + qb + r) * D + ch * 8);
    *(uint4*)(qsh + (set * NR + r) * QP + ch * 8) = u;
  }
  __syncthreads();

  const unsigned short* Kp = (side ? KfrB : KfrA) + (size_t)bh * ((size_t)D * 1024);
  const unsigned short* Vp = (side ? VfrB : VfrA) + (size_t)bh * ((size_t)D * 1024);

  float psum[QT][NQS][4];
#pragma unroll
  for (int qt = 0; qt < QT; ++qt)
#pragma unroll
    for (int s2 = 0; s2 < NQS; ++s2)
#pragma unroll
      for (int r = 0; r < 4; ++r) psum[qt][s2][r] = 0.f;
  f32x4 acc_o[QT][NQS][DT] = {};

#pragma unroll 1
  for (int c = 0; c < 4; ++c) {        // c only feeds addresses (safe runtime)
    // ---- QK^T for chunk: wave w owns stiles c*16 + w*4 .. +3 (keys w*64..+63) ----
    f32x4 sacc[QT][NQS][4] = {};
#pragma unroll 1
    for (int kc = 0; kc < D / 32; ++kc) {
      bf16x8 kf[4];
#pragma unroll
      for (int st = 0; st < 4; ++st)
        kf[st] = *(const bf16x8*)(
            Kp + ((size_t)kc * 64 + c * 16 + w * 4 + st) * 512 + lane * 8);
      bf16x8 qf[QT][NQS];
#pragma unroll
      for (int qt = 0; qt < QT; ++qt)
#pragma unroll
        for (int s2 = 0; s2 < NQS; ++s2)
          qf[qt][s2] = *(const bf16x8*)(
              qsh + (s2 * NR + qt * 16 + l15) * QP + kc * 32 + lq * 8);
      __builtin_amdgcn_s_setprio(1);
#pragma unroll
      for (int st = 0; st < 4; ++st)
#pragma unroll
        for (int qt = 0; qt < QT; ++qt)
#pragma unroll
          for (int s2 = 0; s2 < NQS; ++s2)
            sacc[qt][s2][st] = __builtin_amdgcn_mfma_f32_16x16x32_bf16(
                qf[qt][s2], kf[st], sacc[qt][s2][st], 0, 0, 0);
      __builtin_amdgcn_s_setprio(0);
    }
    // ---- exp2 + running sums + strip write (unnormalized weights) ----
#pragma unroll
    for (int qt = 0; qt < QT; ++qt)
#pragma unroll
      for (int s2 = 0; s2 < NQS; ++s2)
#pragma unroll
        for (int st = 0; st < 4; ++st)
#pragma unroll
          for (int r = 0; r < 4; ++r) {
            const float e = exp2f(sacc[qt][s2][st][r]);
            psum[qt][s2][r] += e;
            ssh[(s2 * NR + qt * 16 + lq * 4 + r) * SP + (w * 4 + st) * 16 + l15] =
                (unsigned short)f2b(e);
          }
    __syncthreads();
    // ---- PV: V loaded once, serves all Q-sets ----
#pragma unroll 1
    for (int sc = 0; sc < 8; sc += 2) {
      bf16x8 vb[2][DT], pa[2][QT][NQS];
#pragma unroll
      for (int u = 0; u < 2; ++u) {
#pragma unroll
        for (int dt = 0; dt < DT; ++dt)
          vb[u][dt] = *(const bf16x8*)(
              Vp + ((size_t)(c * 8 + sc + u) * (D / 16) + w * DT + dt) * 512 + lane * 8);
#pragma unroll
        for (int qt = 0; qt < QT; ++qt)
#pragma unroll
          for (int s2 = 0; s2 < NQS; ++s2)
            pa[u][qt][s2] = *(const bf16x8*)(
                ssh + (s2 * NR + qt * 16 + l15) * SP + (sc + u) * 32 + lq * 8);
      }
      __builtin_amdgcn_s_setprio(1);
#pragma unroll
      for (int u = 0; u < 2; ++u)
#pragma unroll
        for (int qt = 0; qt < QT; ++qt)
#pragma unroll
          for (int s2 = 0; s2 < NQS; ++s2)
#pragma unroll
            for (int dt = 0; dt < DT; ++dt)
              acc_o[qt][s2][dt] = __builtin_amdgcn_mfma_f32_16x16x32_bf16(
                  pa[u][qt][s2], vb[u][dt], acc_o[qt][s2][dt], 0, 0, 0);
      __builtin_amdgcn_s_setprio(0);
    }
    __syncthreads();
  }

  // ---- final row sums: reduce over 16 key-lanes, then over 4 waves ----
#pragma unroll
  for (int o = 1; o < 16; o <<= 1)
#pragma unroll
    for (int qt = 0; qt < QT; ++qt)
#pragma unroll
      for (int s2 = 0; s2 < NQS; ++s2)
#pragma unroll
        for (int r = 0; r < 4; ++r)
          psum[qt][s2][r] += __shfl_xor(psum[qt][s2][r], o);
  if (l15 == 0) {
#pragma unroll
    for (int qt = 0; qt < QT; ++qt)
#pragma unroll
      for (int s2 = 0; s2 < NQS; ++s2)
#pragma unroll
        for (int r = 0; r < 4; ++r)
          red[((s2 * QT + qt) * 4 + w) * 16 + lq * 4 + r] = psum[qt][s2][r];
  }
  __syncthreads();
  float inv[QT][NQS][4];
#pragma unroll
  for (int qt = 0; qt < QT; ++qt)
#pragma unroll
    for (int s2 = 0; s2 < NQS; ++s2)
#pragma unroll
      for (int r = 0; r < 4; ++r) {
        const float* rp = red + ((s2 * QT + qt) * 4) * 16 + lq * 4 + r;
        inv[qt][s2][r] = 1.f / (rp[0] + rp[16] + rp[32] + rp[48]);
      }

  // ---- epilogue: normalize + write ----
  if constexpr (NQS == 2) {
    float* base = Rp + (size_t)side * (4096 * 512);
#pragma unroll
    for (int qt = 0; qt < QT; ++qt)
#pragma unroll
      for (int dt = 0; dt < DT; ++dt)
#pragma unroll
        for (int r = 0; r < 4; ++r) {
          const int q = qb + qt * 16 + lq * 4 + r;
          const int d = w * (DT * 16) + dt * 16 + l15;
          base[(rowb + q) * 512 + colo + d] =
              acc_o[qt][0][dt][r] * inv[qt][0][r] + acc_o[qt][1][dt][r] * inv[qt][1][r];
        }
  } else {
#pragma unroll
    for (int qt = 0; qt < QT; ++qt)
#pragma unroll
      for (int dt = 0; dt < DT; ++dt)
#pragma unroll
        for (int r = 0; r < 4; ++r) {
          const int q = qb + qt * 16 + lq * 4 + r;
          const int d = w * (DT * 16) + dt * 16 + l15;
          R[(rowb + q) * 512 + colo + d] =
              (unsigned short)f2b(acc_o[qt][0][dt][r] * inv[qt][0][r] * post_scale);
        }
  }
}

// ---- out = LayerNorm(G0 + G1 + res) * g + b  (f32 out + optional bf16 out) ----
__global__ __launch_bounds__(256) void ln_kernel(
    const float* __restrict__ G0, const float* __restrict__ G1,
    const float* __restrict__ res, const float* __restrict__ g,
    const float* __restrict__ b, float* __restrict__ out,
    unsigned short* __restrict__ outb) {
  __shared__ float sh[4];
  const int row = blockIdx.x, tid = threadIdx.x;
  const size_t off = (size_t)row * 512;
  const float x0 = G0[off + tid] + G1[off + tid] + res[off + tid];
  const float x1 = G0[off + tid + 256] + G1[off + tid + 256] + res[off + tid + 256];
  const float mean = block_sum1(x0 + x1, sh) * (1.0f / 512.0f);
  const float d0 = x0 - mean, d1 = x1 - mean;
  const float var = block_sum1(d0 * d0 + d1 * d1, sh) * (1.0f / 512.0f);
  const float inv = rsqrtf(var + 1e-5f);
  const float y0 = d0 * inv * g[tid] + b[tid];
  const float y1 = d1 * inv * g[tid + 256] + b[tid + 256];
  out[off + tid] = y0;
  out[off + tid + 256] = y1;
  if (outb) {
    outb[off + tid] = (unsigned short)f2b(y0);
    outb[off + tid + 256] = (unsigned short)f2b(y1);
  }
}

extern "C" void kernel_launch(void* const* d_in, const int* in_sizes, int n_in,
                              void* d_out, int out_size, void* d_ws, size_t ws_size,
                              hipStream_t stream) {
  typedef unsigned short ushort_t;
  const float* cx   = (const float*)d_in[0];
  const float* cy   = (const float*)d_in[1];
  const float* txp  = (const float*)d_in[2];
  const float* in_W = (const float*)d_in[3];
  const float* in_b = (const float*)d_in[4];
  const float* cx_W = (const float*)d_in[5];
  const float* cx_b = (const float*)d_in[6];
  const float* tx_W = (const float*)d_in[7];
  const float* tx_b = (const float*)d_in[8];
  const float* sWk  = (const float*)d_in[9];
  const float* sWv  = (const float*)d_in[10];
  const float* sWq  = (const float*)d_in[11];
  const float* sWf  = (const float*)d_in[12];
  const float* sbf  = (const float*)d_in[13];
  const float* sg   = (const float*)d_in[14];
  const float* sb   = (const float*)d_in[15];
  const float* aWk  = (const float*)d_in[16];
  const float* aWv  = (const float*)d_in[17];
  const float* aWq  = (const float*)d_in[18];
  const float* aWf  = (const float*)d_in[19];
  const float* abf  = (const float*)d_in[20];
  const float* ag   = (const float*)d_in[21];
  const float* ab   = (const float*)d_in[22];

  const size_t MB = 1024 * 1024;
  char* ws = (char*)d_ws;
  float*    E     = (float*)(ws + 0 * MB);       // 8 MB
  ushort_t* Ebf   = (ushort_t*)(ws + 8 * MB);    // 4 MB
  float*    QA    = (float*)(ws + 12 * MB);      // 8 MB
  ushort_t* QAbf  = (ushort_t*)(ws + 20 * MB);   // 4 MB
  ushort_t* Rbbf  = (ushort_t*)(ws + 24 * MB);   // 4 MB
  float*    Rp    = (float*)(ws + 28 * MB);      // 16 MB attn f32 partials (2 sides)
  float*    G0    = (float*)(ws + 44 * MB);      // 8 MB Wf partial kz=0
  ushort_t* KfrA  = (ushort_t*)(ws + 52 * MB);   // 4 MB
  ushort_t* VfrA  = (ushort_t*)(ws + 56 * MB);   // 4 MB
  ushort_t* QbfA  = (ushort_t*)(ws + 60 * MB);   // 4 MB
  ushort_t* KfrB  = (ushort_t*)(ws + 64 * MB);   // 4 MB
  ushort_t* VfrB  = (ushort_t*)(ws + 68 * MB);   // 4 MB
  ushort_t* QbfB  = (ushort_t*)(ws + 72 * MB);   // 4 MB
  float*    G1    = (float*)(ws + 84 * MB);      // 8 MB Wf partial kz=1
  ushort_t* Wkvqt0 = (ushort_t*)(ws + 92 * MB);  // 2 x 1.5 MB
  ushort_t* Wkvqt[2] = {Wkvqt0, Wkvqt0 + 786432};
  ushort_t* Wft0   = (ushort_t*)(ws + 95 * MB);  // 2 x 1 MB
  ushort_t* Wft[2] = {Wft0, Wft0 + 524288};
  ushort_t* aWvt0  = (ushort_t*)(ws + 97 * MB);  // 2 x 0.5 MB
  ushort_t* aWvt[2] = {aWvt0, aWvt0 + 262144};
  ushort_t* aWqt1  = (ushort_t*)(ws + 98 * MB);  // 0.5 MB
  ushort_t* aWft0  = (ushort_t*)(ws + 99 * MB);  // 2 x 1 MB
  ushort_t* aWft[2] = {aWft0, aWft0 + 524288};
  float*    Ttab   = (float*)(ws + 101 * MB);

  float* T_sc[2][3];
  for (int i = 0; i < 2; ++i)
    for (int w = 0; w < 3; ++w) T_sc[i][w] = Ttab + (size_t)(i * 3 + w) * 2048;
  float* T_cak[2] = {Ttab + 12288, Ttab + 12288 + 1024};
  float* T_caq0 = Ttab + 14336;

  const dim3 tb(32, 8);

  // ---- prep: fused weight transposes + projection tables ----
  transpose_kvq_kernel<<<dim3(16, 16, 9), tb, 0, stream>>>(sWk, sWv, sWq, aWv, aWq,
                                                           Wkvqt0, aWvt0, aWqt1);
  transpose_f_kernel<<<dim3(16, 32, 4), tb, 0, stream>>>(sWf, aWf, Wft0, aWft0);
  tabproj9_kernel<<<dim3(512, 9), 256, 0, stream>>>(in_W, in_b, cx_W, cx_b, tx_W, tx_b,
                                                    sWk, sWv, sWq, aWk, aWq, Ttab);

  // ---- initial activations (merged) ----
  init2_kernel<<<dim3(4096, 2), 512, 0, stream>>>(cx, cy, in_W, in_b, txp, tx_W, tx_b,
                                                  E, Ebf, QA, QAbf);

  // ---- 8 self/cross encoder layers ----
  for (int p = 0; p < 4; ++p) {
    for (int i = 0; i < 2; ++i) {
      gemm_pack_big_kernel<<<dim3(12, 32), 256, 0, stream>>>(Ebf, Wkvqt[i], KfrA, VfrA,
                                                             QbfA);
      const float* F0 = nullptr;
      const float* F1 = nullptr;
      if (p > 0) {
        affine3kqv_kernel<<<4096, 256, 0, stream>>>(cx, cy, p, T_sc[i][0], T_sc[i][1],
                                                    T_sc[i][2], KfrB, QbfB, VfrB);
        attn_mfma_kernel<256, 2, 2><<<512, 256, 0, stream>>>(
            QbfA, QbfB, KfrA, KfrB, VfrA, VfrB, 1.0f, 2, nullptr, Rp);
        F0 = Rp; F1 = Rp + 4096 * 512;
      } else {
        // x2 is x: 4 identical sdpa terms -> 4 * sdpa(sQ,sK,sV)
        attn_mfma_kernel<256, 1, 1><<<512, 256, 0, stream>>>(
            QbfA, QbfA, KfrA, KfrA, VfrA, VfrA, 4.0f, 2, Rbbf, nullptr);
      }
      gemm_wf_kernel<<<dim3(8, 32, 2), 256, 0, stream>>>(
          Ebf, Rbbf, F0, F1, Wft[i], sbf + (size_t)i * 512, G0, G1);
      ln_kernel<<<4096, 256, 0, stream>>>(G0, G1, E, sg + (size_t)i * 512,
                                          sb + (size_t)i * 512, E, Ebf);
    }
  }

  // ---- 2 cross-attention decoder layers (nh=4, D=128) ----
  for (int i = 0; i < 2; ++i) {
    if (i == 0) {
      rank1kq_kernel<<<4096, 128, 0, stream>>>(cx, T_cak[0], KfrA, txp, T_caq0, QbfB);
    } else {
      rank1_pack_kernel<<<4096, 64, 0, stream>>>(cx, T_cak[1], KfrA, 0);
    }
    gemm_pack_kernel<1><<<dim3(8, 32), 256, 0, stream>>>(Ebf, aWvt[i], nullptr, VfrA,
                                                         nullptr);
    if (i == 1) {
      gemm_pack_kernel<2><<<dim3(8, 32), 256, 0, stream>>>(QAbf, aWqt1, nullptr, nullptr,
                                                           QbfB);
    }
    attn_mfma_kernel<128, 1, 2><<<512, 256, 0, stream>>>(
        QbfB, QbfB, KfrA, KfrA, VfrA, VfrA, 1.0f, 4, Rbbf, nullptr);
    gemm_wf_kernel<<<dim3(8, 32, 2), 256, 0, stream>>>(
        QAbf, Rbbf, nullptr, nullptr, aWft[i], abf + (size_t)i * 512, G0, G1);
    ln_kernel<<<4096, 256, 0, stream>>>(G0, G1, QA, ag + (size_t)i * 512,
                                        ab + (size_t)i * 512,
                                        (i == 1) ? (float*)d_out : QA,
                                        (i == 1) ? nullptr : QAbf);
  }
  (void)in_sizes; (void)n_in; (void)out_size; (void)ws_size;
}